// Round 1
// baseline (543.818 us; speedup 1.0000x reference)
//
#include <hip/hip_runtime.h>

// HATGNN forward. All f32. Pipeline:
//   memset -> k_pre (reduced weight tables) -> CSR build (count/scan/fill)
//   -> node type-sort -> k_node (v GEMV) -> k_kqr (ks,qd,r tables)
//   -> k_logit -> k_main (per-dst-node softmax + aggregation + both classifiers)
// ws usage ~82 MB.

#define NN 100000
#define NE 600000
#define FD 128
#define HIDD 128
#define NH 4
#define DH 32
#define NT 3
#define NET 4
#define SLOPE 0.2f

// ---------------- ws layout (bytes) ----------------
#define OFF_V       0UL            // N*128 f32      51,200,000
#define OFF_KS      51200000UL     // N*4 f32         1,600,000
#define OFF_QD      52800000UL     // N*4 f32         1,600,000
#define OFF_R       54400000UL     // N*4*4 f32       6,400,000
#define OFF_LOG     60800000UL     // E*4 f32         9,600,000
#define OFF_COUNTS  70400000UL     // N int             400,000
#define OFF_NCNT    70800000UL     // 4 int
#define OFF_NCUR    70800016UL     // 4 int
#define ZERO_BASE   OFF_COUNTS
#define ZERO_BYTES  400032UL
#define OFF_ROWPTR  70800128UL     // (N+1) int
#define OFF_CURSOR  71200256UL     // N int
#define OFF_INCL    71600384UL     // N int
#define OFF_BSUMS   72000512UL     // 64 int
#define OFF_SSRC    72000768UL     // E int
#define OFF_SET     74400896UL     // E int
#define OFF_SEID    76801024UL     // E int
#define OFF_EPOS    79201024UL     // E int
#define OFF_WKRED   81601024UL     // 3*128*4 f32
#define OFF_WQRED   81607168UL
#define OFF_ETL     81613312UL     // 4*4 f32
#define OFF_NBASE   81613440UL     // 4 int
#define OFF_NPERM   81613568UL     // (N+96) int      400,384
#define NPERM_BYTES 400384UL

// ------------- tiny precompute: reduced weights -------------
__global__ void k_pre(const float* __restrict__ Wq, const float* __restrict__ Wk,
                      const float* __restrict__ att_src, const float* __restrict__ att_dst,
                      const float* __restrict__ be, const float* __restrict__ att_edge,
                      float* __restrict__ wk_red, float* __restrict__ wq_red, float* __restrict__ etl) {
    int gid = blockIdx.x * blockDim.x + threadIdx.x;
    if (gid < NT * FD * NH) {
        int h = gid % NH;
        int i = (gid / NH) % FD;
        int t = gid / (NH * FD);
        const float* wkp = Wk + ((size_t)t * FD + i) * HIDD + h * DH;
        const float* wqp = Wq + ((size_t)t * FD + i) * HIDD + h * DH;
        const float* as = att_src + h * DH;
        const float* ad = att_dst + h * DH;
        float sk = 0.f, sq = 0.f;
        for (int d = 0; d < DH; ++d) { sk += wkp[d] * as[d]; sq += wqp[d] * ad[d]; }
        wk_red[gid] = sk;
        wq_red[gid] = sq;
    } else if (gid < NT * FD * NH + NET * NH) {
        int rdx = gid - NT * FD * NH;
        int h = rdx % NH;
        int t = rdx / NH;
        float s = 0.f;
        for (int d = 0; d < DH; ++d) s += be[t * HIDD + h * DH + d] * att_edge[h * DH + d];
        etl[rdx] = s;
    }
}

// ------------- CSR build -------------
__global__ void k_count(const int* __restrict__ ei, int* __restrict__ counts) {
    int e = blockIdx.x * blockDim.x + threadIdx.x;
    if (e < NE) atomicAdd(&counts[ei[NE + e]], 1);
}

__global__ void k_scan1(const int* __restrict__ counts, int* __restrict__ incl, int* __restrict__ bsums) {
    __shared__ int lds[2048];
    int base = blockIdx.x * 2048;
    for (int k = threadIdx.x; k < 2048; k += 256)
        lds[k] = (base + k < NN) ? counts[base + k] : 0;
    __syncthreads();
    for (int off = 1; off < 2048; off <<= 1) {
        int vals[8];
        for (int j = 0; j < 8; ++j) {
            int k = threadIdx.x + j * 256;
            vals[j] = (k >= off) ? lds[k - off] : 0;
        }
        __syncthreads();
        for (int j = 0; j < 8; ++j) {
            int k = threadIdx.x + j * 256;
            lds[k] += vals[j];
        }
        __syncthreads();
    }
    for (int k = threadIdx.x; k < 2048; k += 256)
        if (base + k < NN) incl[base + k] = lds[k];
    if (threadIdx.x == 0) bsums[blockIdx.x] = lds[2047];
}

__global__ void k_scan2(int* __restrict__ bsums, int nb) {
    if (threadIdx.x == 0) {
        int run = 0;
        for (int i = 0; i < nb; ++i) { int vv = bsums[i]; bsums[i] = run; run += vv; }
    }
}

__global__ void k_scan3(const int* __restrict__ counts, const int* __restrict__ incl,
                        const int* __restrict__ bsums, int* __restrict__ row_ptr, int* __restrict__ cursor) {
    int i = blockIdx.x * blockDim.x + threadIdx.x;
    if (i < NN) {
        int ex = incl[i] - counts[i] + bsums[i / 2048];
        row_ptr[i] = ex;
        cursor[i] = ex;
    }
    if (i == 0) row_ptr[NN] = NE;
}

__global__ void k_fill(const int* __restrict__ ei, const int* __restrict__ etype, int* __restrict__ cursor,
                       int* __restrict__ ssrc, int* __restrict__ sset, int* __restrict__ seid,
                       int* __restrict__ epos) {
    int e = blockIdx.x * blockDim.x + threadIdx.x;
    if (e >= NE) return;
    int dst = ei[NE + e];
    int pos = atomicAdd(&cursor[dst], 1);
    seid[pos] = e;
    ssrc[pos] = ei[e];
    sset[pos] = etype[e];
    epos[e] = pos;
}

// ------------- node type sort (padded to 8 per type) -------------
__global__ void k_ncount(const int* __restrict__ ntype, int* __restrict__ ncnt) {
    __shared__ int c[NT];
    if (threadIdx.x < NT) c[threadIdx.x] = 0;
    __syncthreads();
    int n = blockIdx.x * blockDim.x + threadIdx.x;
    if (n < NN) atomicAdd(&c[ntype[n]], 1);
    __syncthreads();
    if (threadIdx.x < NT) atomicAdd(&ncnt[threadIdx.x], c[threadIdx.x]);
}

__global__ void k_nbase(const int* __restrict__ ncnt, int* __restrict__ nbase, int* __restrict__ ncur) {
    if (threadIdx.x == 0) {
        int b = 0;
        for (int t = 0; t < NT; ++t) {
            nbase[t] = b;
            ncur[t] = 0;
            b += (ncnt[t] + 7) & ~7;
        }
        nbase[NT] = b;
    }
}

__global__ void k_nscatter(const int* __restrict__ ntype, const int* __restrict__ nbase,
                           int* __restrict__ ncur, int* __restrict__ nperm) {
    int n = blockIdx.x * blockDim.x + threadIdx.x;
    if (n >= NN) return;
    int tt = ntype[n];
    int lane = threadIdx.x & 63;
    for (int t = 0; t < NT; ++t) {
        unsigned long long m = __ballot(tt == t);
        if (tt == t) {
            int rank = __popcll(m & ((1ull << lane) - 1ull));
            int leader = __ffsll((unsigned long long)m) - 1;
            int base = 0;
            if (lane == leader) base = atomicAdd(&ncur[t], (int)__popcll(m));
            base = __shfl(base, leader, 64);
            nperm[nbase[t] + base + rank] = n;
        }
    }
}

// ------------- v = x @ Wv[type] : 8 nodes per 32-lane group -------------
__global__ __launch_bounds__(256) void k_node(const float* __restrict__ x, const float* __restrict__ Wv,
                                              const int* __restrict__ ntype, const int* __restrict__ nperm,
                                              float* __restrict__ v) {
    int g = threadIdx.x >> 5;
    int c = threadIdx.x & 31;
    int s0 = blockIdx.x * 64 + g * 8;
    int idx[8];
    unsigned wmask = 0;
    int t = -1;
    for (int m = 0; m < 8; ++m) {
        int nm = nperm[s0 + m];
        idx[m] = nm;
        if (nm >= 0) { wmask |= 1u << m; if (t < 0) t = ntype[nm]; }
    }
    if (t < 0) return;
    for (int m = 0; m < 8; ++m) if (idx[m] < 0) idx[m] = 0;  // dummy read, masked write
    const float* W = Wv + (size_t)t * FD * HIDD;
    float ax[8], ay[8], az[8], aw[8];
    for (int m = 0; m < 8; ++m) { ax[m] = ay[m] = az[m] = aw[m] = 0.f; }
    for (int i = 0; i < FD; ++i) {
        float4 w4 = reinterpret_cast<const float4*>(W + (size_t)i * HIDD)[c];
        for (int m = 0; m < 8; ++m) {
            float xi = x[(size_t)idx[m] * FD + i];
            ax[m] = fmaf(xi, w4.x, ax[m]);
            ay[m] = fmaf(xi, w4.y, ay[m]);
            az[m] = fmaf(xi, w4.z, az[m]);
            aw[m] = fmaf(xi, w4.w, aw[m]);
        }
    }
    for (int m = 0; m < 8; ++m) {
        if (wmask & (1u << m)) {
            float4 o = {ax[m], ay[m], az[m], aw[m]};
            reinterpret_cast<float4*>(v + (size_t)idx[m] * HIDD)[c] = o;
        }
    }
}

// ------------- per-node small tables: ks, qd, r -------------
__global__ void k_kqr(const float* __restrict__ x, const float* __restrict__ v, const int* __restrict__ ntype,
                      const float* __restrict__ wk_red, const float* __restrict__ wq_red,
                      const float* __restrict__ be, const float* __restrict__ Wec,
                      float* __restrict__ ks4, float* __restrict__ qd4, float* __restrict__ r) {
    int n = blockIdx.x * blockDim.x + threadIdx.x;
    if (n >= NN) return;
    int t = ntype[n];
    const float4* wk = reinterpret_cast<const float4*>(wk_red + (size_t)t * FD * NH);
    const float4* wq = reinterpret_cast<const float4*>(wq_red + (size_t)t * FD * NH);
    const float* xr = x + (size_t)n * FD;
    float kx = 0, ky = 0, kz = 0, kw = 0, qx = 0, qy = 0, qz = 0, qw = 0;
    for (int i = 0; i < FD; ++i) {
        float xi = xr[i];
        float4 a = wk[i], b = wq[i];
        kx = fmaf(xi, a.x, kx); ky = fmaf(xi, a.y, ky); kz = fmaf(xi, a.z, kz); kw = fmaf(xi, a.w, kw);
        qx = fmaf(xi, b.x, qx); qy = fmaf(xi, b.y, qy); qz = fmaf(xi, b.z, qz); qw = fmaf(xi, b.w, qw);
    }
    float4 ko = {kx, ky, kz, kw}, qo = {qx, qy, qz, qw};
    reinterpret_cast<float4*>(ks4)[n] = ko;
    reinterpret_cast<float4*>(qd4)[n] = qo;
    const float* vr = v + (size_t)n * HIDD;
    for (int t2 = 0; t2 < NET; ++t2) {
        float acc[NH] = {0.f, 0.f, 0.f, 0.f};
        for (int h = 0; h < NH; ++h) {
            const float* bep = be + t2 * HIDD + h * DH;
            const float* wep = Wec + t2 * HIDD + h * DH;
            const float* vp = vr + h * DH;
            float s = 0.f;
            for (int d = 0; d < DH; ++d) {
                float u = vp[d] + bep[d];
                s = fmaf(fmaxf(u, 0.f), wep[d], s);
            }
            acc[h] = s;
        }
        float4 o = {acc[0], acc[1], acc[2], acc[3]};
        reinterpret_cast<float4*>(r + ((size_t)n * NET + t2) * NH)[0] = o;
    }
}

// ------------- logits per edge (scattered to CSR order) -------------
__global__ void k_logit(const int* __restrict__ ei, const int* __restrict__ etype,
                        const float* __restrict__ ks4, const float* __restrict__ qd4,
                        const float* __restrict__ etl, const int* __restrict__ epos,
                        float* __restrict__ logits) {
    int e = blockIdx.x * blockDim.x + threadIdx.x;
    if (e >= NE) return;
    int s = ei[e], dnode = ei[NE + e], t = etype[e];
    float4 a = reinterpret_cast<const float4*>(ks4)[s];
    float4 b = reinterpret_cast<const float4*>(qd4)[dnode];
    float4 cc = reinterpret_cast<const float4*>(etl)[t];
    float4 l;
    l.x = a.x + b.x + cc.x;
    l.y = a.y + b.y + cc.y;
    l.z = a.z + b.z + cc.z;
    l.w = a.w + b.w + cc.w;
    l.x = l.x >= 0.f ? l.x : SLOPE * l.x;
    l.y = l.y >= 0.f ? l.y : SLOPE * l.y;
    l.z = l.z >= 0.f ? l.z : SLOPE * l.z;
    l.w = l.w >= 0.f ? l.w : SLOPE * l.w;
    reinterpret_cast<float4*>(logits)[epos[e]] = l;
}

// ------------- main: per-dst-node softmax + aggregate + classifiers -------------
__global__ __launch_bounds__(256) void k_main(const int* __restrict__ row_ptr, const int* __restrict__ ssrc,
                                              const int* __restrict__ sset, const int* __restrict__ seid,
                                              const float* __restrict__ logits, const float* __restrict__ v,
                                              const float* __restrict__ be, const float* __restrict__ r,
                                              const float* __restrict__ Wn, const float* __restrict__ bn,
                                              const float* __restrict__ bec, const int* __restrict__ ntype,
                                              float* __restrict__ out_x, float* __restrict__ out_e) {
    int wave = threadIdx.x >> 6;
    int lane = threadIdx.x & 63;
    int n = blockIdx.x * 4 + wave;
    if (n >= NN) return;
    int rs = row_ptr[n], re = row_ptr[n + 1];
    int deg = re - rs;

    int hh = lane & 3;
    // pass 1: per-head max
    float mx = -INFINITY;
    for (int k = lane >> 2; k < deg; k += 16)
        mx = fmaxf(mx, logits[(size_t)(rs + k) * NH + hh]);
    for (int off = 4; off < 64; off <<= 1) mx = fmaxf(mx, __shfl_xor(mx, off, 64));
    // pass 2: denom
    float dn = 0.f;
    for (int k = lane >> 2; k < deg; k += 16)
        dn += __expf(logits[(size_t)(rs + k) * NH + hh] - mx);
    for (int off = 4; off < 64; off <<= 1) dn += __shfl_xor(dn, off, 64);

    int hv = lane >> 4;                 // head owning v-dims [32h,32h+32)
    float mh = __shfl(mx, hv, 64);      // lane h (h<4) holds head h's reduced value
    float dh = __shfl(dn, hv, 64);
    float inv_dn = 1.0f / (dh + 1e-16f);

    // pass 3: weighted aggregation + e_cls
    float accx = 0.f, accy = 0.f;
    for (int j = 0; j < deg; ++j) {
        int pos = rs + j;
        int sn = ssrc[pos];
        int et = sset[pos];
        float lg = logits[(size_t)pos * NH + hv];
        float p = __expf(lg - mh);
        float2 v2 = reinterpret_cast<const float2*>(v + (size_t)sn * HIDD)[lane];
        float2 b2 = reinterpret_cast<const float2*>(be + (size_t)et * HIDD)[lane];
        accx = fmaf(p, v2.x + b2.x, accx);
        accy = fmaf(p, v2.y + b2.y, accy);
        float term = ((lane & 15) == 0) ? p * inv_dn * r[((size_t)sn * NET + et) * NH + hv] : 0.f;
        term += __shfl_xor(term, 16, 64);
        term += __shfl_xor(term, 32, 64);
        if (lane == 0) out_e[seid[pos]] = term + bec[et];
    }
    accx *= inv_dn;
    accy *= inv_dn;

    // x_cls: relu then dot with Wn[type]
    int t = ntype[n];
    float w0 = Wn[t * HIDD + lane * 2];
    float w1 = Wn[t * HIDD + lane * 2 + 1];
    float s = fmaxf(accx, 0.f) * w0 + fmaxf(accy, 0.f) * w1;
    for (int off = 1; off < 64; off <<= 1) s += __shfl_xor(s, off, 64);
    if (lane == 0) out_x[n] = s + bn[t];
}

extern "C" void kernel_launch(void* const* d_in, const int* in_sizes, int n_in,
                              void* d_out, int out_size, void* d_ws, size_t ws_size,
                              hipStream_t stream) {
    const float* x        = (const float*)d_in[0];
    const int*   ei       = (const int*)d_in[1];
    const int*   ntype    = (const int*)d_in[2];
    const int*   etype    = (const int*)d_in[3];
    // d_in[4] edge_attr: unused (reference feeds zeros into the conv)
    const float* Wq       = (const float*)d_in[5];
    const float* Wk       = (const float*)d_in[6];
    const float* Wv       = (const float*)d_in[7];
    const float* att_src  = (const float*)d_in[8];
    const float* att_dst  = (const float*)d_in[9];
    const float* att_edge = (const float*)d_in[10];
    // d_in[11] We: unused (multiplied by zero edge_attr)
    const float* be       = (const float*)d_in[12];
    const float* Wn       = (const float*)d_in[13];
    const float* bn       = (const float*)d_in[14];
    const float* Wec      = (const float*)d_in[15];
    const float* bec      = (const float*)d_in[16];

    char* ws = (char*)d_ws;
    float* v       = (float*)(ws + OFF_V);
    float* ks4     = (float*)(ws + OFF_KS);
    float* qd4     = (float*)(ws + OFF_QD);
    float* rtab    = (float*)(ws + OFF_R);
    float* logits  = (float*)(ws + OFF_LOG);
    int*   counts  = (int*)(ws + OFF_COUNTS);
    int*   ncnt    = (int*)(ws + OFF_NCNT);
    int*   ncur    = (int*)(ws + OFF_NCUR);
    int*   row_ptr = (int*)(ws + OFF_ROWPTR);
    int*   cursor  = (int*)(ws + OFF_CURSOR);
    int*   incl    = (int*)(ws + OFF_INCL);
    int*   bsums   = (int*)(ws + OFF_BSUMS);
    int*   ssrc    = (int*)(ws + OFF_SSRC);
    int*   sset    = (int*)(ws + OFF_SET);
    int*   seid    = (int*)(ws + OFF_SEID);
    int*   epos    = (int*)(ws + OFF_EPOS);
    float* wk_red  = (float*)(ws + OFF_WKRED);
    float* wq_red  = (float*)(ws + OFF_WQRED);
    float* etl     = (float*)(ws + OFF_ETL);
    int*   nbase   = (int*)(ws + OFF_NBASE);
    int*   nperm   = (int*)(ws + OFF_NPERM);

    float* out_x = (float*)d_out;
    float* out_e = (float*)d_out + NN;

    hipMemsetAsync(ws + ZERO_BASE, 0, ZERO_BYTES, stream);
    hipMemsetAsync(ws + OFF_NPERM, 0xFF, NPERM_BYTES, stream);

    k_pre<<<7, 256, 0, stream>>>(Wq, Wk, att_src, att_dst, be, att_edge, wk_red, wq_red, etl);
    k_count<<<(NE + 255) / 256, 256, 0, stream>>>(ei, counts);
    k_scan1<<<49, 256, 0, stream>>>(counts, incl, bsums);
    k_scan2<<<1, 64, 0, stream>>>(bsums, 49);
    k_scan3<<<(NN + 255) / 256, 256, 0, stream>>>(counts, incl, bsums, row_ptr, cursor);
    k_fill<<<(NE + 255) / 256, 256, 0, stream>>>(ei, etype, cursor, ssrc, sset, seid, epos);
    k_ncount<<<(NN + 255) / 256, 256, 0, stream>>>(ntype, ncnt);
    k_nbase<<<1, 64, 0, stream>>>(ncnt, nbase, ncur);
    k_nscatter<<<(NN + 255) / 256, 256, 0, stream>>>(ntype, nbase, ncur, nperm);
    k_node<<<1564, 256, 0, stream>>>(x, Wv, ntype, nperm, v);
    k_kqr<<<(NN + 255) / 256, 256, 0, stream>>>(x, v, ntype, wk_red, wq_red, be, Wec, ks4, qd4, rtab);
    k_logit<<<(NE + 255) / 256, 256, 0, stream>>>(ei, etype, ks4, qd4, etl, epos, logits);
    k_main<<<(NN + 3) / 4, 256, 0, stream>>>(row_ptr, ssrc, sset, seid, logits, v, be, rtab,
                                             Wn, bn, bec, ntype, out_x, out_e);
}

// Round 2
// 387.094 us; speedup vs baseline: 1.4049x; 1.4049x over previous
//
#include <hip/hip_runtime.h>

// HATGNN forward, all f32.
// Pipeline: memset -> k_pre -> CSR build (count/scan/fill) -> node type-sort
//   -> k_node (v GEMV + ks/qd/r tables fused) -> k_main (softmax+agg+x_cls, stores m/inv)
//   -> k_ecls (edge-parallel e_cls).
// Key ideas: e_emb == be[etype] (edge_attr is zeroed in the reference); q/k fold into
// per-type reduced weights (ks,qd scalars per head); e_cls = sum_h alpha_h * r[src,et,h]
// since alpha>=0 commutes with relu.

#define NN 100000
#define NE 600000
#define FD 128
#define HIDD 128
#define NH 4
#define DH 32
#define NT 3
#define NET 4
#define SLOPE 0.2f

// ---------------- ws layout (bytes) ----------------
#define OFF_V       0UL            // N*128 f32      51,200,000
#define OFF_KS      51200000UL     // N*4 f32         1,600,000
#define OFF_QMI     52800000UL     // N*12 f32 (qd4 | m4 | inv4)  4,800,000
#define OFF_R       57600000UL     // N*4*4 f32       6,400,000
#define OFF_COUNTS  64000000UL     // N int             400,000
#define OFF_NCNT    64400000UL     // 4 int
#define OFF_NCUR    64400016UL     // 4 int
#define ZERO_BASE   OFF_COUNTS
#define ZERO_BYTES  400032UL
#define OFF_ROWPTR  64400128UL     // (N+1) int
#define OFF_CURSOR  64800256UL     // N int
#define OFF_INCL    65200384UL     // N int
#define OFF_BSUMS   65600512UL     // 64 int
#define OFF_SSRC    65600768UL     // E int
#define OFF_SET     68000768UL     // E int
#define OFF_WKRED   70400768UL     // 3*128*4 f32
#define OFF_WQRED   70406912UL
#define OFF_ETL     70413056UL     // 4*4 f32
#define OFF_NBASE   70413184UL     // 4 int
#define OFF_NPERM   70413312UL     // (N+96) int      400,384
#define NPERM_BYTES 400384UL

// ------------- tiny precompute: reduced weights -------------
__global__ void k_pre(const float* __restrict__ Wq, const float* __restrict__ Wk,
                      const float* __restrict__ att_src, const float* __restrict__ att_dst,
                      const float* __restrict__ be, const float* __restrict__ att_edge,
                      float* __restrict__ wk_red, float* __restrict__ wq_red, float* __restrict__ etl) {
    int gid = blockIdx.x * blockDim.x + threadIdx.x;
    if (gid < NT * FD * NH) {
        int h = gid % NH;
        int i = (gid / NH) % FD;
        int t = gid / (NH * FD);
        const float* wkp = Wk + ((size_t)t * FD + i) * HIDD + h * DH;
        const float* wqp = Wq + ((size_t)t * FD + i) * HIDD + h * DH;
        const float* as = att_src + h * DH;
        const float* ad = att_dst + h * DH;
        float sk = 0.f, sq = 0.f;
        for (int d = 0; d < DH; ++d) { sk += wkp[d] * as[d]; sq += wqp[d] * ad[d]; }
        wk_red[gid] = sk;   // layout [t][i][h]
        wq_red[gid] = sq;
    } else if (gid < NT * FD * NH + NET * NH) {
        int rdx = gid - NT * FD * NH;
        int h = rdx % NH;
        int t = rdx / NH;
        float s = 0.f;
        for (int d = 0; d < DH; ++d) s += be[t * HIDD + h * DH + d] * att_edge[h * DH + d];
        etl[rdx] = s;       // layout [t][h]
    }
}

// ------------- CSR build -------------
__global__ void k_count(const int* __restrict__ ei, int* __restrict__ counts) {
    int e = blockIdx.x * blockDim.x + threadIdx.x;
    if (e < NE) atomicAdd(&counts[ei[NE + e]], 1);
}

__global__ void k_scan1(const int* __restrict__ counts, int* __restrict__ incl, int* __restrict__ bsums) {
    __shared__ int lds[2048];
    int base = blockIdx.x * 2048;
    for (int k = threadIdx.x; k < 2048; k += 256)
        lds[k] = (base + k < NN) ? counts[base + k] : 0;
    __syncthreads();
    for (int off = 1; off < 2048; off <<= 1) {
        int vals[8];
        for (int j = 0; j < 8; ++j) {
            int k = threadIdx.x + j * 256;
            vals[j] = (k >= off) ? lds[k - off] : 0;
        }
        __syncthreads();
        for (int j = 0; j < 8; ++j) {
            int k = threadIdx.x + j * 256;
            lds[k] += vals[j];
        }
        __syncthreads();
    }
    for (int k = threadIdx.x; k < 2048; k += 256)
        if (base + k < NN) incl[base + k] = lds[k];
    if (threadIdx.x == 0) bsums[blockIdx.x] = lds[2047];
}

__global__ void k_scan2(int* __restrict__ bsums, int nb) {
    if (threadIdx.x == 0) {
        int run = 0;
        for (int i = 0; i < nb; ++i) { int vv = bsums[i]; bsums[i] = run; run += vv; }
    }
}

__global__ void k_scan3(const int* __restrict__ counts, const int* __restrict__ incl,
                        const int* __restrict__ bsums, int* __restrict__ row_ptr, int* __restrict__ cursor) {
    int i = blockIdx.x * blockDim.x + threadIdx.x;
    if (i < NN) {
        int ex = incl[i] - counts[i] + bsums[i / 2048];
        row_ptr[i] = ex;
        cursor[i] = ex;
    }
    if (i == 0) row_ptr[NN] = NE;
}

__global__ void k_fill(const int* __restrict__ ei, const int* __restrict__ etype, int* __restrict__ cursor,
                       int* __restrict__ ssrc, int* __restrict__ sset) {
    int e = blockIdx.x * blockDim.x + threadIdx.x;
    if (e >= NE) return;
    int dst = ei[NE + e];
    int pos = atomicAdd(&cursor[dst], 1);
    ssrc[pos] = ei[e];
    sset[pos] = etype[e];
}

// ------------- node type sort (padded to 8 per type) -------------
__global__ void k_ncount(const int* __restrict__ ntype, int* __restrict__ ncnt) {
    __shared__ int c[NT];
    if (threadIdx.x < NT) c[threadIdx.x] = 0;
    __syncthreads();
    int n = blockIdx.x * blockDim.x + threadIdx.x;
    if (n < NN) atomicAdd(&c[ntype[n]], 1);
    __syncthreads();
    if (threadIdx.x < NT) atomicAdd(&ncnt[threadIdx.x], c[threadIdx.x]);
}

__global__ void k_nbase(const int* __restrict__ ncnt, int* __restrict__ nbase, int* __restrict__ ncur) {
    if (threadIdx.x == 0) {
        int b = 0;
        for (int t = 0; t < NT; ++t) {
            nbase[t] = b;
            ncur[t] = 0;
            b += (ncnt[t] + 7) & ~7;
        }
        nbase[NT] = b;
    }
}

__global__ void k_nscatter(const int* __restrict__ ntype, const int* __restrict__ nbase,
                           int* __restrict__ ncur, int* __restrict__ nperm) {
    int n = blockIdx.x * blockDim.x + threadIdx.x;
    if (n >= NN) return;
    int tt = ntype[n];
    int lane = threadIdx.x & 63;
    for (int t = 0; t < NT; ++t) {
        unsigned long long m = __ballot(tt == t);
        if (tt == t) {
            int rank = __popcll(m & ((1ull << lane) - 1ull));
            int leader = __ffsll((unsigned long long)m) - 1;
            int base = 0;
            if (lane == leader) base = atomicAdd(&ncur[t], (int)__popcll(m));
            base = __shfl(base, leader, 64);
            nperm[nbase[t] + base + rank] = n;
        }
    }
}

// ------------- v = x @ Wv[type] (+ fused r, ks, qd tables) -------------
// 32-lane group handles 8 same-type nodes; lane c owns output dims 4c..4c+3.
__global__ __launch_bounds__(256) void k_node(const float* __restrict__ x, const float* __restrict__ Wv,
                                              const int* __restrict__ ntype, const int* __restrict__ nperm,
                                              const float* __restrict__ be, const float* __restrict__ Wec,
                                              const float* __restrict__ wk_red, const float* __restrict__ wq_red,
                                              float* __restrict__ v, float* __restrict__ ks4,
                                              float* __restrict__ qmi, float* __restrict__ r) {
    int g = threadIdx.x >> 5;
    int c = threadIdx.x & 31;
    int s0 = blockIdx.x * 64 + g * 8;
    int idx[8];
    unsigned wmask = 0;
    int t = -1;
#pragma unroll
    for (int m = 0; m < 8; ++m) {
        int nm = nperm[s0 + m];
        idx[m] = nm;
        if (nm >= 0) { wmask |= 1u << m; if (t < 0) t = ntype[nm]; }
    }
    if (t < 0) return;
#pragma unroll
    for (int m = 0; m < 8; ++m) if (idx[m] < 0) idx[m] = 0;  // dummy read, masked write

    const float* W = Wv + (size_t)t * FD * HIDD;
    float acc[8][4];
#pragma unroll
    for (int m = 0; m < 8; ++m) { acc[m][0] = acc[m][1] = acc[m][2] = acc[m][3] = 0.f; }

    for (int i0 = 0; i0 < FD; i0 += 4) {
        float4 w0 = *reinterpret_cast<const float4*>(W + (size_t)(i0 + 0) * HIDD + 4 * c);
        float4 w1 = *reinterpret_cast<const float4*>(W + (size_t)(i0 + 1) * HIDD + 4 * c);
        float4 w2 = *reinterpret_cast<const float4*>(W + (size_t)(i0 + 2) * HIDD + 4 * c);
        float4 w3 = *reinterpret_cast<const float4*>(W + (size_t)(i0 + 3) * HIDD + 4 * c);
        float4 xv[8];
#pragma unroll
        for (int m = 0; m < 8; ++m)
            xv[m] = *reinterpret_cast<const float4*>(x + (size_t)idx[m] * FD + i0);
#pragma unroll
        for (int m = 0; m < 8; ++m) {
            acc[m][0] = fmaf(xv[m].x, w0.x, fmaf(xv[m].y, w1.x, fmaf(xv[m].z, w2.x, fmaf(xv[m].w, w3.x, acc[m][0]))));
            acc[m][1] = fmaf(xv[m].x, w0.y, fmaf(xv[m].y, w1.y, fmaf(xv[m].z, w2.y, fmaf(xv[m].w, w3.y, acc[m][1]))));
            acc[m][2] = fmaf(xv[m].x, w0.z, fmaf(xv[m].y, w1.z, fmaf(xv[m].z, w2.z, fmaf(xv[m].w, w3.z, acc[m][2]))));
            acc[m][3] = fmaf(xv[m].x, w0.w, fmaf(xv[m].y, w1.w, fmaf(xv[m].z, w2.w, fmaf(xv[m].w, w3.w, acc[m][3]))));
        }
    }
    // v store
#pragma unroll
    for (int m = 0; m < 8; ++m) {
        if (wmask & (1u << m)) {
            float4 o = {acc[m][0], acc[m][1], acc[m][2], acc[m][3]};
            *reinterpret_cast<float4*>(v + (size_t)idx[m] * HIDD + 4 * c) = o;
        }
    }
    // r table: r[n][t2][h] = sum_d relu(v+be)*Wec ; lane c holds dims 4c..4c+3, head = c>>3
#pragma unroll
    for (int t2 = 0; t2 < NET; ++t2) {
        float4 b4 = *reinterpret_cast<const float4*>(be + t2 * HIDD + 4 * c);
        float4 w4 = *reinterpret_cast<const float4*>(Wec + t2 * HIDD + 4 * c);
#pragma unroll
        for (int m = 0; m < 8; ++m) {
            float s = fmaxf(acc[m][0] + b4.x, 0.f) * w4.x
                    + fmaxf(acc[m][1] + b4.y, 0.f) * w4.y
                    + fmaxf(acc[m][2] + b4.z, 0.f) * w4.z
                    + fmaxf(acc[m][3] + b4.w, 0.f) * w4.w;
            s += __shfl_xor(s, 1, 64);
            s += __shfl_xor(s, 2, 64);
            s += __shfl_xor(s, 4, 64);
            if (((c & 7) == 0) && (wmask & (1u << m)))
                r[(size_t)idx[m] * (NET * NH) + t2 * NH + (c >> 3)] = s;
        }
    }
    // ks/qd: lane c handles input dims 4c..4c+3
    {
        const float* wk = wk_red + (size_t)t * FD * NH;
        const float* wq = wq_red + (size_t)t * FD * NH;
        float4 wkv[4], wqv[4];
#pragma unroll
        for (int j = 0; j < 4; ++j) {
            wkv[j] = *reinterpret_cast<const float4*>(wk + (4 * c + j) * NH);
            wqv[j] = *reinterpret_cast<const float4*>(wq + (4 * c + j) * NH);
        }
#pragma unroll
        for (int m = 0; m < 8; ++m) {
            float4 x4 = *reinterpret_cast<const float4*>(x + (size_t)idx[m] * FD + 4 * c);
            float ka0 = x4.x * wkv[0].x + x4.y * wkv[1].x + x4.z * wkv[2].x + x4.w * wkv[3].x;
            float ka1 = x4.x * wkv[0].y + x4.y * wkv[1].y + x4.z * wkv[2].y + x4.w * wkv[3].y;
            float ka2 = x4.x * wkv[0].z + x4.y * wkv[1].z + x4.z * wkv[2].z + x4.w * wkv[3].z;
            float ka3 = x4.x * wkv[0].w + x4.y * wkv[1].w + x4.z * wkv[2].w + x4.w * wkv[3].w;
            float qa0 = x4.x * wqv[0].x + x4.y * wqv[1].x + x4.z * wqv[2].x + x4.w * wqv[3].x;
            float qa1 = x4.x * wqv[0].y + x4.y * wqv[1].y + x4.z * wqv[2].y + x4.w * wqv[3].y;
            float qa2 = x4.x * wqv[0].z + x4.y * wqv[1].z + x4.z * wqv[2].z + x4.w * wqv[3].z;
            float qa3 = x4.x * wqv[0].w + x4.y * wqv[1].w + x4.z * wqv[2].w + x4.w * wqv[3].w;
#pragma unroll
            for (int off = 1; off < 32; off <<= 1) {
                ka0 += __shfl_xor(ka0, off, 64); ka1 += __shfl_xor(ka1, off, 64);
                ka2 += __shfl_xor(ka2, off, 64); ka3 += __shfl_xor(ka3, off, 64);
                qa0 += __shfl_xor(qa0, off, 64); qa1 += __shfl_xor(qa1, off, 64);
                qa2 += __shfl_xor(qa2, off, 64); qa3 += __shfl_xor(qa3, off, 64);
            }
            if (c == 0 && (wmask & (1u << m))) {
                float4 ko = {ka0, ka1, ka2, ka3};
                float4 qo = {qa0, qa1, qa2, qa3};
                *reinterpret_cast<float4*>(ks4 + (size_t)idx[m] * NH) = ko;
                *reinterpret_cast<float4*>(qmi + (size_t)idx[m] * 12) = qo;
            }
        }
    }
}

// ------------- main: per-dst-node softmax + aggregation + x_cls; stores m/inv -------------
__global__ __launch_bounds__(256) void k_main(const int* __restrict__ row_ptr, const int* __restrict__ ssrc,
                                              const int* __restrict__ sset, const float* __restrict__ ks4,
                                              float* __restrict__ qmi, const float* __restrict__ etl,
                                              const float* __restrict__ v, const float* __restrict__ be,
                                              const float* __restrict__ Wn, const float* __restrict__ bn,
                                              const int* __restrict__ ntype, float* __restrict__ out_x) {
    int wave = threadIdx.x >> 6;
    int lane = threadIdx.x & 63;
    int n = blockIdx.x * 4 + wave;
    if (n >= NN) return;
    int rs = row_ptr[n], deg = row_ptr[n + 1] - rs;
    int hh = lane & 3;      // head for logit work
    int k0 = lane >> 2;     // edge slot 0..15
    int hv = lane >> 4;     // head owning v-dims [32*hv, 32*hv+32)

    float q = qmi[(size_t)n * 12 + hh];

    // chunk-0 logits, kept in register (covers deg<=16, the overwhelming case)
    float lg0 = 0.f;
    bool act0 = k0 < deg;
    if (act0) {
        int pos = rs + k0;
        int s = ssrc[pos], et = sset[pos];
        float l = ks4[(size_t)s * NH + hh] + q + etl[et * NH + hh];
        lg0 = l >= 0.f ? l : SLOPE * l;
    }
    float mx = act0 ? lg0 : -INFINITY;
    if (deg > 16) {
        for (int base = 16; base < deg; base += 16) {
            int kk = base + k0;
            if (kk < deg) {
                int pos = rs + kk;
                int s = ssrc[pos], et = sset[pos];
                float l = ks4[(size_t)s * NH + hh] + q + etl[et * NH + hh];
                l = l >= 0.f ? l : SLOPE * l;
                mx = fmaxf(mx, l);
            }
        }
    }
#pragma unroll
    for (int off = 4; off < 64; off <<= 1) mx = fmaxf(mx, __shfl_xor(mx, off, 64));

    float e0 = act0 ? __expf(lg0 - mx) : 0.f;
    float dn = e0;
    if (deg > 16) {
        for (int base = 16; base < deg; base += 16) {
            int kk = base + k0;
            if (kk < deg) {
                int pos = rs + kk;
                int s = ssrc[pos], et = sset[pos];
                float l = ks4[(size_t)s * NH + hh] + q + etl[et * NH + hh];
                l = l >= 0.f ? l : SLOPE * l;
                dn += __expf(l - mx);
            }
        }
    }
#pragma unroll
    for (int off = 4; off < 64; off <<= 1) dn += __shfl_xor(dn, off, 64);
    float inv = 1.0f / (dn + 1e-16f);

    if (lane < 4) {                       // lane l holds head l's reduced values
        qmi[(size_t)n * 12 + 4 + lane] = mx;
        qmi[(size_t)n * 12 + 8 + lane] = inv;
    }

    // aggregation: acc over v-dims (float2 per lane)
    float ax = 0.f, ay = 0.f;
    for (int base = 0; base < deg; base += 16) {
        float alpha;
        if (base == 0) {
            alpha = e0 * inv;
        } else {
            int kk = base + k0;
            alpha = 0.f;
            if (kk < deg) {
                int pos = rs + kk;
                int s = ssrc[pos], et = sset[pos];
                float l = ks4[(size_t)s * NH + hh] + q + etl[et * NH + hh];
                l = l >= 0.f ? l : SLOPE * l;
                alpha = __expf(l - mx) * inv;
            }
        }
        int cnt = deg - base; if (cnt > 16) cnt = 16;
        for (int j = 0; j < cnt; ++j) {
            float p = __shfl(alpha, j * 4 + hv, 64);
            int pos = rs + base + j;
            int sn = ssrc[pos], et = sset[pos];
            float2 v2 = *reinterpret_cast<const float2*>(v + (size_t)sn * HIDD + 2 * lane);
            float2 b2 = *reinterpret_cast<const float2*>(be + et * HIDD + 2 * lane);
            ax = fmaf(p, v2.x + b2.x, ax);
            ay = fmaf(p, v2.y + b2.y, ay);
        }
    }

    int t = ntype[n];
    float w0 = Wn[t * HIDD + 2 * lane];
    float w1 = Wn[t * HIDD + 2 * lane + 1];
    float s = fmaxf(ax, 0.f) * w0 + fmaxf(ay, 0.f) * w1;
#pragma unroll
    for (int off = 1; off < 64; off <<= 1) s += __shfl_xor(s, off, 64);
    if (lane == 0) out_x[n] = s + bn[t];
}

// ------------- edge classifier, edge-parallel, coalesced out -------------
__global__ void k_ecls(const int* __restrict__ ei, const int* __restrict__ etype,
                       const float* __restrict__ ks4, const float* __restrict__ qmi,
                       const float* __restrict__ etl, const float* __restrict__ r,
                       const float* __restrict__ bec, float* __restrict__ out_e) {
    int e = blockIdx.x * blockDim.x + threadIdx.x;
    if (e >= NE) return;
    int s = ei[e], d = ei[NE + e], t = etype[e];
    float4 a   = *reinterpret_cast<const float4*>(ks4 + (size_t)s * NH);
    float4 qd  = *reinterpret_cast<const float4*>(qmi + (size_t)d * 12);
    float4 m   = *reinterpret_cast<const float4*>(qmi + (size_t)d * 12 + 4);
    float4 inv = *reinterpret_cast<const float4*>(qmi + (size_t)d * 12 + 8);
    float4 c   = *reinterpret_cast<const float4*>(etl + t * NH);
    float l0 = a.x + qd.x + c.x; l0 = l0 >= 0.f ? l0 : SLOPE * l0;
    float l1 = a.y + qd.y + c.y; l1 = l1 >= 0.f ? l1 : SLOPE * l1;
    float l2 = a.z + qd.z + c.z; l2 = l2 >= 0.f ? l2 : SLOPE * l2;
    float l3 = a.w + qd.w + c.w; l3 = l3 >= 0.f ? l3 : SLOPE * l3;
    float4 rr = *reinterpret_cast<const float4*>(r + (size_t)s * (NET * NH) + t * NH);
    float o = __expf(l0 - m.x) * inv.x * rr.x
            + __expf(l1 - m.y) * inv.y * rr.y
            + __expf(l2 - m.z) * inv.z * rr.z
            + __expf(l3 - m.w) * inv.w * rr.w;
    out_e[e] = o + bec[t];
}

extern "C" void kernel_launch(void* const* d_in, const int* in_sizes, int n_in,
                              void* d_out, int out_size, void* d_ws, size_t ws_size,
                              hipStream_t stream) {
    const float* x        = (const float*)d_in[0];
    const int*   ei       = (const int*)d_in[1];
    const int*   ntype    = (const int*)d_in[2];
    const int*   etype    = (const int*)d_in[3];
    // d_in[4] edge_attr: unused (reference feeds zeros into the conv)
    const float* Wq       = (const float*)d_in[5];
    const float* Wk       = (const float*)d_in[6];
    const float* Wv       = (const float*)d_in[7];
    const float* att_src  = (const float*)d_in[8];
    const float* att_dst  = (const float*)d_in[9];
    const float* att_edge = (const float*)d_in[10];
    // d_in[11] We: unused (multiplied by zero edge_attr)
    const float* be       = (const float*)d_in[12];
    const float* Wn       = (const float*)d_in[13];
    const float* bn       = (const float*)d_in[14];
    const float* Wec      = (const float*)d_in[15];
    const float* bec      = (const float*)d_in[16];

    char* ws = (char*)d_ws;
    float* v       = (float*)(ws + OFF_V);
    float* ks4     = (float*)(ws + OFF_KS);
    float* qmi     = (float*)(ws + OFF_QMI);
    float* rtab    = (float*)(ws + OFF_R);
    int*   counts  = (int*)(ws + OFF_COUNTS);
    int*   ncnt    = (int*)(ws + OFF_NCNT);
    int*   ncur    = (int*)(ws + OFF_NCUR);
    int*   row_ptr = (int*)(ws + OFF_ROWPTR);
    int*   cursor  = (int*)(ws + OFF_CURSOR);
    int*   incl    = (int*)(ws + OFF_INCL);
    int*   bsums   = (int*)(ws + OFF_BSUMS);
    int*   ssrc    = (int*)(ws + OFF_SSRC);
    int*   sset    = (int*)(ws + OFF_SET);
    float* wk_red  = (float*)(ws + OFF_WKRED);
    float* wq_red  = (float*)(ws + OFF_WQRED);
    float* etl     = (float*)(ws + OFF_ETL);
    int*   nbase   = (int*)(ws + OFF_NBASE);
    int*   nperm   = (int*)(ws + OFF_NPERM);

    float* out_x = (float*)d_out;
    float* out_e = (float*)d_out + NN;

    hipMemsetAsync(ws + ZERO_BASE, 0, ZERO_BYTES, stream);
    hipMemsetAsync(ws + OFF_NPERM, 0xFF, NPERM_BYTES, stream);

    k_pre<<<7, 256, 0, stream>>>(Wq, Wk, att_src, att_dst, be, att_edge, wk_red, wq_red, etl);
    k_count<<<(NE + 255) / 256, 256, 0, stream>>>(ei, counts);
    k_scan1<<<49, 256, 0, stream>>>(counts, incl, bsums);
    k_scan2<<<1, 64, 0, stream>>>(bsums, 49);
    k_scan3<<<(NN + 255) / 256, 256, 0, stream>>>(counts, incl, bsums, row_ptr, cursor);
    k_fill<<<(NE + 255) / 256, 256, 0, stream>>>(ei, etype, cursor, ssrc, sset);
    k_ncount<<<(NN + 255) / 256, 256, 0, stream>>>(ntype, ncnt);
    k_nbase<<<1, 64, 0, stream>>>(ncnt, nbase, ncur);
    k_nscatter<<<(NN + 255) / 256, 256, 0, stream>>>(ntype, nbase, ncur, nperm);
    k_node<<<1564, 256, 0, stream>>>(x, Wv, ntype, nperm, be, Wec, wk_red, wq_red,
                                     v, ks4, qmi, rtab);
    k_main<<<(NN + 3) / 4, 256, 0, stream>>>(row_ptr, ssrc, sset, ks4, qmi, etl, v, be,
                                             Wn, bn, ntype, out_x);
    k_ecls<<<(NE + 255) / 256, 256, 0, stream>>>(ei, etype, ks4, qmi, etl, rtab, bec, out_e);
}

// Round 3
// 383.905 us; speedup vs baseline: 1.4165x; 1.0083x over previous
//
#include <hip/hip_runtime.h>

// HATGNN forward, all f32.
// Pipeline: memset -> k_pre -> CSR build (count/scan/fill) -> node type-sort
//   -> k_node (v GEMV via LDS-staged x + r table) -> k_kq (ks/qd) ->
//   k_main (softmax+agg+x_cls, stores m/inv) -> k_ecls (edge-parallel e_cls).
// Key ideas: e_emb == be[etype] (edge_attr is zeroed in the reference); q/k fold into
// per-type reduced weights (ks,qd scalars per head); e_cls = sum_h alpha_h * r[src,et,h]
// since alpha>=0 commutes with relu; x_out's be-term factored out of the edge loop.

#define NN 100000
#define NE 600000
#define FD 128
#define HIDD 128
#define NH 4
#define DH 32
#define NT 3
#define NET 4
#define SLOPE 0.2f

// ---------------- ws layout (bytes) ----------------
#define OFF_V       0UL            // N*128 f32      51,200,000
#define OFF_KS      51200000UL     // N*4 f32         1,600,000
#define OFF_QMI     52800000UL     // N*16 f32 (qd4 | m4 | inv4 | pad) 6,400,000
#define OFF_R       59200000UL     // N*4*4 f32       6,400,000
#define OFF_COUNTS  65600000UL     // N int             400,000
#define OFF_NCNT    66000000UL     // 4 int
#define OFF_NCUR    66000016UL     // 4 int
#define ZERO_BASE   OFF_COUNTS
#define ZERO_BYTES  400032UL
#define OFF_ROWPTR  66000128UL     // (N+1) int
#define OFF_CURSOR  66400192UL     // N int
#define OFF_INCL    66800192UL     // N int
#define OFF_BSUMS   67200192UL     // 64 int
#define OFF_SSRC    67200448UL     // E int
#define OFF_SET     69600448UL     // E int
#define OFF_WKRED   72000448UL     // 3*128*4 f32
#define OFF_WQRED   72006592UL
#define OFF_ETL     72012736UL     // 4*4 f32
#define OFF_NBASE   72012864UL     // 4 int
#define OFF_NPERM   72012928UL     // (N+96) int      400,384
#define NPERM_BYTES 400384UL

// ------------- tiny precompute: reduced weights -------------
__global__ void k_pre(const float* __restrict__ Wq, const float* __restrict__ Wk,
                      const float* __restrict__ att_src, const float* __restrict__ att_dst,
                      const float* __restrict__ be, const float* __restrict__ att_edge,
                      float* __restrict__ wk_red, float* __restrict__ wq_red, float* __restrict__ etl) {
    int gid = blockIdx.x * blockDim.x + threadIdx.x;
    if (gid < NT * FD * NH) {
        int h = gid % NH;
        int i = (gid / NH) % FD;
        int t = gid / (NH * FD);
        const float* wkp = Wk + ((size_t)t * FD + i) * HIDD + h * DH;
        const float* wqp = Wq + ((size_t)t * FD + i) * HIDD + h * DH;
        const float* as = att_src + h * DH;
        const float* ad = att_dst + h * DH;
        float sk = 0.f, sq = 0.f;
        for (int d = 0; d < DH; ++d) { sk += wkp[d] * as[d]; sq += wqp[d] * ad[d]; }
        wk_red[gid] = sk;   // layout [t][i][h]
        wq_red[gid] = sq;
    } else if (gid < NT * FD * NH + NET * NH) {
        int rdx = gid - NT * FD * NH;
        int h = rdx % NH;
        int t = rdx / NH;
        float s = 0.f;
        for (int d = 0; d < DH; ++d) s += be[t * HIDD + h * DH + d] * att_edge[h * DH + d];
        etl[rdx] = s;       // layout [t][h]
    }
}

// ------------- CSR build -------------
__global__ void k_count(const int* __restrict__ ei, int* __restrict__ counts) {
    int e = blockIdx.x * blockDim.x + threadIdx.x;
    if (e < NE) atomicAdd(&counts[ei[NE + e]], 1);
}

__global__ void k_scan1(const int* __restrict__ counts, int* __restrict__ incl, int* __restrict__ bsums) {
    __shared__ int lds[2048];
    int base = blockIdx.x * 2048;
    for (int k = threadIdx.x; k < 2048; k += 256)
        lds[k] = (base + k < NN) ? counts[base + k] : 0;
    __syncthreads();
    for (int off = 1; off < 2048; off <<= 1) {
        int vals[8];
        for (int j = 0; j < 8; ++j) {
            int k = threadIdx.x + j * 256;
            vals[j] = (k >= off) ? lds[k - off] : 0;
        }
        __syncthreads();
        for (int j = 0; j < 8; ++j) {
            int k = threadIdx.x + j * 256;
            lds[k] += vals[j];
        }
        __syncthreads();
    }
    for (int k = threadIdx.x; k < 2048; k += 256)
        if (base + k < NN) incl[base + k] = lds[k];
    if (threadIdx.x == 0) bsums[blockIdx.x] = lds[2047];
}

__global__ void k_scan2(int* __restrict__ bsums, int nb) {
    if (threadIdx.x == 0) {
        int run = 0;
        for (int i = 0; i < nb; ++i) { int vv = bsums[i]; bsums[i] = run; run += vv; }
    }
}

__global__ void k_scan3(const int* __restrict__ counts, const int* __restrict__ incl,
                        const int* __restrict__ bsums, int* __restrict__ row_ptr, int* __restrict__ cursor) {
    int i = blockIdx.x * blockDim.x + threadIdx.x;
    if (i < NN) {
        int ex = incl[i] - counts[i] + bsums[i / 2048];
        row_ptr[i] = ex;
        cursor[i] = ex;
    }
    if (i == 0) row_ptr[NN] = NE;
}

__global__ void k_fill(const int* __restrict__ ei, const int* __restrict__ etype, int* __restrict__ cursor,
                       int* __restrict__ ssrc, int* __restrict__ sset) {
    int e = blockIdx.x * blockDim.x + threadIdx.x;
    if (e >= NE) return;
    int dst = ei[NE + e];
    int pos = atomicAdd(&cursor[dst], 1);
    ssrc[pos] = ei[e];
    sset[pos] = etype[e];
}

// ------------- node type sort (padded to 8 per type) -------------
__global__ void k_ncount(const int* __restrict__ ntype, int* __restrict__ ncnt) {
    __shared__ int c[NT];
    if (threadIdx.x < NT) c[threadIdx.x] = 0;
    __syncthreads();
    int n = blockIdx.x * blockDim.x + threadIdx.x;
    if (n < NN) atomicAdd(&c[ntype[n]], 1);
    __syncthreads();
    if (threadIdx.x < NT) atomicAdd(&ncnt[threadIdx.x], c[threadIdx.x]);
}

__global__ void k_nbase(const int* __restrict__ ncnt, int* __restrict__ nbase, int* __restrict__ ncur) {
    if (threadIdx.x == 0) {
        int b = 0;
        for (int t = 0; t < NT; ++t) {
            nbase[t] = b;
            ncur[t] = 0;
            b += (ncnt[t] + 7) & ~7;
        }
        nbase[NT] = b;
    }
}

__global__ void k_nscatter(const int* __restrict__ ntype, const int* __restrict__ nbase,
                           int* __restrict__ ncur, int* __restrict__ nperm) {
    int n = blockIdx.x * blockDim.x + threadIdx.x;
    if (n >= NN) return;
    int tt = ntype[n];
    int lane = threadIdx.x & 63;
    for (int t = 0; t < NT; ++t) {
        unsigned long long m = __ballot(tt == t);
        if (tt == t) {
            int rank = __popcll(m & ((1ull << lane) - 1ull));
            int leader = __ffsll((unsigned long long)m) - 1;
            int base = 0;
            if (lane == leader) base = atomicAdd(&ncur[t], (int)__popcll(m));
            base = __shfl(base, leader, 64);
            nperm[nbase[t] + base + rank] = n;
        }
    }
}

// ------------- v = x @ Wv[type] (+ fused r table), x staged in LDS -------------
// Block = 256 threads = 8 groups of 32 lanes; each group: 8 same-type nodes,
// lane c owns output dims 4c..4c+3.
__global__ __launch_bounds__(256) void k_node(const float* __restrict__ x, const float* __restrict__ Wv,
                                              const int* __restrict__ ntype, const int* __restrict__ nperm,
                                              const float* __restrict__ be, const float* __restrict__ Wec,
                                              float* __restrict__ v, float* __restrict__ r) {
    __shared__ float xs[64 * FD];    // 32 KB
    int tid = threadIdx.x;
    int base = blockIdx.x * 64;

    // stage 64 rows, coalesced: pass p stages rows p*8 .. p*8+7
    for (int p = 0; p < 8; ++p) {
        int rrow = p * 8 + (tid >> 5);
        int node = nperm[base + rrow];
        if (node < 0) node = 0;
        int c4 = tid & 31;
        float4 xv = *reinterpret_cast<const float4*>(x + (size_t)node * FD + 4 * c4);
        *reinterpret_cast<float4*>(&xs[rrow * FD + 4 * c4]) = xv;
    }
    __syncthreads();

    int g = tid >> 5;
    int c = tid & 31;
    int s0 = base + g * 8;
    int idx[8];
    unsigned wmask = 0;
    int t = -1;
#pragma unroll
    for (int m = 0; m < 8; ++m) {
        int nm = nperm[s0 + m];
        idx[m] = nm;
        if (nm >= 0) { wmask |= 1u << m; if (t < 0) t = ntype[nm]; }
    }
    if (t < 0) return;   // only fully-padded groups; no barriers after this point
#pragma unroll
    for (int m = 0; m < 8; ++m) if (idx[m] < 0) idx[m] = 0;

    const float* W = Wv + (size_t)t * FD * HIDD;
    float acc[8][4];
#pragma unroll
    for (int m = 0; m < 8; ++m) { acc[m][0] = acc[m][1] = acc[m][2] = acc[m][3] = 0.f; }

    const float* xrow = &xs[g * 8 * FD];
    for (int i0 = 0; i0 < FD; i0 += 4) {
        float4 w0 = *reinterpret_cast<const float4*>(W + (size_t)(i0 + 0) * HIDD + 4 * c);
        float4 w1 = *reinterpret_cast<const float4*>(W + (size_t)(i0 + 1) * HIDD + 4 * c);
        float4 w2 = *reinterpret_cast<const float4*>(W + (size_t)(i0 + 2) * HIDD + 4 * c);
        float4 w3 = *reinterpret_cast<const float4*>(W + (size_t)(i0 + 3) * HIDD + 4 * c);
        float4 xv[8];
#pragma unroll
        for (int m = 0; m < 8; ++m)
            xv[m] = *reinterpret_cast<const float4*>(xrow + m * FD + i0);
#pragma unroll
        for (int m = 0; m < 8; ++m) {
            acc[m][0] = fmaf(xv[m].x, w0.x, fmaf(xv[m].y, w1.x, fmaf(xv[m].z, w2.x, fmaf(xv[m].w, w3.x, acc[m][0]))));
            acc[m][1] = fmaf(xv[m].x, w0.y, fmaf(xv[m].y, w1.y, fmaf(xv[m].z, w2.y, fmaf(xv[m].w, w3.y, acc[m][1]))));
            acc[m][2] = fmaf(xv[m].x, w0.z, fmaf(xv[m].y, w1.z, fmaf(xv[m].z, w2.z, fmaf(xv[m].w, w3.z, acc[m][2]))));
            acc[m][3] = fmaf(xv[m].x, w0.w, fmaf(xv[m].y, w1.w, fmaf(xv[m].z, w2.w, fmaf(xv[m].w, w3.w, acc[m][3]))));
        }
    }
#pragma unroll
    for (int m = 0; m < 8; ++m) {
        if (wmask & (1u << m)) {
            float4 o = {acc[m][0], acc[m][1], acc[m][2], acc[m][3]};
            *reinterpret_cast<float4*>(v + (size_t)idx[m] * HIDD + 4 * c) = o;
        }
    }
    // r table: r[n][t2][h] = sum_d relu(v+be)*Wec ; lane c holds dims 4c..4c+3, head = c>>3
#pragma unroll
    for (int t2 = 0; t2 < NET; ++t2) {
        float4 b4 = *reinterpret_cast<const float4*>(be + t2 * HIDD + 4 * c);
        float4 w4 = *reinterpret_cast<const float4*>(Wec + t2 * HIDD + 4 * c);
#pragma unroll
        for (int m = 0; m < 8; ++m) {
            float s = fmaxf(acc[m][0] + b4.x, 0.f) * w4.x
                    + fmaxf(acc[m][1] + b4.y, 0.f) * w4.y
                    + fmaxf(acc[m][2] + b4.z, 0.f) * w4.z
                    + fmaxf(acc[m][3] + b4.w, 0.f) * w4.w;
            s += __shfl_xor(s, 1, 64);
            s += __shfl_xor(s, 2, 64);
            s += __shfl_xor(s, 4, 64);
            if (((c & 7) == 0) && (wmask & (1u << m)))
                r[(size_t)idx[m] * (NET * NH) + t2 * NH + (c >> 3)] = s;
        }
    }
}

// ------------- ks/qd per node: 4 lanes per node -------------
__global__ __launch_bounds__(256) void k_kq(const float* __restrict__ x, const int* __restrict__ ntype,
                                            const float* __restrict__ wk_red, const float* __restrict__ wq_red,
                                            float* __restrict__ ks4, float* __restrict__ qmi) {
    int tid = threadIdx.x;
    int n = blockIdx.x * 64 + (tid >> 2);
    if (n >= NN) return;
    int j = tid & 3;                 // owns input dims [32j, 32j+32)
    int t = ntype[n];
    const float* xr = x + (size_t)n * FD + j * 32;
    const float* wk = wk_red + ((size_t)t * FD + j * 32) * NH;
    const float* wq = wq_red + ((size_t)t * FD + j * 32) * NH;
    float ka0 = 0, ka1 = 0, ka2 = 0, ka3 = 0, qa0 = 0, qa1 = 0, qa2 = 0, qa3 = 0;
#pragma unroll
    for (int ii = 0; ii < 32; ii += 4) {
        float4 x4 = *reinterpret_cast<const float4*>(xr + ii);
        float4 wk0 = *reinterpret_cast<const float4*>(wk + (ii + 0) * NH);
        float4 wk1 = *reinterpret_cast<const float4*>(wk + (ii + 1) * NH);
        float4 wk2 = *reinterpret_cast<const float4*>(wk + (ii + 2) * NH);
        float4 wk3 = *reinterpret_cast<const float4*>(wk + (ii + 3) * NH);
        float4 wq0 = *reinterpret_cast<const float4*>(wq + (ii + 0) * NH);
        float4 wq1 = *reinterpret_cast<const float4*>(wq + (ii + 1) * NH);
        float4 wq2 = *reinterpret_cast<const float4*>(wq + (ii + 2) * NH);
        float4 wq3 = *reinterpret_cast<const float4*>(wq + (ii + 3) * NH);
        ka0 = fmaf(x4.x, wk0.x, fmaf(x4.y, wk1.x, fmaf(x4.z, wk2.x, fmaf(x4.w, wk3.x, ka0))));
        ka1 = fmaf(x4.x, wk0.y, fmaf(x4.y, wk1.y, fmaf(x4.z, wk2.y, fmaf(x4.w, wk3.y, ka1))));
        ka2 = fmaf(x4.x, wk0.z, fmaf(x4.y, wk1.z, fmaf(x4.z, wk2.z, fmaf(x4.w, wk3.z, ka2))));
        ka3 = fmaf(x4.x, wk0.w, fmaf(x4.y, wk1.w, fmaf(x4.z, wk2.w, fmaf(x4.w, wk3.w, ka3))));
        qa0 = fmaf(x4.x, wq0.x, fmaf(x4.y, wq1.x, fmaf(x4.z, wq2.x, fmaf(x4.w, wq3.x, qa0))));
        qa1 = fmaf(x4.x, wq0.y, fmaf(x4.y, wq1.y, fmaf(x4.z, wq2.y, fmaf(x4.w, wq3.y, qa1))));
        qa2 = fmaf(x4.x, wq0.z, fmaf(x4.y, wq1.z, fmaf(x4.z, wq2.z, fmaf(x4.w, wq3.z, qa2))));
        qa3 = fmaf(x4.x, wq0.w, fmaf(x4.y, wq1.w, fmaf(x4.z, wq2.w, fmaf(x4.w, wq3.w, qa3))));
    }
#pragma unroll
    for (int off = 1; off < 4; off <<= 1) {
        ka0 += __shfl_xor(ka0, off, 64); ka1 += __shfl_xor(ka1, off, 64);
        ka2 += __shfl_xor(ka2, off, 64); ka3 += __shfl_xor(ka3, off, 64);
        qa0 += __shfl_xor(qa0, off, 64); qa1 += __shfl_xor(qa1, off, 64);
        qa2 += __shfl_xor(qa2, off, 64); qa3 += __shfl_xor(qa3, off, 64);
    }
    if (j == 0) {
        float4 ko = {ka0, ka1, ka2, ka3};
        *reinterpret_cast<float4*>(ks4 + (size_t)n * NH) = ko;
    } else if (j == 1) {
        float4 qo = {qa0, qa1, qa2, qa3};
        *reinterpret_cast<float4*>(qmi + (size_t)n * 16) = qo;
    }
}

// ------------- main: per-dst-node softmax + aggregation + x_cls; stores m/inv -------------
__global__ __launch_bounds__(256) void k_main(const int* __restrict__ row_ptr, const int* __restrict__ ssrc,
                                              const int* __restrict__ sset, const float* __restrict__ ks4,
                                              float* __restrict__ qmi, const float* __restrict__ etl,
                                              const float* __restrict__ v, const float* __restrict__ be,
                                              const float* __restrict__ Wn, const float* __restrict__ bn,
                                              const int* __restrict__ ntype, float* __restrict__ out_x) {
    int wave = threadIdx.x >> 6;
    int lane = threadIdx.x & 63;
    int n = blockIdx.x * 4 + wave;
    if (n >= NN) return;
    int rs = row_ptr[n], deg = row_ptr[n + 1] - rs;
    int hh = lane & 3;      // head for logit work
    int k0 = lane >> 2;     // edge slot 0..15
    int hv = lane >> 4;     // head owning v-dims [32*hv, 32*hv+32)

    float q = qmi[(size_t)n * 16 + hh];

    bool act0 = k0 < deg;
    int pos0 = rs + (act0 ? k0 : 0);
    int s0r = act0 ? ssrc[pos0] : 0;
    int et0 = act0 ? sset[pos0] : 0;
    float lg0 = -INFINITY;
    if (act0) {
        float l = ks4[(size_t)s0r * NH + hh] + q + etl[et0 * NH + hh];
        lg0 = l >= 0.f ? l : SLOPE * l;
    }
    float mx = lg0;
    if (deg > 16) {
        for (int bb = 16; bb < deg; bb += 16) {
            int kk = bb + k0;
            if (kk < deg) {
                int pos = rs + kk;
                int s = ssrc[pos], et = sset[pos];
                float l = ks4[(size_t)s * NH + hh] + q + etl[et * NH + hh];
                l = l >= 0.f ? l : SLOPE * l;
                mx = fmaxf(mx, l);
            }
        }
    }
#pragma unroll
    for (int off = 4; off < 64; off <<= 1) mx = fmaxf(mx, __shfl_xor(mx, off, 64));

    // denominator pass + per-etype exp-sums (for the factored-out be term)
    float e0 = act0 ? __expf(lg0 - mx) : 0.f;
    float dn = e0;
    float P0 = (et0 == 0) ? e0 : 0.f;
    float P1 = (et0 == 1) ? e0 : 0.f;
    float P2 = (et0 == 2) ? e0 : 0.f;
    float P3 = (et0 == 3) ? e0 : 0.f;
    if (deg > 16) {
        for (int bb = 16; bb < deg; bb += 16) {
            int kk = bb + k0;
            if (kk < deg) {
                int pos = rs + kk;
                int s = ssrc[pos], et = sset[pos];
                float l = ks4[(size_t)s * NH + hh] + q + etl[et * NH + hh];
                l = l >= 0.f ? l : SLOPE * l;
                float ev = __expf(l - mx);
                dn += ev;
                P0 += (et == 0) ? ev : 0.f;
                P1 += (et == 1) ? ev : 0.f;
                P2 += (et == 2) ? ev : 0.f;
                P3 += (et == 3) ? ev : 0.f;
            }
        }
    }
#pragma unroll
    for (int off = 4; off < 64; off <<= 1) {
        dn += __shfl_xor(dn, off, 64);
        P0 += __shfl_xor(P0, off, 64);
        P1 += __shfl_xor(P1, off, 64);
        P2 += __shfl_xor(P2, off, 64);
        P3 += __shfl_xor(P3, off, 64);
    }
    float inv = 1.0f / (dn + 1e-16f);

    if (lane < 4) {                       // lane l holds head l's reduced values
        qmi[(size_t)n * 16 + 4 + lane] = mx;
        qmi[(size_t)n * 16 + 8 + lane] = inv;
    }

    float inv_v = __shfl(inv, hv, 64);    // head hv's inv
    float alpha0 = e0 * inv;

    // aggregation over v (float2 per lane); sn via register shuffles
    float ax = 0.f, ay = 0.f;
    int cnt0 = deg < 16 ? deg : 16;
    for (int j = 0; j < cnt0; ++j) {
        float p = __shfl(alpha0, 4 * j + hv, 64);
        int sn = __shfl(s0r, 4 * j, 64);
        float2 v2 = *reinterpret_cast<const float2*>(v + (size_t)sn * HIDD + 2 * lane);
        ax = fmaf(p, v2.x, ax);
        ay = fmaf(p, v2.y, ay);
    }
    if (deg > 16) {
        float mh = __shfl(mx, hv, 64);
        for (int bb = 16; bb < deg; bb += 16) {
            int kk = bb + k0;
            float al = 0.f;
            int sr = 0;
            if (kk < deg) {
                int pos = rs + kk;
                sr = ssrc[pos];
                int et = sset[pos];
                float l = ks4[(size_t)sr * NH + hh] + q + etl[et * NH + hh];
                l = l >= 0.f ? l : SLOPE * l;
                al = __expf(l - mx) * inv;
            }
            (void)mh;
            int cnt = deg - bb; if (cnt > 16) cnt = 16;
            for (int j = 0; j < cnt; ++j) {
                float p = __shfl(al, 4 * j + hv, 64);
                int sn = __shfl(sr, 4 * j, 64);
                float2 v2 = *reinterpret_cast<const float2*>(v + (size_t)sn * HIDD + 2 * lane);
                ax = fmaf(p, v2.x, ax);
                ay = fmaf(p, v2.y, ay);
            }
        }
    }
    // factored be contribution: acc += sum_t A[t,hv] * be[t]
#pragma unroll
    for (int t2 = 0; t2 < NET; ++t2) {
        float Pt = (t2 == 0) ? P0 : (t2 == 1) ? P1 : (t2 == 2) ? P2 : P3;
        float A = __shfl(Pt, hv, 64) * inv_v;
        float2 b2 = *reinterpret_cast<const float2*>(be + t2 * HIDD + 2 * lane);
        ax = fmaf(A, b2.x, ax);
        ay = fmaf(A, b2.y, ay);
    }

    int t = ntype[n];
    float w0 = Wn[t * HIDD + 2 * lane];
    float w1 = Wn[t * HIDD + 2 * lane + 1];
    float s = fmaxf(ax, 0.f) * w0 + fmaxf(ay, 0.f) * w1;
#pragma unroll
    for (int off = 1; off < 64; off <<= 1) s += __shfl_xor(s, off, 64);
    if (lane == 0) out_x[n] = s + bn[t];
}

// ------------- edge classifier, edge-parallel, coalesced out -------------
__global__ void k_ecls(const int* __restrict__ ei, const int* __restrict__ etype,
                       const float* __restrict__ ks4, const float* __restrict__ qmi,
                       const float* __restrict__ etl, const float* __restrict__ r,
                       const float* __restrict__ bec, float* __restrict__ out_e) {
    int e = blockIdx.x * blockDim.x + threadIdx.x;
    if (e >= NE) return;
    int s = ei[e], d = ei[NE + e], t = etype[e];
    float4 a   = *reinterpret_cast<const float4*>(ks4 + (size_t)s * NH);
    float4 qd  = *reinterpret_cast<const float4*>(qmi + (size_t)d * 16);
    float4 m   = *reinterpret_cast<const float4*>(qmi + (size_t)d * 16 + 4);
    float4 inv = *reinterpret_cast<const float4*>(qmi + (size_t)d * 16 + 8);
    float4 c   = *reinterpret_cast<const float4*>(etl + t * NH);
    float l0 = a.x + qd.x + c.x; l0 = l0 >= 0.f ? l0 : SLOPE * l0;
    float l1 = a.y + qd.y + c.y; l1 = l1 >= 0.f ? l1 : SLOPE * l1;
    float l2 = a.z + qd.z + c.z; l2 = l2 >= 0.f ? l2 : SLOPE * l2;
    float l3 = a.w + qd.w + c.w; l3 = l3 >= 0.f ? l3 : SLOPE * l3;
    float4 rr = *reinterpret_cast<const float4*>(r + (size_t)s * (NET * NH) + t * NH);
    float o = __expf(l0 - m.x) * inv.x * rr.x
            + __expf(l1 - m.y) * inv.y * rr.y
            + __expf(l2 - m.z) * inv.z * rr.z
            + __expf(l3 - m.w) * inv.w * rr.w;
    out_e[e] = o + bec[t];
}

extern "C" void kernel_launch(void* const* d_in, const int* in_sizes, int n_in,
                              void* d_out, int out_size, void* d_ws, size_t ws_size,
                              hipStream_t stream) {
    const float* x        = (const float*)d_in[0];
    const int*   ei       = (const int*)d_in[1];
    const int*   ntype    = (const int*)d_in[2];
    const int*   etype    = (const int*)d_in[3];
    // d_in[4] edge_attr: unused (reference feeds zeros into the conv)
    const float* Wq       = (const float*)d_in[5];
    const float* Wk       = (const float*)d_in[6];
    const float* Wv       = (const float*)d_in[7];
    const float* att_src  = (const float*)d_in[8];
    const float* att_dst  = (const float*)d_in[9];
    const float* att_edge = (const float*)d_in[10];
    // d_in[11] We: unused (multiplied by zero edge_attr)
    const float* be       = (const float*)d_in[12];
    const float* Wn       = (const float*)d_in[13];
    const float* bn       = (const float*)d_in[14];
    const float* Wec      = (const float*)d_in[15];
    const float* bec      = (const float*)d_in[16];

    char* ws = (char*)d_ws;
    float* v       = (float*)(ws + OFF_V);
    float* ks4     = (float*)(ws + OFF_KS);
    float* qmi     = (float*)(ws + OFF_QMI);
    float* rtab    = (float*)(ws + OFF_R);
    int*   counts  = (int*)(ws + OFF_COUNTS);
    int*   ncnt    = (int*)(ws + OFF_NCNT);
    int*   ncur    = (int*)(ws + OFF_NCUR);
    int*   row_ptr = (int*)(ws + OFF_ROWPTR);
    int*   cursor  = (int*)(ws + OFF_CURSOR);
    int*   incl    = (int*)(ws + OFF_INCL);
    int*   bsums   = (int*)(ws + OFF_BSUMS);
    int*   ssrc    = (int*)(ws + OFF_SSRC);
    int*   sset    = (int*)(ws + OFF_SET);
    float* wk_red  = (float*)(ws + OFF_WKRED);
    float* wq_red  = (float*)(ws + OFF_WQRED);
    float* etl     = (float*)(ws + OFF_ETL);
    int*   nbase   = (int*)(ws + OFF_NBASE);
    int*   nperm   = (int*)(ws + OFF_NPERM);

    float* out_x = (float*)d_out;
    float* out_e = (float*)d_out + NN;

    hipMemsetAsync(ws + ZERO_BASE, 0, ZERO_BYTES, stream);
    hipMemsetAsync(ws + OFF_NPERM, 0xFF, NPERM_BYTES, stream);

    k_pre<<<7, 256, 0, stream>>>(Wq, Wk, att_src, att_dst, be, att_edge, wk_red, wq_red, etl);
    k_count<<<(NE + 255) / 256, 256, 0, stream>>>(ei, counts);
    k_scan1<<<49, 256, 0, stream>>>(counts, incl, bsums);
    k_scan2<<<1, 64, 0, stream>>>(bsums, 49);
    k_scan3<<<(NN + 255) / 256, 256, 0, stream>>>(counts, incl, bsums, row_ptr, cursor);
    k_fill<<<(NE + 255) / 256, 256, 0, stream>>>(ei, etype, cursor, ssrc, sset);
    k_ncount<<<(NN + 255) / 256, 256, 0, stream>>>(ntype, ncnt);
    k_nbase<<<1, 64, 0, stream>>>(ncnt, nbase, ncur);
    k_nscatter<<<(NN + 255) / 256, 256, 0, stream>>>(ntype, nbase, ncur, nperm);
    k_node<<<1564, 256, 0, stream>>>(x, Wv, ntype, nperm, be, Wec, v, rtab);
    k_kq<<<(NN + 63) / 64, 256, 0, stream>>>(x, ntype, wk_red, wq_red, ks4, qmi);
    k_main<<<(NN + 3) / 4, 256, 0, stream>>>(row_ptr, ssrc, sset, ks4, qmi, etl, v, be,
                                             Wn, bn, ntype, out_x);
    k_ecls<<<(NE + 255) / 256, 256, 0, stream>>>(ei, etype, ks4, qmi, etl, rtab, bec, out_e);
}

// Round 4
// 347.004 us; speedup vs baseline: 1.5672x; 1.1063x over previous
//
#include <hip/hip_runtime.h>
#include <hip/hip_bf16.h>

// HATGNN forward.
// Pipeline: k_init -> k_pre -> k_count -> k_scan1/2 -> k_scan3(+ntype hist) -> k_nbase
//   -> k_fill -> k_nscatter -> k_node (v GEMV + r + ks/qd fused, v stored bf16)
//   -> k_main (softmax + aggregation + x_cls + fused e_cls).
// Key ideas: e_emb == be[etype] (edge_attr zeroed in reference); q/k fold into per-type
// reduced weights; e_cls = sum_h alpha*r[src,et,h] (alpha>=0 commutes with relu);
// be-term of x_out factored out of the edge loop via per-etype exp sums.

#define NN 100000
#define NE 600000
#define FD 128
#define HIDD 128
#define NH 4
#define DH 32
#define NT 3
#define NET 4
#define SLOPE 0.2f

// ---------------- ws layout (bytes) ----------------
#define OFF_V       0UL            // N*128 bf16     25,600,000
#define OFF_KS      25600000UL     // N*4 f32         1,600,000
#define OFF_QD      27200000UL     // N*4 f32         1,600,000
#define OFF_R       28800000UL     // N*16 f32        6,400,000
#define OFF_COUNTS  35200000UL     // N int             400,000
#define OFF_NCNT    35600000UL     // 4 int
#define OFF_NCUR    35600016UL     // 4 int
#define OFF_ROWPTR  35600128UL     // (N+1) int
#define OFF_CURSOR  36000256UL     // N int
#define OFF_INCL    36400256UL     // N int
#define OFF_BSUMS   36800256UL     // 64 int
#define OFF_SSRC    36800512UL     // E int
#define OFF_SET     39200512UL     // E int
#define OFF_SEID    41600512UL     // E int
#define OFF_WKRED   44000512UL     // 3*128*4 f32
#define OFF_WQRED   44006656UL
#define OFF_ETL     44012800UL     // 4*4 f32
#define OFF_NBASE   44012928UL     // 4 int
#define OFF_NPERM   44013056UL     // (N+96) int

__device__ __forceinline__ unsigned int pack_bf16(float a, float b) {
    __hip_bfloat16 ha = __float2bfloat16(a);
    __hip_bfloat16 hb = __float2bfloat16(b);
    unsigned short ua = *reinterpret_cast<unsigned short*>(&ha);
    unsigned short ub = *reinterpret_cast<unsigned short*>(&hb);
    return (unsigned int)ua | ((unsigned int)ub << 16);
}

// ------------- init (replaces memsets) -------------
__global__ void k_init(int* __restrict__ counts, int* __restrict__ ncnt, int* __restrict__ nperm) {
    int i = blockIdx.x * blockDim.x + threadIdx.x;
    if (i < NN) counts[i] = 0;
    if (i < NN + 96) nperm[i] = -1;
    if (i < NT) ncnt[i] = 0;
}

// ------------- tiny precompute: reduced weights -------------
__global__ void k_pre(const float* __restrict__ Wq, const float* __restrict__ Wk,
                      const float* __restrict__ att_src, const float* __restrict__ att_dst,
                      const float* __restrict__ be, const float* __restrict__ att_edge,
                      float* __restrict__ wk_red, float* __restrict__ wq_red, float* __restrict__ etl) {
    int gid = blockIdx.x * blockDim.x + threadIdx.x;
    if (gid < NT * FD * NH) {
        int h = gid % NH;
        int i = (gid / NH) % FD;
        int t = gid / (NH * FD);
        const float* wkp = Wk + ((size_t)t * FD + i) * HIDD + h * DH;
        const float* wqp = Wq + ((size_t)t * FD + i) * HIDD + h * DH;
        const float* as = att_src + h * DH;
        const float* ad = att_dst + h * DH;
        float sk = 0.f, sq = 0.f;
        for (int d = 0; d < DH; ++d) { sk += wkp[d] * as[d]; sq += wqp[d] * ad[d]; }
        wk_red[gid] = sk;   // layout [t][i][h]
        wq_red[gid] = sq;
    } else if (gid < NT * FD * NH + NET * NH) {
        int rdx = gid - NT * FD * NH;
        int h = rdx % NH;
        int t = rdx / NH;
        float s = 0.f;
        for (int d = 0; d < DH; ++d) s += be[t * HIDD + h * DH + d] * att_edge[h * DH + d];
        etl[rdx] = s;       // layout [t][h]
    }
}

// ------------- CSR build -------------
__global__ void k_count(const int* __restrict__ ei, int* __restrict__ counts) {
    int e = blockIdx.x * blockDim.x + threadIdx.x;
    if (e < NE) atomicAdd(&counts[ei[NE + e]], 1);
}

__global__ void k_scan1(const int* __restrict__ counts, int* __restrict__ incl, int* __restrict__ bsums) {
    __shared__ int lds[2048];
    int base = blockIdx.x * 2048;
    for (int k = threadIdx.x; k < 2048; k += 256)
        lds[k] = (base + k < NN) ? counts[base + k] : 0;
    __syncthreads();
    for (int off = 1; off < 2048; off <<= 1) {
        int vals[8];
        for (int j = 0; j < 8; ++j) {
            int k = threadIdx.x + j * 256;
            vals[j] = (k >= off) ? lds[k - off] : 0;
        }
        __syncthreads();
        for (int j = 0; j < 8; ++j) {
            int k = threadIdx.x + j * 256;
            lds[k] += vals[j];
        }
        __syncthreads();
    }
    for (int k = threadIdx.x; k < 2048; k += 256)
        if (base + k < NN) incl[base + k] = lds[k];
    if (threadIdx.x == 0) bsums[blockIdx.x] = lds[2047];
}

__global__ void k_scan2(int* __restrict__ bsums, int nb) {
    if (threadIdx.x == 0) {
        int run = 0;
        for (int i = 0; i < nb; ++i) { int vv = bsums[i]; bsums[i] = run; run += vv; }
    }
}

// + ntype histogram (merged k_ncount)
__global__ void k_scan3(const int* __restrict__ counts, const int* __restrict__ incl,
                        const int* __restrict__ bsums, int* __restrict__ row_ptr, int* __restrict__ cursor,
                        const int* __restrict__ ntype, int* __restrict__ ncnt) {
    __shared__ int c[NT];
    if (threadIdx.x < NT) c[threadIdx.x] = 0;
    __syncthreads();
    int i = blockIdx.x * blockDim.x + threadIdx.x;
    if (i < NN) {
        int ex = incl[i] - counts[i] + bsums[i / 2048];
        row_ptr[i] = ex;
        cursor[i] = ex;
        atomicAdd(&c[ntype[i]], 1);
    }
    if (i == 0) row_ptr[NN] = NE;
    __syncthreads();
    if (threadIdx.x < NT) atomicAdd(&ncnt[threadIdx.x], c[threadIdx.x]);
}

__global__ void k_nbase(const int* __restrict__ ncnt, int* __restrict__ nbase, int* __restrict__ ncur) {
    if (threadIdx.x == 0) {
        int b = 0;
        for (int t = 0; t < NT; ++t) {
            nbase[t] = b;
            ncur[t] = 0;
            b += (ncnt[t] + 7) & ~7;
        }
        nbase[NT] = b;
    }
}

__global__ void k_fill(const int* __restrict__ ei, const int* __restrict__ etype, int* __restrict__ cursor,
                       int* __restrict__ ssrc, int* __restrict__ sset, int* __restrict__ seid) {
    int e = blockIdx.x * blockDim.x + threadIdx.x;
    if (e >= NE) return;
    int dst = ei[NE + e];
    int pos = atomicAdd(&cursor[dst], 1);
    ssrc[pos] = ei[e];
    sset[pos] = etype[e];
    seid[pos] = e;
}

__global__ void k_nscatter(const int* __restrict__ ntype, const int* __restrict__ nbase,
                           int* __restrict__ ncur, int* __restrict__ nperm) {
    int n = blockIdx.x * blockDim.x + threadIdx.x;
    if (n >= NN) return;
    int tt = ntype[n];
    int lane = threadIdx.x & 63;
    for (int t = 0; t < NT; ++t) {
        unsigned long long m = __ballot(tt == t);
        if (tt == t) {
            int rank = __popcll(m & ((1ull << lane) - 1ull));
            int leader = __ffsll((unsigned long long)m) - 1;
            int base = 0;
            if (lane == leader) base = atomicAdd(&ncur[t], (int)__popcll(m));
            base = __shfl(base, leader, 64);
            nperm[nbase[t] + base + rank] = n;
        }
    }
}

// ------------- v = x @ Wv[type] (+ r table + ks/qd), x staged in LDS -------------
// Block = 256 threads = 8 groups of 32 lanes; each group: 8 same-type nodes,
// lane c owns output dims 4c..4c+3 in the GEMV phase.
__global__ __launch_bounds__(256) void k_node(const float* __restrict__ x, const float* __restrict__ Wv,
                                              const int* __restrict__ ntype, const int* __restrict__ nperm,
                                              const float* __restrict__ be, const float* __restrict__ Wec,
                                              const float* __restrict__ wk_red, const float* __restrict__ wq_red,
                                              unsigned int* __restrict__ vb, float* __restrict__ r,
                                              float* __restrict__ ks4, float* __restrict__ qd4) {
    __shared__ float xs[64 * FD];    // 32 KB
    int tid = threadIdx.x;
    int base = blockIdx.x * 64;

    for (int p = 0; p < 8; ++p) {
        int rrow = p * 8 + (tid >> 5);
        int node = nperm[base + rrow];
        if (node < 0) node = 0;
        int c4 = tid & 31;
        float4 xv = *reinterpret_cast<const float4*>(x + (size_t)node * FD + 4 * c4);
        *reinterpret_cast<float4*>(&xs[rrow * FD + 4 * c4]) = xv;
    }
    __syncthreads();

    int g = tid >> 5;
    int c = tid & 31;
    int s0 = base + g * 8;
    int idx[8];
    unsigned wmask = 0;
    int t = -1;
#pragma unroll
    for (int m = 0; m < 8; ++m) {
        int nm = nperm[s0 + m];
        idx[m] = nm;
        if (nm >= 0) { wmask |= 1u << m; if (t < 0) t = ntype[nm]; }
    }
    if (t < 0) return;   // fully-padded group; no barriers after this point
#pragma unroll
    for (int m = 0; m < 8; ++m) if (idx[m] < 0) idx[m] = 0;

    const float* W = Wv + (size_t)t * FD * HIDD;
    float acc[8][4];
#pragma unroll
    for (int m = 0; m < 8; ++m) { acc[m][0] = acc[m][1] = acc[m][2] = acc[m][3] = 0.f; }

    const float* xrow = &xs[g * 8 * FD];
    for (int i0 = 0; i0 < FD; i0 += 4) {
        float4 w0 = *reinterpret_cast<const float4*>(W + (size_t)(i0 + 0) * HIDD + 4 * c);
        float4 w1 = *reinterpret_cast<const float4*>(W + (size_t)(i0 + 1) * HIDD + 4 * c);
        float4 w2 = *reinterpret_cast<const float4*>(W + (size_t)(i0 + 2) * HIDD + 4 * c);
        float4 w3 = *reinterpret_cast<const float4*>(W + (size_t)(i0 + 3) * HIDD + 4 * c);
        float4 xv[8];
#pragma unroll
        for (int m = 0; m < 8; ++m)
            xv[m] = *reinterpret_cast<const float4*>(xrow + m * FD + i0);
#pragma unroll
        for (int m = 0; m < 8; ++m) {
            acc[m][0] = fmaf(xv[m].x, w0.x, fmaf(xv[m].y, w1.x, fmaf(xv[m].z, w2.x, fmaf(xv[m].w, w3.x, acc[m][0]))));
            acc[m][1] = fmaf(xv[m].x, w0.y, fmaf(xv[m].y, w1.y, fmaf(xv[m].z, w2.y, fmaf(xv[m].w, w3.y, acc[m][1]))));
            acc[m][2] = fmaf(xv[m].x, w0.z, fmaf(xv[m].y, w1.z, fmaf(xv[m].z, w2.z, fmaf(xv[m].w, w3.z, acc[m][2]))));
            acc[m][3] = fmaf(xv[m].x, w0.w, fmaf(xv[m].y, w1.w, fmaf(xv[m].z, w2.w, fmaf(xv[m].w, w3.w, acc[m][3]))));
        }
    }
    // v store (bf16): lane c -> words 2c (dims 4c,4c+1), 2c+1 (dims 4c+2,4c+3)
#pragma unroll
    for (int m = 0; m < 8; ++m) {
        if (wmask & (1u << m)) {
            uint2 o;
            o.x = pack_bf16(acc[m][0], acc[m][1]);
            o.y = pack_bf16(acc[m][2], acc[m][3]);
            *reinterpret_cast<uint2*>(vb + (size_t)idx[m] * 64 + 2 * c) = o;
        }
    }
    // r table: r[n][t2][h] = sum_d relu(v+be)*Wec ; head = c>>3
#pragma unroll
    for (int t2 = 0; t2 < NET; ++t2) {
        float4 b4 = *reinterpret_cast<const float4*>(be + t2 * HIDD + 4 * c);
        float4 w4 = *reinterpret_cast<const float4*>(Wec + t2 * HIDD + 4 * c);
#pragma unroll
        for (int m = 0; m < 8; ++m) {
            float s = fmaxf(acc[m][0] + b4.x, 0.f) * w4.x
                    + fmaxf(acc[m][1] + b4.y, 0.f) * w4.y
                    + fmaxf(acc[m][2] + b4.z, 0.f) * w4.z
                    + fmaxf(acc[m][3] + b4.w, 0.f) * w4.w;
            s += __shfl_xor(s, 1, 64);
            s += __shfl_xor(s, 2, 64);
            s += __shfl_xor(s, 4, 64);
            if (((c & 7) == 0) && (wmask & (1u << m)))
                r[(size_t)idx[m] * (NET * NH) + t2 * NH + (c >> 3)] = s;
        }
    }
    // ks/qd (fused, x already in LDS): lane c -> node m=c>>2, quarter qq=c&3
    {
        int m = c >> 2, qq = c & 3;
        int node = nperm[s0 + m];
        const float* xq = &xs[(g * 8 + m) * FD];
        const float4* wkt = reinterpret_cast<const float4*>(wk_red + (size_t)t * FD * NH);
        const float4* wqt = reinterpret_cast<const float4*>(wq_red + (size_t)t * FD * NH);
        float ka0 = 0, ka1 = 0, ka2 = 0, ka3 = 0, qa0 = 0, qa1 = 0, qa2 = 0, qa3 = 0;
#pragma unroll
        for (int j = 0; j < 8; ++j) {
            int jj = (j + m) & 7;          // rotate chunks to spread LDS banks
            int dim = qq * 32 + jj * 4;
            float4 x4 = *reinterpret_cast<const float4*>(xq + dim);
            float4 k0w = wkt[dim], k1w = wkt[dim + 1], k2w = wkt[dim + 2], k3w = wkt[dim + 3];
            ka0 = fmaf(x4.x, k0w.x, fmaf(x4.y, k1w.x, fmaf(x4.z, k2w.x, fmaf(x4.w, k3w.x, ka0))));
            ka1 = fmaf(x4.x, k0w.y, fmaf(x4.y, k1w.y, fmaf(x4.z, k2w.y, fmaf(x4.w, k3w.y, ka1))));
            ka2 = fmaf(x4.x, k0w.z, fmaf(x4.y, k1w.z, fmaf(x4.z, k2w.z, fmaf(x4.w, k3w.z, ka2))));
            ka3 = fmaf(x4.x, k0w.w, fmaf(x4.y, k1w.w, fmaf(x4.z, k2w.w, fmaf(x4.w, k3w.w, ka3))));
            float4 q0w = wqt[dim], q1w = wqt[dim + 1], q2w = wqt[dim + 2], q3w = wqt[dim + 3];
            qa0 = fmaf(x4.x, q0w.x, fmaf(x4.y, q1w.x, fmaf(x4.z, q2w.x, fmaf(x4.w, q3w.x, qa0))));
            qa1 = fmaf(x4.x, q0w.y, fmaf(x4.y, q1w.y, fmaf(x4.z, q2w.y, fmaf(x4.w, q3w.y, qa1))));
            qa2 = fmaf(x4.x, q0w.z, fmaf(x4.y, q1w.z, fmaf(x4.z, q2w.z, fmaf(x4.w, q3w.z, qa2))));
            qa3 = fmaf(x4.x, q0w.w, fmaf(x4.y, q1w.w, fmaf(x4.z, q2w.w, fmaf(x4.w, q3w.w, qa3))));
        }
#pragma unroll
        for (int off = 1; off < 4; off <<= 1) {
            ka0 += __shfl_xor(ka0, off, 64); ka1 += __shfl_xor(ka1, off, 64);
            ka2 += __shfl_xor(ka2, off, 64); ka3 += __shfl_xor(ka3, off, 64);
            qa0 += __shfl_xor(qa0, off, 64); qa1 += __shfl_xor(qa1, off, 64);
            qa2 += __shfl_xor(qa2, off, 64); qa3 += __shfl_xor(qa3, off, 64);
        }
        if (qq == 0 && node >= 0) {
            float4 ko = {ka0, ka1, ka2, ka3};
            float4 qo = {qa0, qa1, qa2, qa3};
            *reinterpret_cast<float4*>(ks4 + (size_t)node * NH) = ko;
            *reinterpret_cast<float4*>(qd4 + (size_t)node * NH) = qo;
        }
    }
}

// ------------- main: softmax + aggregation + x_cls + fused e_cls -------------
__global__ __launch_bounds__(256) void k_main(const int* __restrict__ row_ptr, const int* __restrict__ ssrc,
                                              const int* __restrict__ sset, const int* __restrict__ seid,
                                              const float* __restrict__ ks4, const float* __restrict__ qd4,
                                              const float* __restrict__ etl, const unsigned int* __restrict__ vb,
                                              const float* __restrict__ be, const float* __restrict__ rtab,
                                              const float* __restrict__ bec, const float* __restrict__ Wn,
                                              const float* __restrict__ bn, const int* __restrict__ ntype,
                                              float* __restrict__ out_x, float* __restrict__ out_e) {
    int wave = threadIdx.x >> 6;
    int lane = threadIdx.x & 63;
    int n = blockIdx.x * 4 + wave;
    if (n >= NN) return;
    int rs = row_ptr[n], deg = row_ptr[n + 1] - rs;
    int hh = lane & 3;      // head for logit work
    int k0 = lane >> 2;     // edge slot 0..15
    int hv = lane >> 4;     // head owning v-dims [32*hv, 32*hv+32)

    float q = qd4[(size_t)n * NH + hh];

    bool act0 = k0 < deg;
    int pos0 = rs + (act0 ? k0 : 0);
    int s0r = 0, et0 = 0, eid0 = 0;
    float lg0 = -INFINITY;
    if (act0) {
        s0r = ssrc[pos0]; et0 = sset[pos0]; eid0 = seid[pos0];
        float l = ks4[(size_t)s0r * NH + hh] + q + etl[et0 * NH + hh];
        lg0 = l >= 0.f ? l : SLOPE * l;
    }
    float mx = lg0;
    if (deg > 16) {
        for (int bb = 16; bb < deg; bb += 16) {
            int kk = bb + k0;
            if (kk < deg) {
                int pos = rs + kk;
                int s = ssrc[pos], et = sset[pos];
                float l = ks4[(size_t)s * NH + hh] + q + etl[et * NH + hh];
                l = l >= 0.f ? l : SLOPE * l;
                mx = fmaxf(mx, l);
            }
        }
    }
#pragma unroll
    for (int off = 4; off < 64; off <<= 1) mx = fmaxf(mx, __shfl_xor(mx, off, 64));

    // denominator + per-etype exp sums
    float e0 = act0 ? __expf(lg0 - mx) : 0.f;
    float dn = e0;
    float P0 = (et0 == 0) ? e0 : 0.f;
    float P1 = (et0 == 1) ? e0 : 0.f;
    float P2 = (et0 == 2) ? e0 : 0.f;
    float P3 = (et0 == 3) ? e0 : 0.f;
    if (deg > 16) {
        for (int bb = 16; bb < deg; bb += 16) {
            int kk = bb + k0;
            if (kk < deg) {
                int pos = rs + kk;
                int s = ssrc[pos], et = sset[pos];
                float l = ks4[(size_t)s * NH + hh] + q + etl[et * NH + hh];
                l = l >= 0.f ? l : SLOPE * l;
                float ev = __expf(l - mx);
                dn += ev;
                P0 += (et == 0) ? ev : 0.f;
                P1 += (et == 1) ? ev : 0.f;
                P2 += (et == 2) ? ev : 0.f;
                P3 += (et == 3) ? ev : 0.f;
            }
        }
    }
#pragma unroll
    for (int off = 4; off < 64; off <<= 1) {
        dn += __shfl_xor(dn, off, 64);
        P0 += __shfl_xor(P0, off, 64);
        P1 += __shfl_xor(P1, off, 64);
        P2 += __shfl_xor(P2, off, 64);
        P3 += __shfl_xor(P3, off, 64);
    }
    float inv = 1.0f / (dn + 1e-16f);   // per-head (lane's hh)

    // fused e_cls: chunk 0 from registers
    if (act0) {
        float term = e0 * inv * rtab[((size_t)s0r * NET + et0) * NH + hh];
        term += __shfl_xor(term, 1, 64);
        term += __shfl_xor(term, 2, 64);
        if (hh == 0) out_e[eid0] = term + bec[et0];
    }
    if (deg > 16) {
        for (int bb = 16; bb < deg; bb += 16) {
            int kk = bb + k0;
            if (kk < deg) {
                int pos = rs + kk;
                int s = ssrc[pos], et = sset[pos], eid = seid[pos];
                float l = ks4[(size_t)s * NH + hh] + q + etl[et * NH + hh];
                l = l >= 0.f ? l : SLOPE * l;
                float term = __expf(l - mx) * inv * rtab[((size_t)s * NET + et) * NH + hh];
                term += __shfl_xor(term, 1, 64);
                term += __shfl_xor(term, 2, 64);
                if (hh == 0) out_e[eid] = term + bec[et];
            }
        }
    }

    float inv_v = __shfl(inv, hv, 64);
    float alpha0 = e0 * inv;

    // aggregation over bf16 v; sn via register shuffles
    float ax = 0.f, ay = 0.f;
    int cnt0 = deg < 16 ? deg : 16;
    for (int j = 0; j < cnt0; ++j) {
        float p = __shfl(alpha0, 4 * j + hv, 64);
        int sn = __shfl(s0r, 4 * j, 64);
        unsigned int w = vb[(size_t)sn * 64 + lane];
        ax = fmaf(p, __uint_as_float(w << 16), ax);
        ay = fmaf(p, __uint_as_float(w & 0xffff0000u), ay);
    }
    if (deg > 16) {
        for (int bb = 16; bb < deg; bb += 16) {
            int kk = bb + k0;
            float al = 0.f;
            int sr = 0;
            if (kk < deg) {
                int pos = rs + kk;
                sr = ssrc[pos];
                int et = sset[pos];
                float l = ks4[(size_t)sr * NH + hh] + q + etl[et * NH + hh];
                l = l >= 0.f ? l : SLOPE * l;
                al = __expf(l - mx) * inv;
            }
            int cnt = deg - bb; if (cnt > 16) cnt = 16;
            for (int j = 0; j < cnt; ++j) {
                float p = __shfl(al, 4 * j + hv, 64);
                int sn = __shfl(sr, 4 * j, 64);
                unsigned int w = vb[(size_t)sn * 64 + lane];
                ax = fmaf(p, __uint_as_float(w << 16), ax);
                ay = fmaf(p, __uint_as_float(w & 0xffff0000u), ay);
            }
        }
    }
    // factored be contribution
#pragma unroll
    for (int t2 = 0; t2 < NET; ++t2) {
        float Pt = (t2 == 0) ? P0 : (t2 == 1) ? P1 : (t2 == 2) ? P2 : P3;
        float A = __shfl(Pt, hv, 64) * inv_v;
        float2 b2 = *reinterpret_cast<const float2*>(be + t2 * HIDD + 2 * lane);
        ax = fmaf(A, b2.x, ax);
        ay = fmaf(A, b2.y, ay);
    }

    int t = ntype[n];
    float w0 = Wn[t * HIDD + 2 * lane];
    float w1 = Wn[t * HIDD + 2 * lane + 1];
    float s = fmaxf(ax, 0.f) * w0 + fmaxf(ay, 0.f) * w1;
#pragma unroll
    for (int off = 1; off < 64; off <<= 1) s += __shfl_xor(s, off, 64);
    if (lane == 0) out_x[n] = s + bn[t];
}

extern "C" void kernel_launch(void* const* d_in, const int* in_sizes, int n_in,
                              void* d_out, int out_size, void* d_ws, size_t ws_size,
                              hipStream_t stream) {
    const float* x        = (const float*)d_in[0];
    const int*   ei       = (const int*)d_in[1];
    const int*   ntype    = (const int*)d_in[2];
    const int*   etype    = (const int*)d_in[3];
    // d_in[4] edge_attr: unused (reference feeds zeros into the conv)
    const float* Wq       = (const float*)d_in[5];
    const float* Wk       = (const float*)d_in[6];
    const float* Wv       = (const float*)d_in[7];
    const float* att_src  = (const float*)d_in[8];
    const float* att_dst  = (const float*)d_in[9];
    const float* att_edge = (const float*)d_in[10];
    // d_in[11] We: unused (multiplied by zero edge_attr)
    const float* be       = (const float*)d_in[12];
    const float* Wn       = (const float*)d_in[13];
    const float* bn       = (const float*)d_in[14];
    const float* Wec      = (const float*)d_in[15];
    const float* bec      = (const float*)d_in[16];

    char* ws = (char*)d_ws;
    unsigned int* vb = (unsigned int*)(ws + OFF_V);
    float* ks4     = (float*)(ws + OFF_KS);
    float* qd4     = (float*)(ws + OFF_QD);
    float* rtab    = (float*)(ws + OFF_R);
    int*   counts  = (int*)(ws + OFF_COUNTS);
    int*   ncnt    = (int*)(ws + OFF_NCNT);
    int*   ncur    = (int*)(ws + OFF_NCUR);
    int*   row_ptr = (int*)(ws + OFF_ROWPTR);
    int*   cursor  = (int*)(ws + OFF_CURSOR);
    int*   incl    = (int*)(ws + OFF_INCL);
    int*   bsums   = (int*)(ws + OFF_BSUMS);
    int*   ssrc    = (int*)(ws + OFF_SSRC);
    int*   sset    = (int*)(ws + OFF_SET);
    int*   seid    = (int*)(ws + OFF_SEID);
    float* wk_red  = (float*)(ws + OFF_WKRED);
    float* wq_red  = (float*)(ws + OFF_WQRED);
    float* etl     = (float*)(ws + OFF_ETL);
    int*   nbase   = (int*)(ws + OFF_NBASE);
    int*   nperm   = (int*)(ws + OFF_NPERM);

    float* out_x = (float*)d_out;
    float* out_e = (float*)d_out + NN;

    k_init<<<(NN + 96 + 255) / 256, 256, 0, stream>>>(counts, ncnt, nperm);
    k_pre<<<7, 256, 0, stream>>>(Wq, Wk, att_src, att_dst, be, att_edge, wk_red, wq_red, etl);
    k_count<<<(NE + 255) / 256, 256, 0, stream>>>(ei, counts);
    k_scan1<<<49, 256, 0, stream>>>(counts, incl, bsums);
    k_scan2<<<1, 64, 0, stream>>>(bsums, 49);
    k_scan3<<<(NN + 255) / 256, 256, 0, stream>>>(counts, incl, bsums, row_ptr, cursor, ntype, ncnt);
    k_nbase<<<1, 64, 0, stream>>>(ncnt, nbase, ncur);
    k_fill<<<(NE + 255) / 256, 256, 0, stream>>>(ei, etype, cursor, ssrc, sset, seid);
    k_nscatter<<<(NN + 255) / 256, 256, 0, stream>>>(ntype, nbase, ncur, nperm);
    k_node<<<1564, 256, 0, stream>>>(x, Wv, ntype, nperm, be, Wec, wk_red, wq_red,
                                     vb, rtab, ks4, qd4);
    k_main<<<(NN + 3) / 4, 256, 0, stream>>>(row_ptr, ssrc, sset, seid, ks4, qd4, etl, vb, be,
                                             rtab, bec, Wn, bn, ntype, out_x, out_e);
}

// Round 5
// 336.034 us; speedup vs baseline: 1.6183x; 1.0326x over previous
//
#include <hip/hip_runtime.h>
#include <hip/hip_bf16.h>

// HATGNN forward.
// Pipeline: k_init -> k_pre (reduced weights + Wv bf16 fragment pack) -> CSR build
//   -> k_nscatter (type sort, padded to 16) -> k_xcast (x->bf16 + ks/qd)
//   -> k_node (v GEMV via MFMA, bf16) -> k_r (r table) -> k_main (softmax+agg+x_cls+e_cls).
// Key ideas: e_emb == be[etype] (edge_attr zeroed in reference); q/k fold into per-type
// reduced weights; e_cls = sum_h alpha*r[src,et,h] (alpha>=0 commutes with relu);
// be-term of x_out factored out via per-etype exp sums; v GEMV on matrix cores.

#define NN 100000
#define NE 600000
#define FD 128
#define HIDD 128
#define NH 4
#define DH 32
#define NT 3
#define NET 4
#define SLOPE 0.2f

typedef short bf16x8 __attribute__((ext_vector_type(8)));
typedef float f32x4 __attribute__((ext_vector_type(4)));

// ---------------- ws layout (bytes) ----------------
#define OFF_V       0UL            // N*128 bf16     25,600,000
#define OFF_XB      25600000UL     // N*128 bf16     25,600,000
#define OFF_KS      51200000UL     // N*4 f32         1,600,000
#define OFF_QD      52800000UL     // N*4 f32         1,600,000
#define OFF_R       54400000UL     // N*16 f32        6,400,000
#define OFF_COUNTS  60800000UL     // N int             400,000
#define OFF_NCNT    61200000UL     // 4 int
#define OFF_NCUR    61200016UL     // 4 int
#define OFF_ROWPTR  61200128UL     // (N+1) int
#define OFF_CURSOR  61600256UL     // N int
#define OFF_INCL    62000256UL     // N int
#define OFF_BSUMS   62400256UL     // 64 int
#define OFF_SSRC    62400512UL     // E int
#define OFF_SET     64800512UL     // E int
#define OFF_SEID    67200512UL     // E int
#define OFF_WKRED   69600512UL     // 3*128*4 f32
#define OFF_WQRED   69606656UL
#define OFF_ETL     69612800UL     // 4*4 f32
#define OFF_NBASE   69612928UL
#define OFF_NPERM   69613056UL     // (N+96) int
#define OFF_WPACK   70013440UL     // 3*8*4*64*8 bf16 = 196,608 B

__device__ __forceinline__ unsigned int pack_bf16(float a, float b) {
    __hip_bfloat16 ha = __float2bfloat16(a);
    __hip_bfloat16 hb = __float2bfloat16(b);
    unsigned short ua = *reinterpret_cast<unsigned short*>(&ha);
    unsigned short ub = *reinterpret_cast<unsigned short*>(&hb);
    return (unsigned int)ua | ((unsigned int)ub << 16);
}

// ------------- init -------------
__global__ void k_init(int* __restrict__ counts, int* __restrict__ ncnt, int* __restrict__ nperm) {
    int i = blockIdx.x * blockDim.x + threadIdx.x;
    if (i < NN) counts[i] = 0;
    if (i < NN + 96) nperm[i] = -1;
    if (i < NT) ncnt[i] = 0;
}

// ------------- precompute: reduced weights + etl + Wv bf16 fragment pack -------------
// Wpack[t][ot][kc][lane][j] = bf16(Wv[t][k = kc*32+(lane>>4)*8+j][o = ot*16+(lane&15)])
#define PACK_BASE 1600
__global__ void k_pre(const float* __restrict__ Wq, const float* __restrict__ Wk,
                      const float* __restrict__ Wv,
                      const float* __restrict__ att_src, const float* __restrict__ att_dst,
                      const float* __restrict__ be, const float* __restrict__ att_edge,
                      float* __restrict__ wk_red, float* __restrict__ wq_red, float* __restrict__ etl,
                      unsigned int* __restrict__ wpack) {
    int gid = blockIdx.x * blockDim.x + threadIdx.x;
    if (gid < NT * FD * NH) {
        int h = gid % NH;
        int i = (gid / NH) % FD;
        int t = gid / (NH * FD);
        const float* wkp = Wk + ((size_t)t * FD + i) * HIDD + h * DH;
        const float* wqp = Wq + ((size_t)t * FD + i) * HIDD + h * DH;
        const float* as = att_src + h * DH;
        const float* ad = att_dst + h * DH;
        float sk = 0.f, sq = 0.f;
        for (int d = 0; d < DH; ++d) { sk += wkp[d] * as[d]; sq += wqp[d] * ad[d]; }
        wk_red[gid] = sk;   // layout [t][i][h]
        wq_red[gid] = sq;
    } else if (gid < NT * FD * NH + NET * NH) {
        int rdx = gid - NT * FD * NH;
        int h = rdx % NH;
        int t = rdx / NH;
        float s = 0.f;
        for (int d = 0; d < DH; ++d) s += be[t * HIDD + h * DH + d] * att_edge[h * DH + d];
        etl[rdx] = s;       // layout [t][h]
    } else if (gid >= PACK_BASE && gid < PACK_BASE + NT * 8 * 4 * 64) {
        int q = gid - PACK_BASE;
        int t = q >> 11;
        int rem = q & 2047;
        int ot = rem >> 8;
        int rem2 = rem & 255;
        int kc = rem2 >> 6;
        int l = rem2 & 63;
        int o = ot * 16 + (l & 15);
        int kb = kc * 32 + (l >> 4) * 8;
        unsigned int w[4];
#pragma unroll
        for (int jj = 0; jj < 4; ++jj) {
            float v0 = Wv[((size_t)t * FD + kb + 2 * jj) * HIDD + o];
            float v1 = Wv[((size_t)t * FD + kb + 2 * jj + 1) * HIDD + o];
            w[jj] = pack_bf16(v0, v1);
        }
        uint4 o4 = {w[0], w[1], w[2], w[3]};
        *reinterpret_cast<uint4*>(wpack + (size_t)q * 4) = o4;
    }
}

// ------------- CSR build -------------
__global__ void k_count(const int* __restrict__ ei, int* __restrict__ counts) {
    int e = blockIdx.x * blockDim.x + threadIdx.x;
    if (e < NE) atomicAdd(&counts[ei[NE + e]], 1);
}

__global__ void k_scan1(const int* __restrict__ counts, int* __restrict__ incl, int* __restrict__ bsums) {
    __shared__ int lds[2048];
    int base = blockIdx.x * 2048;
    for (int k = threadIdx.x; k < 2048; k += 256)
        lds[k] = (base + k < NN) ? counts[base + k] : 0;
    __syncthreads();
    for (int off = 1; off < 2048; off <<= 1) {
        int vals[8];
        for (int j = 0; j < 8; ++j) {
            int k = threadIdx.x + j * 256;
            vals[j] = (k >= off) ? lds[k - off] : 0;
        }
        __syncthreads();
        for (int j = 0; j < 8; ++j) {
            int k = threadIdx.x + j * 256;
            lds[k] += vals[j];
        }
        __syncthreads();
    }
    for (int k = threadIdx.x; k < 2048; k += 256)
        if (base + k < NN) incl[base + k] = lds[k];
    if (threadIdx.x == 0) bsums[blockIdx.x] = lds[2047];
}

__global__ void k_scan2(int* __restrict__ bsums, int nb) {
    if (threadIdx.x == 0) {
        int run = 0;
        for (int i = 0; i < nb; ++i) { int vv = bsums[i]; bsums[i] = run; run += vv; }
    }
}

__global__ void k_scan3(const int* __restrict__ counts, const int* __restrict__ incl,
                        const int* __restrict__ bsums, int* __restrict__ row_ptr, int* __restrict__ cursor,
                        const int* __restrict__ ntype, int* __restrict__ ncnt) {
    __shared__ int c[NT];
    if (threadIdx.x < NT) c[threadIdx.x] = 0;
    __syncthreads();
    int i = blockIdx.x * blockDim.x + threadIdx.x;
    if (i < NN) {
        int ex = incl[i] - counts[i] + bsums[i / 2048];
        row_ptr[i] = ex;
        cursor[i] = ex;
        atomicAdd(&c[ntype[i]], 1);
    }
    if (i == 0) row_ptr[NN] = NE;
    __syncthreads();
    if (threadIdx.x < NT) atomicAdd(&ncnt[threadIdx.x], c[threadIdx.x]);
}

// pad each type block to 16 so every 16-node MFMA tile is type-uniform
__global__ void k_nbase(const int* __restrict__ ncnt, int* __restrict__ nbase, int* __restrict__ ncur) {
    if (threadIdx.x == 0) {
        int b = 0;
        for (int t = 0; t < NT; ++t) {
            nbase[t] = b;
            ncur[t] = 0;
            b += (ncnt[t] + 15) & ~15;
        }
        nbase[NT] = b;
    }
}

__global__ void k_fill(const int* __restrict__ ei, const int* __restrict__ etype, int* __restrict__ cursor,
                       int* __restrict__ ssrc, int* __restrict__ sset, int* __restrict__ seid) {
    int e = blockIdx.x * blockDim.x + threadIdx.x;
    if (e >= NE) return;
    int dst = ei[NE + e];
    int pos = atomicAdd(&cursor[dst], 1);
    ssrc[pos] = ei[e];
    sset[pos] = etype[e];
    seid[pos] = e;
}

__global__ void k_nscatter(const int* __restrict__ ntype, const int* __restrict__ nbase,
                           int* __restrict__ ncur, int* __restrict__ nperm) {
    int n = blockIdx.x * blockDim.x + threadIdx.x;
    if (n >= NN) return;
    int tt = ntype[n];
    int lane = threadIdx.x & 63;
    for (int t = 0; t < NT; ++t) {
        unsigned long long m = __ballot(tt == t);
        if (tt == t) {
            int rank = __popcll(m & ((1ull << lane) - 1ull));
            int leader = __ffsll((unsigned long long)m) - 1;
            int base = 0;
            if (lane == leader) base = atomicAdd(&ncur[t], (int)__popcll(m));
            base = __shfl(base, leader, 64);
            nperm[nbase[t] + base + rank] = n;
        }
    }
}

// ------------- x -> bf16 cast, fused ks/qd (4 lanes per node) -------------
__global__ __launch_bounds__(256) void k_xcast(const float* __restrict__ x, const int* __restrict__ ntype,
                                               const float* __restrict__ wk_red, const float* __restrict__ wq_red,
                                               unsigned short* __restrict__ xb,
                                               float* __restrict__ ks4, float* __restrict__ qd4) {
    int tid = threadIdx.x;
    int n = blockIdx.x * 64 + (tid >> 2);
    if (n >= NN) return;
    int j = tid & 3;                 // owns input dims [32j, 32j+32)
    int t = ntype[n];
    const float* xr = x + (size_t)n * FD + j * 32;
    const float* wk = wk_red + ((size_t)t * FD + j * 32) * NH;
    const float* wq = wq_red + ((size_t)t * FD + j * 32) * NH;
    float ka0 = 0, ka1 = 0, ka2 = 0, ka3 = 0, qa0 = 0, qa1 = 0, qa2 = 0, qa3 = 0;
    unsigned int ob[16];
#pragma unroll
    for (int ii = 0; ii < 32; ii += 4) {
        float4 x4 = *reinterpret_cast<const float4*>(xr + ii);
        ob[ii / 2] = pack_bf16(x4.x, x4.y);
        ob[ii / 2 + 1] = pack_bf16(x4.z, x4.w);
        float4 wk0 = *reinterpret_cast<const float4*>(wk + (ii + 0) * NH);
        float4 wk1 = *reinterpret_cast<const float4*>(wk + (ii + 1) * NH);
        float4 wk2 = *reinterpret_cast<const float4*>(wk + (ii + 2) * NH);
        float4 wk3 = *reinterpret_cast<const float4*>(wk + (ii + 3) * NH);
        float4 wq0 = *reinterpret_cast<const float4*>(wq + (ii + 0) * NH);
        float4 wq1 = *reinterpret_cast<const float4*>(wq + (ii + 1) * NH);
        float4 wq2 = *reinterpret_cast<const float4*>(wq + (ii + 2) * NH);
        float4 wq3 = *reinterpret_cast<const float4*>(wq + (ii + 3) * NH);
        ka0 = fmaf(x4.x, wk0.x, fmaf(x4.y, wk1.x, fmaf(x4.z, wk2.x, fmaf(x4.w, wk3.x, ka0))));
        ka1 = fmaf(x4.x, wk0.y, fmaf(x4.y, wk1.y, fmaf(x4.z, wk2.y, fmaf(x4.w, wk3.y, ka1))));
        ka2 = fmaf(x4.x, wk0.z, fmaf(x4.y, wk1.z, fmaf(x4.z, wk2.z, fmaf(x4.w, wk3.z, ka2))));
        ka3 = fmaf(x4.x, wk0.w, fmaf(x4.y, wk1.w, fmaf(x4.z, wk2.w, fmaf(x4.w, wk3.w, ka3))));
        qa0 = fmaf(x4.x, wq0.x, fmaf(x4.y, wq1.x, fmaf(x4.z, wq2.x, fmaf(x4.w, wq3.x, qa0))));
        qa1 = fmaf(x4.x, wq0.y, fmaf(x4.y, wq1.y, fmaf(x4.z, wq2.y, fmaf(x4.w, wq3.y, qa1))));
        qa2 = fmaf(x4.x, wq0.z, fmaf(x4.y, wq1.z, fmaf(x4.z, wq2.z, fmaf(x4.w, wq3.z, qa2))));
        qa3 = fmaf(x4.x, wq0.w, fmaf(x4.y, wq1.w, fmaf(x4.z, wq2.w, fmaf(x4.w, wq3.w, qa3))));
    }
    uint4* dst = reinterpret_cast<uint4*>(xb + (size_t)n * FD + j * 32);
    uint4 o0 = {ob[0], ob[1], ob[2], ob[3]};
    uint4 o1 = {ob[4], ob[5], ob[6], ob[7]};
    uint4 o2 = {ob[8], ob[9], ob[10], ob[11]};
    uint4 o3 = {ob[12], ob[13], ob[14], ob[15]};
    dst[0] = o0; dst[1] = o1; dst[2] = o2; dst[3] = o3;
#pragma unroll
    for (int off = 1; off < 4; off <<= 1) {
        ka0 += __shfl_xor(ka0, off, 64); ka1 += __shfl_xor(ka1, off, 64);
        ka2 += __shfl_xor(ka2, off, 64); ka3 += __shfl_xor(ka3, off, 64);
        qa0 += __shfl_xor(qa0, off, 64); qa1 += __shfl_xor(qa1, off, 64);
        qa2 += __shfl_xor(qa2, off, 64); qa3 += __shfl_xor(qa3, off, 64);
    }
    if (j == 0) {
        float4 ko = {ka0, ka1, ka2, ka3};
        *reinterpret_cast<float4*>(ks4 + (size_t)n * NH) = ko;
    } else if (j == 1) {
        float4 qo = {qa0, qa1, qa2, qa3};
        *reinterpret_cast<float4*>(qd4 + (size_t)n * NH) = qo;
    }
}

// ------------- v = x @ Wv[type] on matrix cores -------------
// Wave handles 16 same-type nodes (perm slots base..base+15), full 128 output dims.
// A: row = lane&15 (node), k = (lane>>4)*8 + j.  B: col = lane&15 (out dim), same k.
// D: col = lane&15 (out dim), row = (lane>>4)*4 + r (node).
__global__ __launch_bounds__(256) void k_node(const unsigned short* __restrict__ xb,
                                              const unsigned short* __restrict__ wpack,
                                              const int* __restrict__ ntype, const int* __restrict__ nperm,
                                              unsigned short* __restrict__ vb) {
    int wave = threadIdx.x >> 6, lane = threadIdx.x & 63;
    int base = blockIdx.x * 64 + wave * 16;
    int n0 = nperm[base];
    if (n0 < 0) return;                      // fully padded tile
    int t = ntype[n0];
    int an = nperm[base + (lane & 15)];
    if (an < 0) an = 0;                      // pad row: dummy read, masked store
    int kg = lane >> 4;
    bf16x8 a[4];
#pragma unroll
    for (int kc = 0; kc < 4; ++kc)
        a[kc] = *reinterpret_cast<const bf16x8*>(xb + (size_t)an * FD + kc * 32 + kg * 8);
    int dn[4];
#pragma unroll
    for (int r = 0; r < 4; ++r) dn[r] = nperm[base + kg * 4 + r];
    const unsigned short* wt = wpack + (size_t)t * 8 * 4 * 64 * 8;
#pragma unroll
    for (int ot = 0; ot < 8; ++ot) {
        f32x4 acc = {0.f, 0.f, 0.f, 0.f};
#pragma unroll
        for (int kc = 0; kc < 4; ++kc) {
            bf16x8 b = *reinterpret_cast<const bf16x8*>(wt + ((size_t)(ot * 4 + kc) * 64 + lane) * 8);
            acc = __builtin_amdgcn_mfma_f32_16x16x32_bf16(a[kc], b, acc, 0, 0, 0);
        }
#pragma unroll
        for (int r = 0; r < 4; ++r) {
            if (dn[r] >= 0) {
                __hip_bfloat16 hv = __float2bfloat16(acc[r]);
                vb[(size_t)dn[r] * FD + ot * 16 + (lane & 15)] = *reinterpret_cast<unsigned short*>(&hv);
            }
        }
    }
}

// ------------- r table: r[n][t2][h] = sum_d relu(v+be)*Wec -------------
// 16 lanes per node; lane j owns dims 8j..8j+7 (head h = j>>2).
__global__ __launch_bounds__(256) void k_r(const unsigned short* __restrict__ vb, const float* __restrict__ be,
                                           const float* __restrict__ Wec, float* __restrict__ r) {
    int tid = threadIdx.x;
    int n = blockIdx.x * 16 + (tid >> 4);
    if (n >= NN) return;
    int j = tid & 15;
    uint4 raw = *reinterpret_cast<const uint4*>(vb + (size_t)n * FD + j * 8);
    float vv[8];
    vv[0] = __uint_as_float(raw.x << 16); vv[1] = __uint_as_float(raw.x & 0xffff0000u);
    vv[2] = __uint_as_float(raw.y << 16); vv[3] = __uint_as_float(raw.y & 0xffff0000u);
    vv[4] = __uint_as_float(raw.z << 16); vv[5] = __uint_as_float(raw.z & 0xffff0000u);
    vv[6] = __uint_as_float(raw.w << 16); vv[7] = __uint_as_float(raw.w & 0xffff0000u);
    int h = j >> 2;
#pragma unroll
    for (int t2 = 0; t2 < NET; ++t2) {
        float4 b0 = *reinterpret_cast<const float4*>(be + t2 * HIDD + j * 8);
        float4 b1 = *reinterpret_cast<const float4*>(be + t2 * HIDD + j * 8 + 4);
        float4 w0 = *reinterpret_cast<const float4*>(Wec + t2 * HIDD + j * 8);
        float4 w1 = *reinterpret_cast<const float4*>(Wec + t2 * HIDD + j * 8 + 4);
        float s = fmaxf(vv[0] + b0.x, 0.f) * w0.x + fmaxf(vv[1] + b0.y, 0.f) * w0.y
                + fmaxf(vv[2] + b0.z, 0.f) * w0.z + fmaxf(vv[3] + b0.w, 0.f) * w0.w
                + fmaxf(vv[4] + b1.x, 0.f) * w1.x + fmaxf(vv[5] + b1.y, 0.f) * w1.y
                + fmaxf(vv[6] + b1.z, 0.f) * w1.z + fmaxf(vv[7] + b1.w, 0.f) * w1.w;
        s += __shfl_xor(s, 1, 64);
        s += __shfl_xor(s, 2, 64);
        if ((j & 3) == 0) r[(size_t)n * (NET * NH) + t2 * NH + h] = s;
    }
}

// ------------- main: softmax + aggregation + x_cls + fused e_cls -------------
__global__ __launch_bounds__(256) void k_main(const int* __restrict__ row_ptr, const int* __restrict__ ssrc,
                                              const int* __restrict__ sset, const int* __restrict__ seid,
                                              const float* __restrict__ ks4, const float* __restrict__ qd4,
                                              const float* __restrict__ etl, const unsigned int* __restrict__ vb,
                                              const float* __restrict__ be, const float* __restrict__ rtab,
                                              const float* __restrict__ bec, const float* __restrict__ Wn,
                                              const float* __restrict__ bn, const int* __restrict__ ntype,
                                              float* __restrict__ out_x, float* __restrict__ out_e) {
    int wave = threadIdx.x >> 6;
    int lane = threadIdx.x & 63;
    int n = blockIdx.x * 4 + wave;
    if (n >= NN) return;
    int rs = row_ptr[n], deg = row_ptr[n + 1] - rs;
    int hh = lane & 3;
    int k0 = lane >> 2;
    int hv = lane >> 4;

    float q = qd4[(size_t)n * NH + hh];

    bool act0 = k0 < deg;
    int pos0 = rs + (act0 ? k0 : 0);
    int s0r = 0, et0 = 0, eid0 = 0;
    float lg0 = -INFINITY;
    if (act0) {
        s0r = ssrc[pos0]; et0 = sset[pos0]; eid0 = seid[pos0];
        float l = ks4[(size_t)s0r * NH + hh] + q + etl[et0 * NH + hh];
        lg0 = l >= 0.f ? l : SLOPE * l;
    }
    float mx = lg0;
    if (deg > 16) {
        for (int bb = 16; bb < deg; bb += 16) {
            int kk = bb + k0;
            if (kk < deg) {
                int pos = rs + kk;
                int s = ssrc[pos], et = sset[pos];
                float l = ks4[(size_t)s * NH + hh] + q + etl[et * NH + hh];
                l = l >= 0.f ? l : SLOPE * l;
                mx = fmaxf(mx, l);
            }
        }
    }
#pragma unroll
    for (int off = 4; off < 64; off <<= 1) mx = fmaxf(mx, __shfl_xor(mx, off, 64));

    float e0 = act0 ? __expf(lg0 - mx) : 0.f;
    float dn = e0;
    float P0 = (et0 == 0) ? e0 : 0.f;
    float P1 = (et0 == 1) ? e0 : 0.f;
    float P2 = (et0 == 2) ? e0 : 0.f;
    float P3 = (et0 == 3) ? e0 : 0.f;
    if (deg > 16) {
        for (int bb = 16; bb < deg; bb += 16) {
            int kk = bb + k0;
            if (kk < deg) {
                int pos = rs + kk;
                int s = ssrc[pos], et = sset[pos];
                float l = ks4[(size_t)s * NH + hh] + q + etl[et * NH + hh];
                l = l >= 0.f ? l : SLOPE * l;
                float ev = __expf(l - mx);
                dn += ev;
                P0 += (et == 0) ? ev : 0.f;
                P1 += (et == 1) ? ev : 0.f;
                P2 += (et == 2) ? ev : 0.f;
                P3 += (et == 3) ? ev : 0.f;
            }
        }
    }
#pragma unroll
    for (int off = 4; off < 64; off <<= 1) {
        dn += __shfl_xor(dn, off, 64);
        P0 += __shfl_xor(P0, off, 64);
        P1 += __shfl_xor(P1, off, 64);
        P2 += __shfl_xor(P2, off, 64);
        P3 += __shfl_xor(P3, off, 64);
    }
    float inv = 1.0f / (dn + 1e-16f);

    if (act0) {
        float term = e0 * inv * rtab[((size_t)s0r * NET + et0) * NH + hh];
        term += __shfl_xor(term, 1, 64);
        term += __shfl_xor(term, 2, 64);
        if (hh == 0) out_e[eid0] = term + bec[et0];
    }
    if (deg > 16) {
        for (int bb = 16; bb < deg; bb += 16) {
            int kk = bb + k0;
            if (kk < deg) {
                int pos = rs + kk;
                int s = ssrc[pos], et = sset[pos], eid = seid[pos];
                float l = ks4[(size_t)s * NH + hh] + q + etl[et * NH + hh];
                l = l >= 0.f ? l : SLOPE * l;
                float term = __expf(l - mx) * inv * rtab[((size_t)s * NET + et) * NH + hh];
                term += __shfl_xor(term, 1, 64);
                term += __shfl_xor(term, 2, 64);
                if (hh == 0) out_e[eid] = term + bec[et];
            }
        }
    }

    float inv_v = __shfl(inv, hv, 64);
    float alpha0 = e0 * inv;

    float ax = 0.f, ay = 0.f;
    int cnt0 = deg < 16 ? deg : 16;
    for (int j = 0; j < cnt0; ++j) {
        float p = __shfl(alpha0, 4 * j + hv, 64);
        int sn = __shfl(s0r, 4 * j, 64);
        unsigned int w = vb[(size_t)sn * 64 + lane];
        ax = fmaf(p, __uint_as_float(w << 16), ax);
        ay = fmaf(p, __uint_as_float(w & 0xffff0000u), ay);
    }
    if (deg > 16) {
        for (int bb = 16; bb < deg; bb += 16) {
            int kk = bb + k0;
            float al = 0.f;
            int sr = 0;
            if (kk < deg) {
                int pos = rs + kk;
                sr = ssrc[pos];
                int et = sset[pos];
                float l = ks4[(size_t)sr * NH + hh] + q + etl[et * NH + hh];
                l = l >= 0.f ? l : SLOPE * l;
                al = __expf(l - mx) * inv;
            }
            int cnt = deg - bb; if (cnt > 16) cnt = 16;
            for (int j = 0; j < cnt; ++j) {
                float p = __shfl(al, 4 * j + hv, 64);
                int sn = __shfl(sr, 4 * j, 64);
                unsigned int w = vb[(size_t)sn * 64 + lane];
                ax = fmaf(p, __uint_as_float(w << 16), ax);
                ay = fmaf(p, __uint_as_float(w & 0xffff0000u), ay);
            }
        }
    }
#pragma unroll
    for (int t2 = 0; t2 < NET; ++t2) {
        float Pt = (t2 == 0) ? P0 : (t2 == 1) ? P1 : (t2 == 2) ? P2 : P3;
        float A = __shfl(Pt, hv, 64) * inv_v;
        float2 b2 = *reinterpret_cast<const float2*>(be + t2 * HIDD + 2 * lane);
        ax = fmaf(A, b2.x, ax);
        ay = fmaf(A, b2.y, ay);
    }

    int t = ntype[n];
    float w0 = Wn[t * HIDD + 2 * lane];
    float w1 = Wn[t * HIDD + 2 * lane + 1];
    float s = fmaxf(ax, 0.f) * w0 + fmaxf(ay, 0.f) * w1;
#pragma unroll
    for (int off = 1; off < 64; off <<= 1) s += __shfl_xor(s, off, 64);
    if (lane == 0) out_x[n] = s + bn[t];
}

extern "C" void kernel_launch(void* const* d_in, const int* in_sizes, int n_in,
                              void* d_out, int out_size, void* d_ws, size_t ws_size,
                              hipStream_t stream) {
    const float* x        = (const float*)d_in[0];
    const int*   ei       = (const int*)d_in[1];
    const int*   ntype    = (const int*)d_in[2];
    const int*   etype    = (const int*)d_in[3];
    // d_in[4] edge_attr: unused (reference feeds zeros into the conv)
    const float* Wq       = (const float*)d_in[5];
    const float* Wk       = (const float*)d_in[6];
    const float* Wv       = (const float*)d_in[7];
    const float* att_src  = (const float*)d_in[8];
    const float* att_dst  = (const float*)d_in[9];
    const float* att_edge = (const float*)d_in[10];
    // d_in[11] We: unused (multiplied by zero edge_attr)
    const float* be       = (const float*)d_in[12];
    const float* Wn       = (const float*)d_in[13];
    const float* bn       = (const float*)d_in[14];
    const float* Wec      = (const float*)d_in[15];
    const float* bec      = (const float*)d_in[16];

    char* ws = (char*)d_ws;
    unsigned int*   vb32 = (unsigned int*)(ws + OFF_V);
    unsigned short* vb16 = (unsigned short*)(ws + OFF_V);
    unsigned short* xb   = (unsigned short*)(ws + OFF_XB);
    float* ks4     = (float*)(ws + OFF_KS);
    float* qd4     = (float*)(ws + OFF_QD);
    float* rtab    = (float*)(ws + OFF_R);
    int*   counts  = (int*)(ws + OFF_COUNTS);
    int*   ncnt    = (int*)(ws + OFF_NCNT);
    int*   ncur    = (int*)(ws + OFF_NCUR);
    int*   row_ptr = (int*)(ws + OFF_ROWPTR);
    int*   cursor  = (int*)(ws + OFF_CURSOR);
    int*   incl    = (int*)(ws + OFF_INCL);
    int*   bsums   = (int*)(ws + OFF_BSUMS);
    int*   ssrc    = (int*)(ws + OFF_SSRC);
    int*   sset    = (int*)(ws + OFF_SET);
    int*   seid    = (int*)(ws + OFF_SEID);
    float* wk_red  = (float*)(ws + OFF_WKRED);
    float* wq_red  = (float*)(ws + OFF_WQRED);
    float* etl     = (float*)(ws + OFF_ETL);
    int*   nbase   = (int*)(ws + OFF_NBASE);
    int*   nperm   = (int*)(ws + OFF_NPERM);
    unsigned int* wpack = (unsigned int*)(ws + OFF_WPACK);

    float* out_x = (float*)d_out;
    float* out_e = (float*)d_out + NN;

    k_init<<<(NN + 96 + 255) / 256, 256, 0, stream>>>(counts, ncnt, nperm);
    k_pre<<<31, 256, 0, stream>>>(Wq, Wk, Wv, att_src, att_dst, be, att_edge,
                                  wk_red, wq_red, etl, wpack);
    k_count<<<(NE + 255) / 256, 256, 0, stream>>>(ei, counts);
    k_scan1<<<49, 256, 0, stream>>>(counts, incl, bsums);
    k_scan2<<<1, 64, 0, stream>>>(bsums, 49);
    k_scan3<<<(NN + 255) / 256, 256, 0, stream>>>(counts, incl, bsums, row_ptr, cursor, ntype, ncnt);
    k_nbase<<<1, 64, 0, stream>>>(ncnt, nbase, ncur);
    k_fill<<<(NE + 255) / 256, 256, 0, stream>>>(ei, etype, cursor, ssrc, sset, seid);
    k_nscatter<<<(NN + 255) / 256, 256, 0, stream>>>(ntype, nbase, ncur, nperm);
    k_xcast<<<(NN + 63) / 64, 256, 0, stream>>>(x, ntype, wk_red, wq_red, xb, ks4, qd4);
    k_node<<<(NN + 96) / 64, 256, 0, stream>>>(xb, (const unsigned short*)wpack, ntype, nperm, vb16);
    k_r<<<(NN + 15) / 16, 256, 0, stream>>>(vb16, be, Wec, rtab);
    k_main<<<(NN + 3) / 4, 256, 0, stream>>>(row_ptr, ssrc, sset, seid, ks4, qd4, etl, vb32, be,
                                             rtab, bec, Wn, bn, ntype, out_x, out_e);
}

// Round 6
// 291.227 us; speedup vs baseline: 1.8673x; 1.1539x over previous
//
#include <hip/hip_runtime.h>
#include <hip/hip_bf16.h>

// HATGNN forward.
// Pipeline: memset(ncnt) -> k_init(+ntype hist) -> k_pre -> k_count -> k_scan1 ->
//   k_scan2(+nbase) -> k_scan3 -> k_fill -> k_nscatter ->
//   k_node (x->bf16 + MFMA v-GEMV + ks/qd + r table, all fused) ->
//   k_main (softmax + aggregation + x_cls + fused e_cls).
// Key ideas: e_emb == be[etype] (edge_attr zeroed in reference); q/k fold into per-type
// reduced weights; e_cls = sum_h alpha*r[src,et,h] (alpha>=0 commutes with relu);
// v GEMV on matrix cores; CSR edge record packed to 8B.

#define NN 100000
#define NE 600000
#define FD 128
#define HIDD 128
#define NH 4
#define DH 32
#define NT 3
#define NET 4
#define SLOPE 0.2f

typedef short bf16x8 __attribute__((ext_vector_type(8)));
typedef float f32x4 __attribute__((ext_vector_type(4)));

// ---------------- ws layout (bytes) ----------------
#define OFF_V       0UL            // N*128 bf16     25,600,000
#define OFF_KS      25600000UL     // N*4 f32         1,600,000
#define OFF_QD      27200000UL     // N*4 f32         1,600,000
#define OFF_R       28800000UL     // N*16 f32        6,400,000
#define OFF_COUNTS  35200000UL     // N int             400,000
#define OFF_NCNT    35600000UL     // 4 int (memset)
#define OFF_NCUR    35600016UL     // 4 int
#define OFF_ROWPTR  35600128UL     // (N+1) int
#define OFF_CURSOR  36000256UL     // N int
#define OFF_INCL    36400256UL     // N int
#define OFF_BSUMS   36800256UL     // 64 int
#define OFF_EDGES   36800512UL     // E uint2         4,800,000
#define OFF_WKRED   41600512UL     // 3*128*4 f32
#define OFF_WQRED   41606656UL
#define OFF_ETL     41612800UL     // 4*4 f32
#define OFF_NBASE   41612928UL
#define OFF_NPERM   41613056UL     // (N+96) int
#define OFF_WPACK   42013440UL     // 3*8*4*64*8 bf16 = 196,608 B

__device__ __forceinline__ unsigned int pack_bf16(float a, float b) {
    __hip_bfloat16 ha = __float2bfloat16(a);
    __hip_bfloat16 hb = __float2bfloat16(b);
    unsigned short ua = *reinterpret_cast<unsigned short*>(&ha);
    unsigned short ub = *reinterpret_cast<unsigned short*>(&hb);
    return (unsigned int)ua | ((unsigned int)ub << 16);
}

union U8 { uint4 u; bf16x8 v; };

// ------------- init: zero counts, fill nperm, ntype histogram -------------
__global__ void k_init(int* __restrict__ counts, int* __restrict__ nperm,
                       const int* __restrict__ ntype, int* __restrict__ ncnt) {
    __shared__ int c[NT];
    if (threadIdx.x < NT) c[threadIdx.x] = 0;
    __syncthreads();
    int i = blockIdx.x * blockDim.x + threadIdx.x;
    if (i < NN) { counts[i] = 0; atomicAdd(&c[ntype[i]], 1); }
    if (i < NN + 96) nperm[i] = -1;
    __syncthreads();
    if (threadIdx.x < NT) atomicAdd(&ncnt[threadIdx.x], c[threadIdx.x]);
}

// ------------- precompute: reduced weights + etl + Wv bf16 fragment pack -------------
// Wpack[t][ot][kc][lane][j] = bf16(Wv[t][k = kc*32+(lane>>4)*8+j][o = ot*16+(lane&15)])
#define PACK_BASE 1600
__global__ void k_pre(const float* __restrict__ Wq, const float* __restrict__ Wk,
                      const float* __restrict__ Wv,
                      const float* __restrict__ att_src, const float* __restrict__ att_dst,
                      const float* __restrict__ be, const float* __restrict__ att_edge,
                      float* __restrict__ wk_red, float* __restrict__ wq_red, float* __restrict__ etl,
                      unsigned int* __restrict__ wpack) {
    int gid = blockIdx.x * blockDim.x + threadIdx.x;
    if (gid < NT * FD * NH) {
        int h = gid % NH;
        int i = (gid / NH) % FD;
        int t = gid / (NH * FD);
        const float* wkp = Wk + ((size_t)t * FD + i) * HIDD + h * DH;
        const float* wqp = Wq + ((size_t)t * FD + i) * HIDD + h * DH;
        const float* as = att_src + h * DH;
        const float* ad = att_dst + h * DH;
        float sk = 0.f, sq = 0.f;
        for (int d = 0; d < DH; ++d) { sk += wkp[d] * as[d]; sq += wqp[d] * ad[d]; }
        wk_red[gid] = sk;   // layout [t][i][h]
        wq_red[gid] = sq;
    } else if (gid < NT * FD * NH + NET * NH) {
        int rdx = gid - NT * FD * NH;
        int h = rdx % NH;
        int t = rdx / NH;
        float s = 0.f;
        for (int d = 0; d < DH; ++d) s += be[t * HIDD + h * DH + d] * att_edge[h * DH + d];
        etl[rdx] = s;       // layout [t][h]
    } else if (gid >= PACK_BASE && gid < PACK_BASE + NT * 8 * 4 * 64) {
        int q = gid - PACK_BASE;
        int t = q >> 11;
        int rem = q & 2047;
        int ot = rem >> 8;
        int rem2 = rem & 255;
        int kc = rem2 >> 6;
        int l = rem2 & 63;
        int o = ot * 16 + (l & 15);
        int kb = kc * 32 + (l >> 4) * 8;
        unsigned int w[4];
#pragma unroll
        for (int jj = 0; jj < 4; ++jj) {
            float v0 = Wv[((size_t)t * FD + kb + 2 * jj) * HIDD + o];
            float v1 = Wv[((size_t)t * FD + kb + 2 * jj + 1) * HIDD + o];
            w[jj] = pack_bf16(v0, v1);
        }
        uint4 o4 = {w[0], w[1], w[2], w[3]};
        *reinterpret_cast<uint4*>(wpack + (size_t)q * 4) = o4;
    }
}

// ------------- CSR build -------------
__global__ void k_count(const int* __restrict__ ei, int* __restrict__ counts) {
    int e = blockIdx.x * blockDim.x + threadIdx.x;
    if (e < NE) atomicAdd(&counts[ei[NE + e]], 1);
}

__global__ void k_scan1(const int* __restrict__ counts, int* __restrict__ incl, int* __restrict__ bsums) {
    __shared__ int lds[2048];
    int base = blockIdx.x * 2048;
    for (int k = threadIdx.x; k < 2048; k += 256)
        lds[k] = (base + k < NN) ? counts[base + k] : 0;
    __syncthreads();
    for (int off = 1; off < 2048; off <<= 1) {
        int vals[8];
        for (int j = 0; j < 8; ++j) {
            int k = threadIdx.x + j * 256;
            vals[j] = (k >= off) ? lds[k - off] : 0;
        }
        __syncthreads();
        for (int j = 0; j < 8; ++j) {
            int k = threadIdx.x + j * 256;
            lds[k] += vals[j];
        }
        __syncthreads();
    }
    for (int k = threadIdx.x; k < 2048; k += 256)
        if (base + k < NN) incl[base + k] = lds[k];
    if (threadIdx.x == 0) bsums[blockIdx.x] = lds[2047];
}

// + nbase/ncur (type blocks padded to 16 for MFMA tiles)
__global__ void k_scan2(int* __restrict__ bsums, int nb, const int* __restrict__ ncnt,
                        int* __restrict__ nbase, int* __restrict__ ncur) {
    if (threadIdx.x == 0) {
        int run = 0;
        for (int i = 0; i < nb; ++i) { int vv = bsums[i]; bsums[i] = run; run += vv; }
        int b = 0;
        for (int t = 0; t < NT; ++t) {
            nbase[t] = b;
            ncur[t] = 0;
            b += (ncnt[t] + 15) & ~15;
        }
        nbase[NT] = b;
    }
}

__global__ void k_scan3(const int* __restrict__ counts, const int* __restrict__ incl,
                        const int* __restrict__ bsums, int* __restrict__ row_ptr, int* __restrict__ cursor) {
    int i = blockIdx.x * blockDim.x + threadIdx.x;
    if (i < NN) {
        int ex = incl[i] - counts[i] + bsums[i / 2048];
        row_ptr[i] = ex;
        cursor[i] = ex;
    }
    if (i == 0) row_ptr[NN] = NE;
}

__global__ void k_fill(const int* __restrict__ ei, const int* __restrict__ etype, int* __restrict__ cursor,
                       uint2* __restrict__ edges) {
    int e = blockIdx.x * blockDim.x + threadIdx.x;
    if (e >= NE) return;
    int dst = ei[NE + e];
    int pos = atomicAdd(&cursor[dst], 1);
    uint2 rec;
    rec.x = ((unsigned)ei[e] << 2) | (unsigned)etype[e];
    rec.y = (unsigned)e;
    edges[pos] = rec;
}

__global__ void k_nscatter(const int* __restrict__ ntype, const int* __restrict__ nbase,
                           int* __restrict__ ncur, int* __restrict__ nperm) {
    int n = blockIdx.x * blockDim.x + threadIdx.x;
    if (n >= NN) return;
    int tt = ntype[n];
    int lane = threadIdx.x & 63;
    for (int t = 0; t < NT; ++t) {
        unsigned long long m = __ballot(tt == t);
        if (tt == t) {
            int rank = __popcll(m & ((1ull << lane) - 1ull));
            int leader = __ffsll((unsigned long long)m) - 1;
            int base = 0;
            if (lane == leader) base = atomicAdd(&ncur[t], (int)__popcll(m));
            base = __shfl(base, leader, 64);
            nperm[nbase[t] + base + rank] = n;
        }
    }
}

// ------------- fused node kernel: v = x @ Wv[type] (MFMA) + ks/qd + r table -------------
// Wave handles 16 same-type nodes. col = lane&15 (node for A / out-dim for D), kg = lane>>4.
// A: node nperm[base+col], k-dims kg*8+j per kc.  D: out-dim ot*16+col, node kg*4+reg.
__global__ __launch_bounds__(256) void k_node(const float* __restrict__ x,
                                              const unsigned short* __restrict__ wpack,
                                              const int* __restrict__ ntype, const int* __restrict__ nperm,
                                              const float* __restrict__ wk_red, const float* __restrict__ wq_red,
                                              const float* __restrict__ be, const float* __restrict__ Wec,
                                              unsigned short* __restrict__ vb, float* __restrict__ ks4,
                                              float* __restrict__ qd4, float* __restrict__ rtab) {
    int wave = threadIdx.x >> 6, lane = threadIdx.x & 63;
    int base = blockIdx.x * 64 + wave * 16;
    int n0 = nperm[base];
    if (n0 < 0) return;                      // fully padded tile
    int t = ntype[n0];
    int col = lane & 15, kg = lane >> 4;
    int anr = nperm[base + col];
    bool avalid = anr >= 0;
    int an = avalid ? anr : 0;

    // ---- load x rows (f32, gathered) ----
    const float* xp = x + (size_t)an * FD;
    float xf[4][8];
#pragma unroll
    for (int kc = 0; kc < 4; ++kc) {
        float4 a4 = *reinterpret_cast<const float4*>(xp + kc * 32 + kg * 8);
        float4 b4 = *reinterpret_cast<const float4*>(xp + kc * 32 + kg * 8 + 4);
        xf[kc][0] = a4.x; xf[kc][1] = a4.y; xf[kc][2] = a4.z; xf[kc][3] = a4.w;
        xf[kc][4] = b4.x; xf[kc][5] = b4.y; xf[kc][6] = b4.z; xf[kc][7] = b4.w;
    }

    // ---- ks/qd (f32): lane covers 32 dims of node 'an'; reduce over kg ----
    {
        float ka[4] = {0, 0, 0, 0}, qa[4] = {0, 0, 0, 0};
#pragma unroll
        for (int kc = 0; kc < 4; ++kc) {
#pragma unroll
            for (int j = 0; j < 8; ++j) {
                int dim = kc * 32 + kg * 8 + j;
                float xv = xf[kc][j];
                float4 wk4 = *reinterpret_cast<const float4*>(wk_red + ((size_t)t * FD + dim) * NH);
                float4 wq4 = *reinterpret_cast<const float4*>(wq_red + ((size_t)t * FD + dim) * NH);
                ka[0] = fmaf(xv, wk4.x, ka[0]); ka[1] = fmaf(xv, wk4.y, ka[1]);
                ka[2] = fmaf(xv, wk4.z, ka[2]); ka[3] = fmaf(xv, wk4.w, ka[3]);
                qa[0] = fmaf(xv, wq4.x, qa[0]); qa[1] = fmaf(xv, wq4.y, qa[1]);
                qa[2] = fmaf(xv, wq4.z, qa[2]); qa[3] = fmaf(xv, wq4.w, qa[3]);
            }
        }
#pragma unroll
        for (int off = 16; off < 64; off <<= 1) {
#pragma unroll
            for (int h = 0; h < 4; ++h) {
                ka[h] += __shfl_xor(ka[h], off, 64);
                qa[h] += __shfl_xor(qa[h], off, 64);
            }
        }
        if (kg == 0 && avalid) {
            float4 ko = {ka[0], ka[1], ka[2], ka[3]};
            float4 qo = {qa[0], qa[1], qa[2], qa[3]};
            *reinterpret_cast<float4*>(ks4 + (size_t)an * NH) = ko;
            *reinterpret_cast<float4*>(qd4 + (size_t)an * NH) = qo;
        }
    }

    // ---- A fragments (bf16) ----
    bf16x8 afrag[4];
#pragma unroll
    for (int kc = 0; kc < 4; ++kc) {
        U8 u;
        u.u.x = pack_bf16(xf[kc][0], xf[kc][1]);
        u.u.y = pack_bf16(xf[kc][2], xf[kc][3]);
        u.u.z = pack_bf16(xf[kc][4], xf[kc][5]);
        u.u.w = pack_bf16(xf[kc][6], xf[kc][7]);
        afrag[kc] = u.v;
    }

    int dn[4];
#pragma unroll
    for (int rg = 0; rg < 4; ++rg) dn[rg] = nperm[base + kg * 4 + rg];

    const unsigned short* wt = wpack + (size_t)t * 8 * 4 * 64 * 8;
    float rpart[4][4];
#pragma unroll
    for (int t2 = 0; t2 < 4; ++t2)
#pragma unroll
        for (int rg = 0; rg < 4; ++rg) rpart[t2][rg] = 0.f;

#pragma unroll
    for (int ot = 0; ot < 8; ++ot) {
        f32x4 acc = {0.f, 0.f, 0.f, 0.f};
#pragma unroll
        for (int kc = 0; kc < 4; ++kc) {
            bf16x8 b = *reinterpret_cast<const bf16x8*>(wt + ((size_t)(ot * 4 + kc) * 64 + lane) * 8);
            acc = __builtin_amdgcn_mfma_f32_16x16x32_bf16(afrag[kc], b, acc, 0, 0, 0);
        }
        // v store (bf16, per node row)
#pragma unroll
        for (int rg = 0; rg < 4; ++rg) {
            if (dn[rg] >= 0) {
                __hip_bfloat16 hv = __float2bfloat16(acc[rg]);
                vb[(size_t)dn[rg] * FD + ot * 16 + col] = *reinterpret_cast<unsigned short*>(&hv);
            }
        }
        // r partials: dim o = ot*16+col belongs to head ot>>1
#pragma unroll
        for (int t2 = 0; t2 < NET; ++t2) {
            float bev = be[t2 * HIDD + ot * 16 + col];
            float wev = Wec[t2 * HIDD + ot * 16 + col];
#pragma unroll
            for (int rg = 0; rg < 4; ++rg)
                rpart[t2][rg] = fmaf(fmaxf(acc[rg] + bev, 0.f), wev, rpart[t2][rg]);
        }
        if (ot & 1) {
            int h = ot >> 1;
#pragma unroll
            for (int t2 = 0; t2 < NET; ++t2) {
#pragma unroll
                for (int rg = 0; rg < 4; ++rg) {
                    float s = rpart[t2][rg];
                    s += __shfl_xor(s, 1, 64);
                    s += __shfl_xor(s, 2, 64);
                    s += __shfl_xor(s, 4, 64);
                    s += __shfl_xor(s, 8, 64);
                    if (col == t2 * 4 + rg && dn[rg] >= 0)
                        rtab[(size_t)dn[rg] * (NET * NH) + t2 * NH + h] = s;
                    rpart[t2][rg] = 0.f;
                }
            }
        }
    }
}

// ------------- main: softmax + aggregation + x_cls + fused e_cls -------------
__global__ __launch_bounds__(256) void k_main(const int* __restrict__ row_ptr, const uint2* __restrict__ edges,
                                              const float* __restrict__ ks4, const float* __restrict__ qd4,
                                              const float* __restrict__ etl, const unsigned int* __restrict__ vb,
                                              const float* __restrict__ be, const float* __restrict__ rtab,
                                              const float* __restrict__ bec, const float* __restrict__ Wn,
                                              const float* __restrict__ bn, const int* __restrict__ ntype,
                                              float* __restrict__ out_x, float* __restrict__ out_e) {
    int wave = threadIdx.x >> 6;
    int lane = threadIdx.x & 63;
    int n = blockIdx.x * 4 + wave;
    if (n >= NN) return;
    int rs = row_ptr[n], deg = row_ptr[n + 1] - rs;
    int hh = lane & 3;
    int k0 = lane >> 2;
    int hv = lane >> 4;

    float q = qd4[(size_t)n * NH + hh];

    bool act0 = k0 < deg;
    uint2 ed0 = {0u, 0u};
    if (act0) ed0 = edges[rs + k0];
    int s0r = (int)(ed0.x >> 2), et0 = (int)(ed0.x & 3u);
    float lg0 = -INFINITY;
    if (act0) {
        float l = ks4[(size_t)s0r * NH + hh] + q + etl[et0 * NH + hh];
        lg0 = l >= 0.f ? l : SLOPE * l;
    }
    float mx = lg0;
    if (deg > 16) {
        for (int bb = 16; bb < deg; bb += 16) {
            int kk = bb + k0;
            if (kk < deg) {
                uint2 ed = edges[rs + kk];
                int s = (int)(ed.x >> 2), et = (int)(ed.x & 3u);
                float l = ks4[(size_t)s * NH + hh] + q + etl[et * NH + hh];
                l = l >= 0.f ? l : SLOPE * l;
                mx = fmaxf(mx, l);
            }
        }
    }
#pragma unroll
    for (int off = 4; off < 64; off <<= 1) mx = fmaxf(mx, __shfl_xor(mx, off, 64));

    float e0 = act0 ? __expf(lg0 - mx) : 0.f;
    float dn = e0;
    if (deg > 16) {
        for (int bb = 16; bb < deg; bb += 16) {
            int kk = bb + k0;
            if (kk < deg) {
                uint2 ed = edges[rs + kk];
                int s = (int)(ed.x >> 2), et = (int)(ed.x & 3u);
                float l = ks4[(size_t)s * NH + hh] + q + etl[et * NH + hh];
                l = l >= 0.f ? l : SLOPE * l;
                dn += __expf(l - mx);
            }
        }
    }
#pragma unroll
    for (int off = 4; off < 64; off <<= 1) dn += __shfl_xor(dn, off, 64);
    float inv = 1.0f / (dn + 1e-16f);

    // fused e_cls
    if (act0) {
        float term = e0 * inv * rtab[((size_t)s0r * NET + et0) * NH + hh];
        term += __shfl_xor(term, 1, 64);
        term += __shfl_xor(term, 2, 64);
        if (hh == 0) out_e[ed0.y] = term + bec[et0];
    }
    if (deg > 16) {
        for (int bb = 16; bb < deg; bb += 16) {
            int kk = bb + k0;
            if (kk < deg) {
                uint2 ed = edges[rs + kk];
                int s = (int)(ed.x >> 2), et = (int)(ed.x & 3u);
                float l = ks4[(size_t)s * NH + hh] + q + etl[et * NH + hh];
                l = l >= 0.f ? l : SLOPE * l;
                float term = __expf(l - mx) * inv * rtab[((size_t)s * NET + et) * NH + hh];
                term += __shfl_xor(term, 1, 64);
                term += __shfl_xor(term, 2, 64);
                if (hh == 0) out_e[ed.y] = term + bec[et];
            }
        }
    }

    float alpha0 = e0 * inv;

    // aggregation: acc += alpha * (v[src] + be[et]) over bf16 v
    float ax = 0.f, ay = 0.f;
    int cnt0 = deg < 16 ? deg : 16;
    for (int j = 0; j < cnt0; ++j) {
        float p = __shfl(alpha0, 4 * j + hv, 64);
        unsigned int pk = __shfl(ed0.x, 4 * j, 64);
        int sn = (int)(pk >> 2), et = (int)(pk & 3u);
        unsigned int w = vb[(size_t)sn * 64 + lane];
        float2 b2 = *reinterpret_cast<const float2*>(be + et * HIDD + 2 * lane);
        ax = fmaf(p, __uint_as_float(w << 16) + b2.x, ax);
        ay = fmaf(p, __uint_as_float(w & 0xffff0000u) + b2.y, ay);
    }
    if (deg > 16) {
        for (int bb = 16; bb < deg; bb += 16) {
            int kk = bb + k0;
            float al = 0.f;
            unsigned int pkr = 0;
            if (kk < deg) {
                uint2 ed = edges[rs + kk];
                pkr = ed.x;
                int s = (int)(ed.x >> 2), et = (int)(ed.x & 3u);
                float l = ks4[(size_t)s * NH + hh] + q + etl[et * NH + hh];
                l = l >= 0.f ? l : SLOPE * l;
                al = __expf(l - mx) * inv;
            }
            int cnt = deg - bb; if (cnt > 16) cnt = 16;
            for (int j = 0; j < cnt; ++j) {
                float p = __shfl(al, 4 * j + hv, 64);
                unsigned int pk = __shfl(pkr, 4 * j, 64);
                int sn = (int)(pk >> 2), et = (int)(pk & 3u);
                unsigned int w = vb[(size_t)sn * 64 + lane];
                float2 b2 = *reinterpret_cast<const float2*>(be + et * HIDD + 2 * lane);
                ax = fmaf(p, __uint_as_float(w << 16) + b2.x, ax);
                ay = fmaf(p, __uint_as_float(w & 0xffff0000u) + b2.y, ay);
            }
        }
    }

    int t = ntype[n];
    float2 w2 = *reinterpret_cast<const float2*>(Wn + t * HIDD + 2 * lane);
    float s = fmaxf(ax, 0.f) * w2.x + fmaxf(ay, 0.f) * w2.y;
#pragma unroll
    for (int off = 1; off < 64; off <<= 1) s += __shfl_xor(s, off, 64);
    if (lane == 0) out_x[n] = s + bn[t];
}

extern "C" void kernel_launch(void* const* d_in, const int* in_sizes, int n_in,
                              void* d_out, int out_size, void* d_ws, size_t ws_size,
                              hipStream_t stream) {
    const float* x        = (const float*)d_in[0];
    const int*   ei       = (const int*)d_in[1];
    const int*   ntype    = (const int*)d_in[2];
    const int*   etype    = (const int*)d_in[3];
    // d_in[4] edge_attr: unused (reference feeds zeros into the conv)
    const float* Wq       = (const float*)d_in[5];
    const float* Wk       = (const float*)d_in[6];
    const float* Wv       = (const float*)d_in[7];
    const float* att_src  = (const float*)d_in[8];
    const float* att_dst  = (const float*)d_in[9];
    const float* att_edge = (const float*)d_in[10];
    // d_in[11] We: unused (multiplied by zero edge_attr)
    const float* be       = (const float*)d_in[12];
    const float* Wn       = (const float*)d_in[13];
    const float* bn       = (const float*)d_in[14];
    const float* Wec      = (const float*)d_in[15];
    const float* bec      = (const float*)d_in[16];

    char* ws = (char*)d_ws;
    unsigned int*   vb32 = (unsigned int*)(ws + OFF_V);
    unsigned short* vb16 = (unsigned short*)(ws + OFF_V);
    float* ks4     = (float*)(ws + OFF_KS);
    float* qd4     = (float*)(ws + OFF_QD);
    float* rtab    = (float*)(ws + OFF_R);
    int*   counts  = (int*)(ws + OFF_COUNTS);
    int*   ncnt    = (int*)(ws + OFF_NCNT);
    int*   ncur    = (int*)(ws + OFF_NCUR);
    int*   row_ptr = (int*)(ws + OFF_ROWPTR);
    int*   cursor  = (int*)(ws + OFF_CURSOR);
    int*   incl    = (int*)(ws + OFF_INCL);
    int*   bsums   = (int*)(ws + OFF_BSUMS);
    uint2* edges   = (uint2*)(ws + OFF_EDGES);
    float* wk_red  = (float*)(ws + OFF_WKRED);
    float* wq_red  = (float*)(ws + OFF_WQRED);
    float* etl     = (float*)(ws + OFF_ETL);
    int*   nbase   = (int*)(ws + OFF_NBASE);
    int*   nperm   = (int*)(ws + OFF_NPERM);
    unsigned int* wpack = (unsigned int*)(ws + OFF_WPACK);

    float* out_x = (float*)d_out;
    float* out_e = (float*)d_out + NN;

    hipMemsetAsync(ws + OFF_NCNT, 0, 16, stream);
    k_init<<<(NN + 96 + 255) / 256, 256, 0, stream>>>(counts, nperm, ntype, ncnt);
    k_pre<<<31, 256, 0, stream>>>(Wq, Wk, Wv, att_src, att_dst, be, att_edge,
                                  wk_red, wq_red, etl, wpack);
    k_count<<<(NE + 255) / 256, 256, 0, stream>>>(ei, counts);
    k_scan1<<<49, 256, 0, stream>>>(counts, incl, bsums);
    k_scan2<<<1, 64, 0, stream>>>(bsums, 49, ncnt, nbase, ncur);
    k_scan3<<<(NN + 255) / 256, 256, 0, stream>>>(counts, incl, bsums, row_ptr, cursor);
    k_fill<<<(NE + 255) / 256, 256, 0, stream>>>(ei, etype, cursor, edges);
    k_nscatter<<<(NN + 255) / 256, 256, 0, stream>>>(ntype, nbase, ncur, nperm);
    k_node<<<(NN + 96) / 64, 256, 0, stream>>>(x, (const unsigned short*)wpack, ntype, nperm,
                                               wk_red, wq_red, be, Wec, vb16, ks4, qd4, rtab);
    k_main<<<(NN + 3) / 4, 256, 0, stream>>>(row_ptr, edges, ks4, qd4, etl, vb32, be,
                                             rtab, bec, Wn, bn, ntype, out_x, out_e);
}

// Round 7
// 267.969 us; speedup vs baseline: 2.0294x; 1.0868x over previous
//
#include <hip/hip_runtime.h>
#include <hip/hip_bf16.h>

// HATGNN forward.
// Pipeline: memset(counts+ncnt) -> k_initcount (nperm fill + ntype hist + edge count)
//   -> k_pre -> k_scan1 -> k_scan2(+nbase) -> k_scan3(+nscatter) -> k_fill
//   -> k_node (x->bf16 + MFMA v-GEMV + ks/qd + r table fused)
//   -> k_main (softmax + aggregation + x_cls + fused e_cls, MLP-4 agg loop).
// Key ideas: e_emb == be[etype] (edge_attr zeroed in reference); q/k fold into per-type
// reduced weights; e_cls = sum_h alpha*r[src,et,h] (alpha>=0 commutes with relu);
// v GEMV on matrix cores; CSR edge record packed to 8B.

#define NN 100000
#define NE 600000
#define FD 128
#define HIDD 128
#define NH 4
#define DH 32
#define NT 3
#define NET 4
#define SLOPE 0.2f

typedef short bf16x8 __attribute__((ext_vector_type(8)));
typedef float f32x4 __attribute__((ext_vector_type(4)));

// ---------------- ws layout (bytes) ----------------
#define OFF_V       0UL            // N*128 bf16     25,600,000
#define OFF_KS      25600000UL     // N*4 f32         1,600,000
#define OFF_QD      27200000UL     // N*4 f32         1,600,000
#define OFF_R       28800000UL     // N*16 f32        6,400,000
#define OFF_COUNTS  35200000UL     // N int             400,000
#define OFF_NCNT    35600000UL     // 4 int (memset, contiguous with counts)
#define OFF_NCUR    35600016UL     // 4 int
#define OFF_ROWPTR  35600128UL     // (N+1) int
#define OFF_CURSOR  36000256UL     // N int
#define OFF_INCL    36400256UL     // N int
#define OFF_BSUMS   36800256UL     // 64 int
#define OFF_EDGES   36800512UL     // E uint2         4,800,000
#define OFF_WKRED   41600512UL     // 3*128*4 f32
#define OFF_WQRED   41606656UL
#define OFF_ETL     41612800UL     // 4*4 f32
#define OFF_NBASE   41612928UL
#define OFF_NPERM   41613056UL     // (N+96) int
#define OFF_WPACK   42013440UL     // 3*8*4*64*8 bf16 = 196,608 B

__device__ __forceinline__ unsigned int pack_bf16(float a, float b) {
    __hip_bfloat16 ha = __float2bfloat16(a);
    __hip_bfloat16 hb = __float2bfloat16(b);
    unsigned short ua = *reinterpret_cast<unsigned short*>(&ha);
    unsigned short ub = *reinterpret_cast<unsigned short*>(&hb);
    return (unsigned int)ua | ((unsigned int)ub << 16);
}

union U8 { uint4 u; bf16x8 v; };

// ------------- init+count: nperm fill, ntype hist, edge degree count -------------
// counts/ncnt pre-zeroed by memsetAsync.
__global__ void k_initcount(const int* __restrict__ ei, const int* __restrict__ ntype,
                            int* __restrict__ counts, int* __restrict__ ncnt,
                            int* __restrict__ nperm) {
    __shared__ int c[NT];
    if (threadIdx.x < NT) c[threadIdx.x] = 0;
    __syncthreads();
    int i = blockIdx.x * blockDim.x + threadIdx.x;
    if (i < NE) atomicAdd(&counts[ei[NE + i]], 1);
    if (i < NN) atomicAdd(&c[ntype[i]], 1);
    if (i < NN + 96) nperm[i] = -1;
    __syncthreads();
    if (threadIdx.x < NT && c[threadIdx.x]) atomicAdd(&ncnt[threadIdx.x], c[threadIdx.x]);
}

// ------------- precompute: reduced weights + etl + Wv bf16 fragment pack -------------
// Wpack[t][ot][kc][lane][j] = bf16(Wv[t][k = kc*32+(lane>>4)*8+j][o = ot*16+(lane&15)])
#define PACK_BASE 1600
__global__ void k_pre(const float* __restrict__ Wq, const float* __restrict__ Wk,
                      const float* __restrict__ Wv,
                      const float* __restrict__ att_src, const float* __restrict__ att_dst,
                      const float* __restrict__ be, const float* __restrict__ att_edge,
                      float* __restrict__ wk_red, float* __restrict__ wq_red, float* __restrict__ etl,
                      unsigned int* __restrict__ wpack) {
    int gid = blockIdx.x * blockDim.x + threadIdx.x;
    if (gid < NT * FD * NH) {
        int h = gid % NH;
        int i = (gid / NH) % FD;
        int t = gid / (NH * FD);
        const float* wkp = Wk + ((size_t)t * FD + i) * HIDD + h * DH;
        const float* wqp = Wq + ((size_t)t * FD + i) * HIDD + h * DH;
        const float* as = att_src + h * DH;
        const float* ad = att_dst + h * DH;
        float sk = 0.f, sq = 0.f;
        for (int d = 0; d < DH; ++d) { sk += wkp[d] * as[d]; sq += wqp[d] * ad[d]; }
        wk_red[gid] = sk;   // layout [t][i][h]
        wq_red[gid] = sq;
    } else if (gid < NT * FD * NH + NET * NH) {
        int rdx = gid - NT * FD * NH;
        int h = rdx % NH;
        int t = rdx / NH;
        float s = 0.f;
        for (int d = 0; d < DH; ++d) s += be[t * HIDD + h * DH + d] * att_edge[h * DH + d];
        etl[rdx] = s;       // layout [t][h]
    } else if (gid >= PACK_BASE && gid < PACK_BASE + NT * 8 * 4 * 64) {
        int q = gid - PACK_BASE;
        int t = q >> 11;
        int rem = q & 2047;
        int ot = rem >> 8;
        int rem2 = rem & 255;
        int kc = rem2 >> 6;
        int l = rem2 & 63;
        int o = ot * 16 + (l & 15);
        int kb = kc * 32 + (l >> 4) * 8;
        unsigned int w[4];
#pragma unroll
        for (int jj = 0; jj < 4; ++jj) {
            float v0 = Wv[((size_t)t * FD + kb + 2 * jj) * HIDD + o];
            float v1 = Wv[((size_t)t * FD + kb + 2 * jj + 1) * HIDD + o];
            w[jj] = pack_bf16(v0, v1);
        }
        uint4 o4 = {w[0], w[1], w[2], w[3]};
        *reinterpret_cast<uint4*>(wpack + (size_t)q * 4) = o4;
    }
}

// ------------- CSR scan -------------
__global__ void k_scan1(const int* __restrict__ counts, int* __restrict__ incl, int* __restrict__ bsums) {
    __shared__ int lds[2048];
    int base = blockIdx.x * 2048;
    for (int k = threadIdx.x; k < 2048; k += 256)
        lds[k] = (base + k < NN) ? counts[base + k] : 0;
    __syncthreads();
    for (int off = 1; off < 2048; off <<= 1) {
        int vals[8];
        for (int j = 0; j < 8; ++j) {
            int k = threadIdx.x + j * 256;
            vals[j] = (k >= off) ? lds[k - off] : 0;
        }
        __syncthreads();
        for (int j = 0; j < 8; ++j) {
            int k = threadIdx.x + j * 256;
            lds[k] += vals[j];
        }
        __syncthreads();
    }
    for (int k = threadIdx.x; k < 2048; k += 256)
        if (base + k < NN) incl[base + k] = lds[k];
    if (threadIdx.x == 0) bsums[blockIdx.x] = lds[2047];
}

// + nbase/ncur (type blocks padded to 16 for MFMA tiles)
__global__ void k_scan2(int* __restrict__ bsums, int nb, const int* __restrict__ ncnt,
                        int* __restrict__ nbase, int* __restrict__ ncur) {
    if (threadIdx.x == 0) {
        int run = 0;
        for (int i = 0; i < nb; ++i) { int vv = bsums[i]; bsums[i] = run; run += vv; }
        int b = 0;
        for (int t = 0; t < NT; ++t) {
            nbase[t] = b;
            ncur[t] = 0;
            b += (ncnt[t] + 15) & ~15;
        }
        nbase[NT] = b;
    }
}

// row_ptr/cursor + type-sort scatter (merged k_nscatter)
__global__ void k_scan3(const int* __restrict__ counts, const int* __restrict__ incl,
                        const int* __restrict__ bsums, int* __restrict__ row_ptr, int* __restrict__ cursor,
                        const int* __restrict__ ntype, const int* __restrict__ nbase,
                        int* __restrict__ ncur, int* __restrict__ nperm) {
    int i = blockIdx.x * blockDim.x + threadIdx.x;
    if (i == 0) row_ptr[NN] = NE;
    if (i >= NN) return;
    int ex = incl[i] - counts[i] + bsums[i / 2048];
    row_ptr[i] = ex;
    cursor[i] = ex;
    int tt = ntype[i];
    int lane = threadIdx.x & 63;
    for (int t = 0; t < NT; ++t) {
        unsigned long long m = __ballot(tt == t);
        if (tt == t) {
            int rank = __popcll(m & ((1ull << lane) - 1ull));
            int leader = __ffsll((unsigned long long)m) - 1;
            int base = 0;
            if (lane == leader) base = atomicAdd(&ncur[t], (int)__popcll(m));
            base = __shfl(base, leader, 64);
            nperm[nbase[t] + base + rank] = i;
        }
    }
}

__global__ void k_fill(const int* __restrict__ ei, const int* __restrict__ etype, int* __restrict__ cursor,
                       uint2* __restrict__ edges) {
    int e = blockIdx.x * blockDim.x + threadIdx.x;
    if (e >= NE) return;
    int dst = ei[NE + e];
    int pos = atomicAdd(&cursor[dst], 1);
    uint2 rec;
    rec.x = ((unsigned)ei[e] << 2) | (unsigned)etype[e];
    rec.y = (unsigned)e;
    edges[pos] = rec;
}

// ------------- fused node kernel: v = x @ Wv[type] (MFMA) + ks/qd + r table -------------
// Wave handles 16 same-type nodes. col = lane&15 (node for A / out-dim for D), kg = lane>>4.
__global__ __launch_bounds__(256) void k_node(const float* __restrict__ x,
                                              const unsigned short* __restrict__ wpack,
                                              const int* __restrict__ ntype, const int* __restrict__ nperm,
                                              const float* __restrict__ wk_red, const float* __restrict__ wq_red,
                                              const float* __restrict__ be, const float* __restrict__ Wec,
                                              unsigned short* __restrict__ vb, float* __restrict__ ks4,
                                              float* __restrict__ qd4, float* __restrict__ rtab) {
    int wave = threadIdx.x >> 6, lane = threadIdx.x & 63;
    int base = blockIdx.x * 64 + wave * 16;
    int n0 = nperm[base];
    if (n0 < 0) return;                      // fully padded tile
    int t = ntype[n0];
    int col = lane & 15, kg = lane >> 4;
    int anr = nperm[base + col];
    bool avalid = anr >= 0;
    int an = avalid ? anr : 0;

    // ---- load x rows (f32, gathered) ----
    const float* xp = x + (size_t)an * FD;
    float xf[4][8];
#pragma unroll
    for (int kc = 0; kc < 4; ++kc) {
        float4 a4 = *reinterpret_cast<const float4*>(xp + kc * 32 + kg * 8);
        float4 b4 = *reinterpret_cast<const float4*>(xp + kc * 32 + kg * 8 + 4);
        xf[kc][0] = a4.x; xf[kc][1] = a4.y; xf[kc][2] = a4.z; xf[kc][3] = a4.w;
        xf[kc][4] = b4.x; xf[kc][5] = b4.y; xf[kc][6] = b4.z; xf[kc][7] = b4.w;
    }

    // ---- ks/qd (f32): lane covers 32 dims of node 'an'; reduce over kg ----
    {
        float ka[4] = {0, 0, 0, 0}, qa[4] = {0, 0, 0, 0};
#pragma unroll
        for (int kc = 0; kc < 4; ++kc) {
#pragma unroll
            for (int j = 0; j < 8; ++j) {
                int dim = kc * 32 + kg * 8 + j;
                float xv = xf[kc][j];
                float4 wk4 = *reinterpret_cast<const float4*>(wk_red + ((size_t)t * FD + dim) * NH);
                float4 wq4 = *reinterpret_cast<const float4*>(wq_red + ((size_t)t * FD + dim) * NH);
                ka[0] = fmaf(xv, wk4.x, ka[0]); ka[1] = fmaf(xv, wk4.y, ka[1]);
                ka[2] = fmaf(xv, wk4.z, ka[2]); ka[3] = fmaf(xv, wk4.w, ka[3]);
                qa[0] = fmaf(xv, wq4.x, qa[0]); qa[1] = fmaf(xv, wq4.y, qa[1]);
                qa[2] = fmaf(xv, wq4.z, qa[2]); qa[3] = fmaf(xv, wq4.w, qa[3]);
            }
        }
#pragma unroll
        for (int off = 16; off < 64; off <<= 1) {
#pragma unroll
            for (int h = 0; h < 4; ++h) {
                ka[h] += __shfl_xor(ka[h], off, 64);
                qa[h] += __shfl_xor(qa[h], off, 64);
            }
        }
        if (kg == 0 && avalid) {
            float4 ko = {ka[0], ka[1], ka[2], ka[3]};
            float4 qo = {qa[0], qa[1], qa[2], qa[3]};
            *reinterpret_cast<float4*>(ks4 + (size_t)an * NH) = ko;
            *reinterpret_cast<float4*>(qd4 + (size_t)an * NH) = qo;
        }
    }

    // ---- A fragments (bf16) ----
    bf16x8 afrag[4];
#pragma unroll
    for (int kc = 0; kc < 4; ++kc) {
        U8 u;
        u.u.x = pack_bf16(xf[kc][0], xf[kc][1]);
        u.u.y = pack_bf16(xf[kc][2], xf[kc][3]);
        u.u.z = pack_bf16(xf[kc][4], xf[kc][5]);
        u.u.w = pack_bf16(xf[kc][6], xf[kc][7]);
        afrag[kc] = u.v;
    }

    int dn[4];
#pragma unroll
    for (int rg = 0; rg < 4; ++rg) dn[rg] = nperm[base + kg * 4 + rg];

    const unsigned short* wt = wpack + (size_t)t * 8 * 4 * 64 * 8;
    float rpart[4][4];
#pragma unroll
    for (int t2 = 0; t2 < 4; ++t2)
#pragma unroll
        for (int rg = 0; rg < 4; ++rg) rpart[t2][rg] = 0.f;

#pragma unroll
    for (int ot = 0; ot < 8; ++ot) {
        f32x4 acc = {0.f, 0.f, 0.f, 0.f};
#pragma unroll
        for (int kc = 0; kc < 4; ++kc) {
            bf16x8 b = *reinterpret_cast<const bf16x8*>(wt + ((size_t)(ot * 4 + kc) * 64 + lane) * 8);
            acc = __builtin_amdgcn_mfma_f32_16x16x32_bf16(afrag[kc], b, acc, 0, 0, 0);
        }
        // v store (bf16, per node row)
#pragma unroll
        for (int rg = 0; rg < 4; ++rg) {
            if (dn[rg] >= 0) {
                __hip_bfloat16 hv = __float2bfloat16(acc[rg]);
                vb[(size_t)dn[rg] * FD + ot * 16 + col] = *reinterpret_cast<unsigned short*>(&hv);
            }
        }
        // r partials: dim o = ot*16+col belongs to head ot>>1
#pragma unroll
        for (int t2 = 0; t2 < NET; ++t2) {
            float bev = be[t2 * HIDD + ot * 16 + col];
            float wev = Wec[t2 * HIDD + ot * 16 + col];
#pragma unroll
            for (int rg = 0; rg < 4; ++rg)
                rpart[t2][rg] = fmaf(fmaxf(acc[rg] + bev, 0.f), wev, rpart[t2][rg]);
        }
        if (ot & 1) {
            int h = ot >> 1;
#pragma unroll
            for (int t2 = 0; t2 < NET; ++t2) {
#pragma unroll
                for (int rg = 0; rg < 4; ++rg) {
                    float s = rpart[t2][rg];
                    s += __shfl_xor(s, 1, 64);
                    s += __shfl_xor(s, 2, 64);
                    s += __shfl_xor(s, 4, 64);
                    s += __shfl_xor(s, 8, 64);
                    if (col == t2 * 4 + rg && dn[rg] >= 0)
                        rtab[(size_t)dn[rg] * (NET * NH) + t2 * NH + h] = s;
                    rpart[t2][rg] = 0.f;
                }
            }
        }
    }
}

// ------------- main: softmax + aggregation + x_cls + fused e_cls -------------
__global__ __launch_bounds__(256) void k_main(const int* __restrict__ row_ptr, const uint2* __restrict__ edges,
                                              const float* __restrict__ ks4, const float* __restrict__ qd4,
                                              const float* __restrict__ etl, const unsigned int* __restrict__ vb,
                                              const float* __restrict__ be, const float* __restrict__ rtab,
                                              const float* __restrict__ bec, const float* __restrict__ Wn,
                                              const float* __restrict__ bn, const int* __restrict__ ntype,
                                              float* __restrict__ out_x, float* __restrict__ out_e) {
    int wave = threadIdx.x >> 6;
    int lane = threadIdx.x & 63;
    int n = blockIdx.x * 4 + wave;
    if (n >= NN) return;
    int rs = row_ptr[n], deg = row_ptr[n + 1] - rs;
    int hh = lane & 3;
    int k0 = lane >> 2;
    int hv = lane >> 4;

    float q = qd4[(size_t)n * NH + hh];

    bool act0 = k0 < deg;
    uint2 ed0 = {0u, 0u};
    if (act0) ed0 = edges[rs + k0];
    int s0r = (int)(ed0.x >> 2), et0 = (int)(ed0.x & 3u);
    float lg0 = -INFINITY;
    if (act0) {
        float l = ks4[(size_t)s0r * NH + hh] + q + etl[et0 * NH + hh];
        lg0 = l >= 0.f ? l : SLOPE * l;
    }
    float mx = lg0;
    if (deg > 16) {
        for (int bb = 16; bb < deg; bb += 16) {
            int kk = bb + k0;
            if (kk < deg) {
                uint2 ed = edges[rs + kk];
                int s = (int)(ed.x >> 2), et = (int)(ed.x & 3u);
                float l = ks4[(size_t)s * NH + hh] + q + etl[et * NH + hh];
                l = l >= 0.f ? l : SLOPE * l;
                mx = fmaxf(mx, l);
            }
        }
    }
#pragma unroll
    for (int off = 4; off < 64; off <<= 1) mx = fmaxf(mx, __shfl_xor(mx, off, 64));

    float e0 = act0 ? __expf(lg0 - mx) : 0.f;
    float dn = e0;
    if (deg > 16) {
        for (int bb = 16; bb < deg; bb += 16) {
            int kk = bb + k0;
            if (kk < deg) {
                uint2 ed = edges[rs + kk];
                int s = (int)(ed.x >> 2), et = (int)(ed.x & 3u);
                float l = ks4[(size_t)s * NH + hh] + q + etl[et * NH + hh];
                l = l >= 0.f ? l : SLOPE * l;
                dn += __expf(l - mx);
            }
        }
    }
#pragma unroll
    for (int off = 4; off < 64; off <<= 1) dn += __shfl_xor(dn, off, 64);
    float inv = 1.0f / (dn + 1e-16f);

    // fused e_cls
    if (act0) {
        float term = e0 * inv * rtab[((size_t)s0r * NET + et0) * NH + hh];
        term += __shfl_xor(term, 1, 64);
        term += __shfl_xor(term, 2, 64);
        if (hh == 0) out_e[ed0.y] = term + bec[et0];
    }
    if (deg > 16) {
        for (int bb = 16; bb < deg; bb += 16) {
            int kk = bb + k0;
            if (kk < deg) {
                uint2 ed = edges[rs + kk];
                int s = (int)(ed.x >> 2), et = (int)(ed.x & 3u);
                float l = ks4[(size_t)s * NH + hh] + q + etl[et * NH + hh];
                l = l >= 0.f ? l : SLOPE * l;
                float term = __expf(l - mx) * inv * rtab[((size_t)s * NET + et) * NH + hh];
                term += __shfl_xor(term, 1, 64);
                term += __shfl_xor(term, 2, 64);
                if (hh == 0) out_e[ed.y] = term + bec[et];
            }
        }
    }

    float alpha0 = e0 * inv;

    // aggregation: acc += alpha * (v[src] + be[et]); 4-wide unroll for MLP
    float ax = 0.f, ay = 0.f;
    int cnt0 = deg < 16 ? deg : 16;
#define AGG_STEP(JJ) { \
        float p = __shfl(alpha0, 4 * (JJ) + hv, 64); \
        unsigned int pk = __shfl(ed0.x, 4 * (JJ), 64); \
        int sn = (int)(pk >> 2), et = (int)(pk & 3u); \
        unsigned int w = vb[(size_t)sn * 64 + lane]; \
        float2 b2 = *reinterpret_cast<const float2*>(be + et * HIDD + 2 * lane); \
        ax = fmaf(p, __uint_as_float(w << 16) + b2.x, ax); \
        ay = fmaf(p, __uint_as_float(w & 0xffff0000u) + b2.y, ay); }
    {
        int j = 0;
        for (; j + 4 <= cnt0; j += 4) {
            AGG_STEP(j) AGG_STEP(j + 1) AGG_STEP(j + 2) AGG_STEP(j + 3)
        }
        for (; j < cnt0; ++j) AGG_STEP(j)
    }
    if (deg > 16) {
        for (int bb = 16; bb < deg; bb += 16) {
            int kk = bb + k0;
            float al = 0.f;
            unsigned int pkr = 0;
            if (kk < deg) {
                uint2 ed = edges[rs + kk];
                pkr = ed.x;
                int s = (int)(ed.x >> 2), et = (int)(ed.x & 3u);
                float l = ks4[(size_t)s * NH + hh] + q + etl[et * NH + hh];
                l = l >= 0.f ? l : SLOPE * l;
                al = __expf(l - mx) * inv;
            }
            int cnt = deg - bb; if (cnt > 16) cnt = 16;
#define AGG_STEP2(JJ) { \
            float p = __shfl(al, 4 * (JJ) + hv, 64); \
            unsigned int pk = __shfl(pkr, 4 * (JJ), 64); \
            int sn = (int)(pk >> 2), et = (int)(pk & 3u); \
            unsigned int w = vb[(size_t)sn * 64 + lane]; \
            float2 b2 = *reinterpret_cast<const float2*>(be + et * HIDD + 2 * lane); \
            ax = fmaf(p, __uint_as_float(w << 16) + b2.x, ax); \
            ay = fmaf(p, __uint_as_float(w & 0xffff0000u) + b2.y, ay); }
            int j = 0;
            for (; j + 4 <= cnt; j += 4) {
                AGG_STEP2(j) AGG_STEP2(j + 1) AGG_STEP2(j + 2) AGG_STEP2(j + 3)
            }
            for (; j < cnt; ++j) AGG_STEP2(j)
        }
    }

    int t = ntype[n];
    float2 w2 = *reinterpret_cast<const float2*>(Wn + t * HIDD + 2 * lane);
    float s = fmaxf(ax, 0.f) * w2.x + fmaxf(ay, 0.f) * w2.y;
#pragma unroll
    for (int off = 1; off < 64; off <<= 1) s += __shfl_xor(s, off, 64);
    if (lane == 0) out_x[n] = s + bn[t];
}

extern "C" void kernel_launch(void* const* d_in, const int* in_sizes, int n_in,
                              void* d_out, int out_size, void* d_ws, size_t ws_size,
                              hipStream_t stream) {
    const float* x        = (const float*)d_in[0];
    const int*   ei       = (const int*)d_in[1];
    const int*   ntype    = (const int*)d_in[2];
    const int*   etype    = (const int*)d_in[3];
    // d_in[4] edge_attr: unused (reference feeds zeros into the conv)
    const float* Wq       = (const float*)d_in[5];
    const float* Wk       = (const float*)d_in[6];
    const float* Wv       = (const float*)d_in[7];
    const float* att_src  = (const float*)d_in[8];
    const float* att_dst  = (const float*)d_in[9];
    const float* att_edge = (const float*)d_in[10];
    // d_in[11] We: unused (multiplied by zero edge_attr)
    const float* be       = (const float*)d_in[12];
    const float* Wn       = (const float*)d_in[13];
    const float* bn       = (const float*)d_in[14];
    const float* Wec      = (const float*)d_in[15];
    const float* bec      = (const float*)d_in[16];

    char* ws = (char*)d_ws;
    unsigned int*   vb32 = (unsigned int*)(ws + OFF_V);
    unsigned short* vb16 = (unsigned short*)(ws + OFF_V);
    float* ks4     = (float*)(ws + OFF_KS);
    float* qd4     = (float*)(ws + OFF_QD);
    float* rtab    = (float*)(ws + OFF_R);
    int*   counts  = (int*)(ws + OFF_COUNTS);
    int*   ncnt    = (int*)(ws + OFF_NCNT);
    int*   ncur    = (int*)(ws + OFF_NCUR);
    int*   row_ptr = (int*)(ws + OFF_ROWPTR);
    int*   cursor  = (int*)(ws + OFF_CURSOR);
    int*   incl    = (int*)(ws + OFF_INCL);
    int*   bsums   = (int*)(ws + OFF_BSUMS);
    uint2* edges   = (uint2*)(ws + OFF_EDGES);
    float* wk_red  = (float*)(ws + OFF_WKRED);
    float* wq_red  = (float*)(ws + OFF_WQRED);
    float* etl     = (float*)(ws + OFF_ETL);
    int*   nbase   = (int*)(ws + OFF_NBASE);
    int*   nperm   = (int*)(ws + OFF_NPERM);
    unsigned int* wpack = (unsigned int*)(ws + OFF_WPACK);

    float* out_x = (float*)d_out;
    float* out_e = (float*)d_out + NN;

    hipMemsetAsync(ws + OFF_COUNTS, 0, 400016, stream);   // counts + ncnt (contiguous)
    k_initcount<<<(NE + 255) / 256, 256, 0, stream>>>(ei, ntype, counts, ncnt, nperm);
    k_pre<<<31, 256, 0, stream>>>(Wq, Wk, Wv, att_src, att_dst, be, att_edge,
                                  wk_red, wq_red, etl, wpack);
    k_scan1<<<49, 256, 0, stream>>>(counts, incl, bsums);
    k_scan2<<<1, 64, 0, stream>>>(bsums, 49, ncnt, nbase, ncur);
    k_scan3<<<(NN + 255) / 256, 256, 0, stream>>>(counts, incl, bsums, row_ptr, cursor,
                                                  ntype, nbase, ncur, nperm);
    k_fill<<<(NE + 255) / 256, 256, 0, stream>>>(ei, etype, cursor, edges);
    k_node<<<(NN + 96) / 64, 256, 0, stream>>>(x, (const unsigned short*)wpack, ntype, nperm,
                                               wk_red, wq_red, be, Wec, vb16, ks4, qd4, rtab);
    k_main<<<(NN + 3) / 4, 256, 0, stream>>>(row_ptr, edges, ks4, qd4, etl, vb32, be,
                                             rtab, bec, Wn, bn, ntype, out_x, out_e);
}

// Round 8
// 265.146 us; speedup vs baseline: 2.0510x; 1.0106x over previous
//
#include <hip/hip_runtime.h>
#include <hip/hip_bf16.h>

// HATGNN forward.
// Pipeline: memset(counts+ncnt) -> k_initcount -> k_pre -> k_scan1 -> k_scan2(+nbase)
//   -> k_scan3(+nscatter) -> k_fill -> k_node (MFMA v-GEMV + ks/qd + r, fused)
//   -> k_main (softmax + aggregation + x_cls + fused e_cls).
// v is stored in MFMA D-fragment order: dim' = col*8+ot  <->  orig dim = ot*16+col.
// be/Wec/Wn are permuted once (k_pre) to match; all consumers are permutation-invariant.

#define NN 100000
#define NE 600000
#define FD 128
#define HIDD 128
#define NH 4
#define DH 32
#define NT 3
#define NET 4
#define SLOPE 0.2f

typedef short bf16x8 __attribute__((ext_vector_type(8)));
typedef float f32x4 __attribute__((ext_vector_type(4)));

// ---------------- ws layout (bytes) ----------------
#define OFF_V       0UL            // N*128 bf16     25,600,000
#define OFF_KS      25600000UL     // N*4 f32         1,600,000
#define OFF_QD      27200000UL     // N*4 f32         1,600,000
#define OFF_R       28800000UL     // N*16 f32        6,400,000
#define OFF_COUNTS  35200000UL     // N int             400,000
#define OFF_NCNT    35600000UL     // 4 int (memset, contiguous with counts)
#define OFF_NCUR    35600016UL     // 4 int
#define OFF_ROWPTR  35600128UL     // (N+1) int
#define OFF_CURSOR  36000256UL     // N int
#define OFF_INCL    36400256UL     // N int
#define OFF_BSUMS   36800256UL     // 64 int
#define OFF_EDGES   36800512UL     // E uint2         4,800,000
#define OFF_WKRED   41600512UL     // 3*128*4 f32
#define OFF_WQRED   41606656UL
#define OFF_ETL     41612800UL     // 4*4 f32
#define OFF_NBASE   41612928UL
#define OFF_NPERM   41613056UL     // (N+96) int
#define OFF_WPACK   42013440UL     // 3*8*4*64*8 bf16 = 196,608 B
#define OFF_BEP     42210048UL     // 4*128 f32 (permuted be)
#define OFF_WECP    42212096UL     // 4*128 f32 (permuted Wec)
#define OFF_WNP     42214144UL     // 3*128 f32 (permuted Wn)

__device__ __forceinline__ unsigned int pack_bf16(float a, float b) {
    __hip_bfloat16 ha = __float2bfloat16(a);
    __hip_bfloat16 hb = __float2bfloat16(b);
    unsigned short ua = *reinterpret_cast<unsigned short*>(&ha);
    unsigned short ub = *reinterpret_cast<unsigned short*>(&hb);
    return (unsigned int)ua | ((unsigned int)ub << 16);
}

union U8 { uint4 u; bf16x8 v; };

// ------------- init+count: nperm fill, ntype hist, edge degree count -------------
__global__ void k_initcount(const int* __restrict__ ei, const int* __restrict__ ntype,
                            int* __restrict__ counts, int* __restrict__ ncnt,
                            int* __restrict__ nperm) {
    __shared__ int c[NT];
    if (threadIdx.x < NT) c[threadIdx.x] = 0;
    __syncthreads();
    int i = blockIdx.x * blockDim.x + threadIdx.x;
    if (i < NE) atomicAdd(&counts[ei[NE + i]], 1);
    if (i < NN) atomicAdd(&c[ntype[i]], 1);
    if (i < NN + 96) nperm[i] = -1;
    __syncthreads();
    if (threadIdx.x < NT && c[threadIdx.x]) atomicAdd(&ncnt[threadIdx.x], c[threadIdx.x]);
}

// ------------- precompute: reduced weights + etl + Wv pack + permuted be/Wec/Wn -------------
#define PACK_BASE 1600
#define PERM_BASE 7744
__global__ void k_pre(const float* __restrict__ Wq, const float* __restrict__ Wk,
                      const float* __restrict__ Wv,
                      const float* __restrict__ att_src, const float* __restrict__ att_dst,
                      const float* __restrict__ be, const float* __restrict__ att_edge,
                      const float* __restrict__ Wec, const float* __restrict__ Wn,
                      float* __restrict__ wk_red, float* __restrict__ wq_red, float* __restrict__ etl,
                      unsigned int* __restrict__ wpack, float* __restrict__ bep,
                      float* __restrict__ wecp, float* __restrict__ wnp) {
    int gid = blockIdx.x * blockDim.x + threadIdx.x;
    if (gid < NT * FD * NH) {
        int h = gid % NH;
        int i = (gid / NH) % FD;
        int t = gid / (NH * FD);
        const float* wkp = Wk + ((size_t)t * FD + i) * HIDD + h * DH;
        const float* wqp = Wq + ((size_t)t * FD + i) * HIDD + h * DH;
        const float* as = att_src + h * DH;
        const float* ad = att_dst + h * DH;
        float sk = 0.f, sq = 0.f;
        for (int d = 0; d < DH; ++d) { sk += wkp[d] * as[d]; sq += wqp[d] * ad[d]; }
        wk_red[gid] = sk;   // layout [t][i][h]
        wq_red[gid] = sq;
    } else if (gid < NT * FD * NH + NET * NH) {
        int rdx = gid - NT * FD * NH;
        int h = rdx % NH;
        int t = rdx / NH;
        float s = 0.f;
        for (int d = 0; d < DH; ++d) s += be[t * HIDD + h * DH + d] * att_edge[h * DH + d];
        etl[rdx] = s;       // layout [t][h]
    } else if (gid >= PACK_BASE && gid < PACK_BASE + NT * 8 * 4 * 64) {
        int q = gid - PACK_BASE;
        int t = q >> 11;
        int rem = q & 2047;
        int ot = rem >> 8;
        int rem2 = rem & 255;
        int kc = rem2 >> 6;
        int l = rem2 & 63;
        int o = ot * 16 + (l & 15);
        int kb = kc * 32 + (l >> 4) * 8;
        unsigned int w[4];
#pragma unroll
        for (int jj = 0; jj < 4; ++jj) {
            float v0 = Wv[((size_t)t * FD + kb + 2 * jj) * HIDD + o];
            float v1 = Wv[((size_t)t * FD + kb + 2 * jj + 1) * HIDD + o];
            w[jj] = pack_bf16(v0, v1);
        }
        uint4 o4 = {w[0], w[1], w[2], w[3]};
        *reinterpret_cast<uint4*>(wpack + (size_t)q * 4) = o4;
    } else if (gid >= PERM_BASE && gid < PERM_BASE + 1408) {
        int p = gid - PERM_BASE;
        int dp = p & 127;                 // dim' = col*8 + ot
        int col = dp >> 3, ot = dp & 7;
        int od = ot * 16 + col;           // original dim
        if (p < 512) {
            int t2 = p >> 7;
            bep[p] = be[t2 * HIDD + od];
        } else if (p < 1024) {
            int t2 = (p - 512) >> 7;
            wecp[p - 512] = Wec[t2 * HIDD + od];
        } else {
            int t = (p - 1024) >> 7;
            wnp[p - 1024] = Wn[t * HIDD + od];
        }
    }
}

// ------------- CSR scan -------------
__global__ void k_scan1(const int* __restrict__ counts, int* __restrict__ incl, int* __restrict__ bsums) {
    __shared__ int lds[2048];
    int base = blockIdx.x * 2048;
    for (int k = threadIdx.x; k < 2048; k += 256)
        lds[k] = (base + k < NN) ? counts[base + k] : 0;
    __syncthreads();
    for (int off = 1; off < 2048; off <<= 1) {
        int vals[8];
        for (int j = 0; j < 8; ++j) {
            int k = threadIdx.x + j * 256;
            vals[j] = (k >= off) ? lds[k - off] : 0;
        }
        __syncthreads();
        for (int j = 0; j < 8; ++j) {
            int k = threadIdx.x + j * 256;
            lds[k] += vals[j];
        }
        __syncthreads();
    }
    for (int k = threadIdx.x; k < 2048; k += 256)
        if (base + k < NN) incl[base + k] = lds[k];
    if (threadIdx.x == 0) bsums[blockIdx.x] = lds[2047];
}

__global__ void k_scan2(int* __restrict__ bsums, int nb, const int* __restrict__ ncnt,
                        int* __restrict__ nbase, int* __restrict__ ncur) {
    if (threadIdx.x == 0) {
        int run = 0;
        for (int i = 0; i < nb; ++i) { int vv = bsums[i]; bsums[i] = run; run += vv; }
        int b = 0;
        for (int t = 0; t < NT; ++t) {
            nbase[t] = b;
            ncur[t] = 0;
            b += (ncnt[t] + 15) & ~15;
        }
        nbase[NT] = b;
    }
}

__global__ void k_scan3(const int* __restrict__ counts, const int* __restrict__ incl,
                        const int* __restrict__ bsums, int* __restrict__ row_ptr, int* __restrict__ cursor,
                        const int* __restrict__ ntype, const int* __restrict__ nbase,
                        int* __restrict__ ncur, int* __restrict__ nperm) {
    int i = blockIdx.x * blockDim.x + threadIdx.x;
    if (i == 0) row_ptr[NN] = NE;
    if (i >= NN) return;
    int ex = incl[i] - counts[i] + bsums[i / 2048];
    row_ptr[i] = ex;
    cursor[i] = ex;
    int tt = ntype[i];
    int lane = threadIdx.x & 63;
    for (int t = 0; t < NT; ++t) {
        unsigned long long m = __ballot(tt == t);
        if (tt == t) {
            int rank = __popcll(m & ((1ull << lane) - 1ull));
            int leader = __ffsll((unsigned long long)m) - 1;
            int base = 0;
            if (lane == leader) base = atomicAdd(&ncur[t], (int)__popcll(m));
            base = __shfl(base, leader, 64);
            nperm[nbase[t] + base + rank] = i;
        }
    }
}

__global__ void k_fill(const int* __restrict__ ei, const int* __restrict__ etype, int* __restrict__ cursor,
                       uint2* __restrict__ edges) {
    int e = blockIdx.x * blockDim.x + threadIdx.x;
    if (e >= NE) return;
    int dst = ei[NE + e];
    int pos = atomicAdd(&cursor[dst], 1);
    uint2 rec;
    rec.x = ((unsigned)ei[e] << 2) | (unsigned)etype[e];
    rec.y = (unsigned)e;
    edges[pos] = rec;
}

// ------------- fused node kernel: v' = x @ Wv[type] (MFMA) + ks/qd + r table -------------
// Wave handles 16 same-type nodes. col = lane&15, kg = lane>>4.
// A: node nperm[base+col], k-dims kg*8+j.  D (ot): out-dim ot*16+col, node kg*4+rg.
// v stored permuted: vb[n][col*8+ot].
__global__ __launch_bounds__(256) void k_node(const float* __restrict__ x,
                                              const unsigned short* __restrict__ wpack,
                                              const int* __restrict__ ntype, const int* __restrict__ nperm,
                                              const float* __restrict__ wk_red, const float* __restrict__ wq_red,
                                              const float* __restrict__ bep, const float* __restrict__ wecp,
                                              unsigned short* __restrict__ vb, float* __restrict__ ks4,
                                              float* __restrict__ qd4, float* __restrict__ rtab) {
    int wave = threadIdx.x >> 6, lane = threadIdx.x & 63;
    int base = blockIdx.x * 64 + wave * 16;
    int n0 = nperm[base];
    if (n0 < 0) return;                      // fully padded tile
    int t = ntype[n0];
    int col = lane & 15, kg = lane >> 4;
    int anr = nperm[base + col];
    bool avalid = anr >= 0;
    int an = avalid ? anr : 0;

    // ---- load x rows (f32, gathered) ----
    const float* xp = x + (size_t)an * FD;
    float xf[4][8];
#pragma unroll
    for (int kc = 0; kc < 4; ++kc) {
        float4 a4 = *reinterpret_cast<const float4*>(xp + kc * 32 + kg * 8);
        float4 b4 = *reinterpret_cast<const float4*>(xp + kc * 32 + kg * 8 + 4);
        xf[kc][0] = a4.x; xf[kc][1] = a4.y; xf[kc][2] = a4.z; xf[kc][3] = a4.w;
        xf[kc][4] = b4.x; xf[kc][5] = b4.y; xf[kc][6] = b4.z; xf[kc][7] = b4.w;
    }

    // ---- ks/qd (f32): lane covers 32 dims of node 'an'; reduce over kg ----
    {
        float ka[4] = {0, 0, 0, 0}, qa[4] = {0, 0, 0, 0};
#pragma unroll
        for (int kc = 0; kc < 4; ++kc) {
#pragma unroll
            for (int j = 0; j < 8; ++j) {
                int dim = kc * 32 + kg * 8 + j;
                float xv = xf[kc][j];
                float4 wk4 = *reinterpret_cast<const float4*>(wk_red + ((size_t)t * FD + dim) * NH);
                float4 wq4 = *reinterpret_cast<const float4*>(wq_red + ((size_t)t * FD + dim) * NH);
                ka[0] = fmaf(xv, wk4.x, ka[0]); ka[1] = fmaf(xv, wk4.y, ka[1]);
                ka[2] = fmaf(xv, wk4.z, ka[2]); ka[3] = fmaf(xv, wk4.w, ka[3]);
                qa[0] = fmaf(xv, wq4.x, qa[0]); qa[1] = fmaf(xv, wq4.y, qa[1]);
                qa[2] = fmaf(xv, wq4.z, qa[2]); qa[3] = fmaf(xv, wq4.w, qa[3]);
            }
        }
#pragma unroll
        for (int off = 16; off < 64; off <<= 1) {
#pragma unroll
            for (int h = 0; h < 4; ++h) {
                ka[h] += __shfl_xor(ka[h], off, 64);
                qa[h] += __shfl_xor(qa[h], off, 64);
            }
        }
        if (kg == 0 && avalid) {
            float4 ko = {ka[0], ka[1], ka[2], ka[3]};
            float4 qo = {qa[0], qa[1], qa[2], qa[3]};
            *reinterpret_cast<float4*>(ks4 + (size_t)an * NH) = ko;
            *reinterpret_cast<float4*>(qd4 + (size_t)an * NH) = qo;
        }
    }

    // ---- A fragments (bf16) ----
    bf16x8 afrag[4];
#pragma unroll
    for (int kc = 0; kc < 4; ++kc) {
        U8 u;
        u.u.x = pack_bf16(xf[kc][0], xf[kc][1]);
        u.u.y = pack_bf16(xf[kc][2], xf[kc][3]);
        u.u.z = pack_bf16(xf[kc][4], xf[kc][5]);
        u.u.w = pack_bf16(xf[kc][6], xf[kc][7]);
        afrag[kc] = u.v;
    }

    int dn[4];
#pragma unroll
    for (int rg = 0; rg < 4; ++rg) dn[rg] = nperm[base + kg * 4 + rg];

    // ---- 32 MFMAs: all 8 ot accumulators ----
    const unsigned short* wt = wpack + (size_t)t * 8 * 4 * 64 * 8;
    f32x4 acc[8];
#pragma unroll
    for (int ot = 0; ot < 8; ++ot) { f32x4 z = {0.f, 0.f, 0.f, 0.f}; acc[ot] = z; }
#pragma unroll
    for (int kc = 0; kc < 4; ++kc) {
#pragma unroll
        for (int ot = 0; ot < 8; ++ot) {
            bf16x8 b = *reinterpret_cast<const bf16x8*>(wt + ((size_t)(ot * 4 + kc) * 64 + lane) * 8);
            acc[ot] = __builtin_amdgcn_mfma_f32_16x16x32_bf16(afrag[kc], b, acc[ot], 0, 0, 0);
        }
    }

    // ---- v' store: 16B per node row per lane, 16-lane contiguous runs ----
#pragma unroll
    for (int rg = 0; rg < 4; ++rg) {
        if (dn[rg] >= 0) {
            uint4 o4;
            o4.x = pack_bf16(acc[0][rg], acc[1][rg]);
            o4.y = pack_bf16(acc[2][rg], acc[3][rg]);
            o4.z = pack_bf16(acc[4][rg], acc[5][rg]);
            o4.w = pack_bf16(acc[6][rg], acc[7][rg]);
            *reinterpret_cast<uint4*>(vb + (size_t)dn[rg] * FD + col * 8) = o4;
        }
    }

    // ---- r table via multi-value butterfly (15 shfl per rg) ----
    // cur[m = t2*4+h] = sum_{o in {2h,2h+1}} relu(acc[o][rg]+be')*Wec' at dim' col*8+o
#pragma unroll
    for (int rg = 0; rg < 4; ++rg) {
        float cur[16];
#pragma unroll
        for (int t2 = 0; t2 < NET; ++t2) {
            float4 b0 = *reinterpret_cast<const float4*>(bep + t2 * HIDD + col * 8);
            float4 b1 = *reinterpret_cast<const float4*>(bep + t2 * HIDD + col * 8 + 4);
            float4 w0 = *reinterpret_cast<const float4*>(wecp + t2 * HIDD + col * 8);
            float4 w1 = *reinterpret_cast<const float4*>(wecp + t2 * HIDD + col * 8 + 4);
            cur[t2 * 4 + 0] = fmaxf(acc[0][rg] + b0.x, 0.f) * w0.x + fmaxf(acc[1][rg] + b0.y, 0.f) * w0.y;
            cur[t2 * 4 + 1] = fmaxf(acc[2][rg] + b0.z, 0.f) * w0.z + fmaxf(acc[3][rg] + b0.w, 0.f) * w0.w;
            cur[t2 * 4 + 2] = fmaxf(acc[4][rg] + b1.x, 0.f) * w1.x + fmaxf(acc[5][rg] + b1.y, 0.f) * w1.y;
            cur[t2 * 4 + 3] = fmaxf(acc[6][rg] + b1.z, 0.f) * w1.z + fmaxf(acc[7][rg] + b1.w, 0.f) * w1.w;
        }
        int cb = col & 1;
        float n8[8];
#pragma unroll
        for (int i = 0; i < 8; ++i) {
            float keep = cb ? cur[2 * i + 1] : cur[2 * i];
            float give = cb ? cur[2 * i] : cur[2 * i + 1];
            n8[i] = keep + __shfl_xor(give, 1, 64);
        }
        cb = (col >> 1) & 1;
        float n4[4];
#pragma unroll
        for (int i = 0; i < 4; ++i) {
            float keep = cb ? n8[2 * i + 1] : n8[2 * i];
            float give = cb ? n8[2 * i] : n8[2 * i + 1];
            n4[i] = keep + __shfl_xor(give, 2, 64);
        }
        cb = (col >> 2) & 1;
        float n2[2];
#pragma unroll
        for (int i = 0; i < 2; ++i) {
            float keep = cb ? n4[2 * i + 1] : n4[2 * i];
            float give = cb ? n4[2 * i] : n4[2 * i + 1];
            n2[i] = keep + __shfl_xor(give, 4, 64);
        }
        cb = (col >> 3) & 1;
        {
            float keep = cb ? n2[1] : n2[0];
            float give = cb ? n2[0] : n2[1];
            float tot = keep + __shfl_xor(give, 8, 64);
            if (dn[rg] >= 0) rtab[(size_t)dn[rg] * 16 + col] = tot;
        }
    }
}

// ------------- main: softmax + aggregation + x_cls + fused e_cls -------------
// vb is in permuted layout: lane's uint covers dim' {2*lane, 2*lane+1}, head = lane&3.
__global__ __launch_bounds__(256) void k_main(const int* __restrict__ row_ptr, const uint2* __restrict__ edges,
                                              const float* __restrict__ ks4, const float* __restrict__ qd4,
                                              const float* __restrict__ etl, const unsigned int* __restrict__ vb,
                                              const float* __restrict__ bep, const float* __restrict__ rtab,
                                              const float* __restrict__ bec, const float* __restrict__ wnp,
                                              const float* __restrict__ bn, const int* __restrict__ ntype,
                                              float* __restrict__ out_x, float* __restrict__ out_e) {
    int wave = threadIdx.x >> 6;
    int lane = threadIdx.x & 63;
    int n = blockIdx.x * 4 + wave;
    if (n >= NN) return;
    int rs = row_ptr[n], deg = row_ptr[n + 1] - rs;
    int hh = lane & 3;
    int k0 = lane >> 2;

    float q = qd4[(size_t)n * NH + hh];

    bool act0 = k0 < deg;
    uint2 ed0 = {0u, 0u};
    if (act0) ed0 = edges[rs + k0];
    int s0r = (int)(ed0.x >> 2), et0 = (int)(ed0.x & 3u);
    float lg0 = -INFINITY;
    if (act0) {
        float l = ks4[(size_t)s0r * NH + hh] + q + etl[et0 * NH + hh];
        lg0 = l >= 0.f ? l : SLOPE * l;
    }
    float mx = lg0;
    if (deg > 16) {
        for (int bb = 16; bb < deg; bb += 16) {
            int kk = bb + k0;
            if (kk < deg) {
                uint2 ed = edges[rs + kk];
                int s = (int)(ed.x >> 2), et = (int)(ed.x & 3u);
                float l = ks4[(size_t)s * NH + hh] + q + etl[et * NH + hh];
                l = l >= 0.f ? l : SLOPE * l;
                mx = fmaxf(mx, l);
            }
        }
    }
#pragma unroll
    for (int off = 4; off < 64; off <<= 1) mx = fmaxf(mx, __shfl_xor(mx, off, 64));

    float e0 = act0 ? __expf(lg0 - mx) : 0.f;
    float dn = e0;
    if (deg > 16) {
        for (int bb = 16; bb < deg; bb += 16) {
            int kk = bb + k0;
            if (kk < deg) {
                uint2 ed = edges[rs + kk];
                int s = (int)(ed.x >> 2), et = (int)(ed.x & 3u);
                float l = ks4[(size_t)s * NH + hh] + q + etl[et * NH + hh];
                l = l >= 0.f ? l : SLOPE * l;
                dn += __expf(l - mx);
            }
        }
    }
#pragma unroll
    for (int off = 4; off < 64; off <<= 1) dn += __shfl_xor(dn, off, 64);
    float inv = 1.0f / (dn + 1e-16f);

    // fused e_cls
    if (act0) {
        float term = e0 * inv * rtab[((size_t)s0r * NET + et0) * NH + hh];
        term += __shfl_xor(term, 1, 64);
        term += __shfl_xor(term, 2, 64);
        if (hh == 0) out_e[ed0.y] = term + bec[et0];
    }
    if (deg > 16) {
        for (int bb = 16; bb < deg; bb += 16) {
            int kk = bb + k0;
            if (kk < deg) {
                uint2 ed = edges[rs + kk];
                int s = (int)(ed.x >> 2), et = (int)(ed.x & 3u);
                float l = ks4[(size_t)s * NH + hh] + q + etl[et * NH + hh];
                l = l >= 0.f ? l : SLOPE * l;
                float term = __expf(l - mx) * inv * rtab[((size_t)s * NET + et) * NH + hh];
                term += __shfl_xor(term, 1, 64);
                term += __shfl_xor(term, 2, 64);
                if (hh == 0) out_e[ed.y] = term + bec[et];
            }
        }
    }

    float alpha0 = e0 * inv;

    // aggregation: acc += alpha * (v'[src] + be'[et]); head of lane's dims = hh
    float ax = 0.f, ay = 0.f;
    int cnt0 = deg < 16 ? deg : 16;
#define AGG_STEP(JJ) { \
        float p = __shfl(alpha0, 4 * (JJ) + hh, 64); \
        unsigned int pk = __shfl(ed0.x, 4 * (JJ), 64); \
        int sn = (int)(pk >> 2), et = (int)(pk & 3u); \
        unsigned int w = vb[(size_t)sn * 64 + lane]; \
        float2 b2 = *reinterpret_cast<const float2*>(bep + et * HIDD + 2 * lane); \
        ax = fmaf(p, __uint_as_float(w << 16) + b2.x, ax); \
        ay = fmaf(p, __uint_as_float(w & 0xffff0000u) + b2.y, ay); }
    {
        int j = 0;
        for (; j + 4 <= cnt0; j += 4) {
            AGG_STEP(j) AGG_STEP(j + 1) AGG_STEP(j + 2) AGG_STEP(j + 3)
        }
        for (; j < cnt0; ++j) AGG_STEP(j)
    }
    if (deg > 16) {
        for (int bb = 16; bb < deg; bb += 16) {
            int kk = bb + k0;
            float al = 0.f;
            unsigned int pkr = 0;
            if (kk < deg) {
                uint2 ed = edges[rs + kk];
                pkr = ed.x;
                int s = (int)(ed.x >> 2), et = (int)(ed.x & 3u);
                float l = ks4[(size_t)s * NH + hh] + q + etl[et * NH + hh];
                l = l >= 0.f ? l : SLOPE * l;
                al = __expf(l - mx) * inv;
            }
            int cnt = deg - bb; if (cnt > 16) cnt = 16;
#define AGG_STEP2(JJ) { \
            float p = __shfl(al, 4 * (JJ) + hh, 64); \
            unsigned int pk = __shfl(pkr, 4 * (JJ), 64); \
            int sn = (int)(pk >> 2), et = (int)(pk & 3u); \
            unsigned int w = vb[(size_t)sn * 64 + lane]; \
            float2 b2 = *reinterpret_cast<const float2*>(bep + et * HIDD + 2 * lane); \
            ax = fmaf(p, __uint_as_float(w << 16) + b2.x, ax); \
            ay = fmaf(p, __uint_as_float(w & 0xffff0000u) + b2.y, ay); }
            int j = 0;
            for (; j + 4 <= cnt; j += 4) {
                AGG_STEP2(j) AGG_STEP2(j + 1) AGG_STEP2(j + 2) AGG_STEP2(j + 3)
            }
            for (; j < cnt; ++j) AGG_STEP2(j)
        }
    }

    int t = ntype[n];
    float2 w2 = *reinterpret_cast<const float2*>(wnp + t * HIDD + 2 * lane);
    float s = fmaxf(ax, 0.f) * w2.x + fmaxf(ay, 0.f) * w2.y;
#pragma unroll
    for (int off = 1; off < 64; off <<= 1) s += __shfl_xor(s, off, 64);
    if (lane == 0) out_x[n] = s + bn[t];
}

extern "C" void kernel_launch(void* const* d_in, const int* in_sizes, int n_in,
                              void* d_out, int out_size, void* d_ws, size_t ws_size,
                              hipStream_t stream) {
    const float* x        = (const float*)d_in[0];
    const int*   ei       = (const int*)d_in[1];
    const int*   ntype    = (const int*)d_in[2];
    const int*   etype    = (const int*)d_in[3];
    // d_in[4] edge_attr: unused (reference feeds zeros into the conv)
    const float* Wq       = (const float*)d_in[5];
    const float* Wk       = (const float*)d_in[6];
    const float* Wv       = (const float*)d_in[7];
    const float* att_src  = (const float*)d_in[8];
    const float* att_dst  = (const float*)d_in[9];
    const float* att_edge = (const float*)d_in[10];
    // d_in[11] We: unused (multiplied by zero edge_attr)
    const float* be       = (const float*)d_in[12];
    const float* Wn       = (const float*)d_in[13];
    const float* bn       = (const float*)d_in[14];
    const float* Wec      = (const float*)d_in[15];
    const float* bec      = (const float*)d_in[16];

    char* ws = (char*)d_ws;
    unsigned int*   vb32 = (unsigned int*)(ws + OFF_V);
    unsigned short* vb16 = (unsigned short*)(ws + OFF_V);
    float* ks4     = (float*)(ws + OFF_KS);
    float* qd4     = (float*)(ws + OFF_QD);
    float* rtab    = (float*)(ws + OFF_R);
    int*   counts  = (int*)(ws + OFF_COUNTS);
    int*   ncnt    = (int*)(ws + OFF_NCNT);
    int*   ncur    = (int*)(ws + OFF_NCUR);
    int*   row_ptr = (int*)(ws + OFF_ROWPTR);
    int*   cursor  = (int*)(ws + OFF_CURSOR);
    int*   incl    = (int*)(ws + OFF_INCL);
    int*   bsums   = (int*)(ws + OFF_BSUMS);
    uint2* edges   = (uint2*)(ws + OFF_EDGES);
    float* wk_red  = (float*)(ws + OFF_WKRED);
    float* wq_red  = (float*)(ws + OFF_WQRED);
    float* etl     = (float*)(ws + OFF_ETL);
    int*   nbase   = (int*)(ws + OFF_NBASE);
    int*   nperm   = (int*)(ws + OFF_NPERM);
    unsigned int* wpack = (unsigned int*)(ws + OFF_WPACK);
    float* bep     = (float*)(ws + OFF_BEP);
    float* wecp    = (float*)(ws + OFF_WECP);
    float* wnp     = (float*)(ws + OFF_WNP);

    float* out_x = (float*)d_out;
    float* out_e = (float*)d_out + NN;

    hipMemsetAsync(ws + OFF_COUNTS, 0, 400016, stream);   // counts + ncnt (contiguous)
    k_initcount<<<(NE + 255) / 256, 256, 0, stream>>>(ei, ntype, counts, ncnt, nperm);
    k_pre<<<36, 256, 0, stream>>>(Wq, Wk, Wv, att_src, att_dst, be, att_edge, Wec, Wn,
                                  wk_red, wq_red, etl, wpack, bep, wecp, wnp);
    k_scan1<<<49, 256, 0, stream>>>(counts, incl, bsums);
    k_scan2<<<1, 64, 0, stream>>>(bsums, 49, ncnt, nbase, ncur);
    k_scan3<<<(NN + 255) / 256, 256, 0, stream>>>(counts, incl, bsums, row_ptr, cursor,
                                                  ntype, nbase, ncur, nperm);
    k_fill<<<(NE + 255) / 256, 256, 0, stream>>>(ei, etype, cursor, edges);
    k_node<<<(NN + 96) / 64, 256, 0, stream>>>(x, (const unsigned short*)wpack, ntype, nperm,
                                               wk_red, wq_red, bep, wecp, vb16, ks4, qd4, rtab);
    k_main<<<(NN + 3) / 4, 256, 0, stream>>>(row_ptr, edges, ks4, qd4, etl, vb32, bep,
                                             rtab, bec, wnp, bn, ntype, out_x, out_e);
}